// Round 8
// baseline (416.104 us; speedup 1.0000x reference)
//
#include <hip/hip_runtime.h>
#include <cmath>

typedef unsigned short u16;
typedef __bf16 bf16x8 __attribute__((ext_vector_type(8)));
typedef float f32x4 __attribute__((ext_vector_type(4)));
typedef unsigned short u16x8 __attribute__((ext_vector_type(8)));

#define NB_B   4
#define NB_L   2048
#define NB_DIM 1024
#define NB_H   2048
#define NB_NS  16
#define NB_DTR 64
#define NB_TOK (NB_B * NB_L)   // 8192
#define NCHUNK 64
#define CLEN   32              // NB_L / NCHUNK

__device__ __forceinline__ u16 f2b(float f) {
  union { float f; unsigned u; } v; v.f = f;
  unsigned r = v.u + 0x7fffu + ((v.u >> 16) & 1u);
  return (u16)(r >> 16);
}
__device__ __forceinline__ float b2f(u16 h) {
  union { unsigned u; float f; } v; v.u = ((unsigned)h) << 16;
  return v.f;
}
// exp(w) for |w| <= ~2e-4 here: 1 + w + w^2/2, err ~ |w|^3/6
__device__ __forceinline__ float exp_small(float w) {
  return __builtin_fmaf(w, __builtin_fmaf(w, 0.5f, 1.0f), 1.0f);
}

// ---------------- fused converts (x, W_in, W_dt, W_out, W_xproj+pad) --------
#define CVT_N0 2097152                      // x          f4
#define CVT_N1 (CVT_N0 + 1048576)           // W_in       f4
#define CVT_N2 (CVT_N1 + 32768)             // W_dt       f4
#define CVT_N3 (CVT_N2 + 524288)            // W_out      f4
#define CVT_N4 (CVT_N3 + 49152)             // W_xproj    f4 (96*2048/4)
#define CVT_N5 (CVT_N4 + 8192)              // xproj pad  u16x8 (32*2048/8)
__global__ void cvt_all_k(const float* __restrict__ x, const float* __restrict__ W_in,
                          const float* __restrict__ W_dt, const float* __restrict__ W_out,
                          const float* __restrict__ W_xp,
                          u16* __restrict__ xb, u16* __restrict__ winb,
                          u16* __restrict__ wdtb, u16* __restrict__ woutb,
                          u16* __restrict__ wxpb) {
  int i = blockIdx.x * 256 + threadIdx.x;
  if (i >= CVT_N5) return;
  if (i >= CVT_N4) {   // zero pad rows 96..127 of wxp
    int q = i - CVT_N4;
    u16x8 z = {};
    *reinterpret_cast<u16x8*>(wxpb + 96 * 2048 + q * 8) = z;
    return;
  }
  const float* src; u16* dst; int off;
  if (i < CVT_N0)      { src = x;     dst = xb;    off = i; }
  else if (i < CVT_N1) { src = W_in;  dst = winb;  off = i - CVT_N0; }
  else if (i < CVT_N2) { src = W_dt;  dst = wdtb;  off = i - CVT_N1; }
  else if (i < CVT_N3) { src = W_out; dst = woutb; off = i - CVT_N2; }
  else                 { src = W_xp;  dst = wxpb;  off = i - CVT_N3; }
  float4 v = reinterpret_cast<const float4*>(src)[off];
  ushort4 o;
  o.x = f2b(v.x); o.y = f2b(v.y); o.z = f2b(v.z); o.w = f2b(v.w);
  reinterpret_cast<ushort4*>(dst)[off] = o;
}

#define EPI_CONV    0   // GEMM1: xz store (u raw / silu z) + fused dwconv->uc
#define EPI_F32     1   // GEMM2: f32 xdbl + bf16 dtp (cols<64)
#define EPI_SP_BF16 2   // GEMM3: softplus
#define EPI_RES_F32 3   // GEMM4: +residual f32

__device__ __forceinline__ void stage16(const u16* g, u16* l) {
  __builtin_amdgcn_global_load_lds(
      (const __attribute__((address_space(1))) unsigned int*)g,
      (__attribute__((address_space(3))) unsigned int*)l, 16, 0, 0);
}

// ============ 2-barrier/K-tile pipelined GEMM (BK=64, BN=256) ==============
// C = A(MxK)*B(NxK)^T bf16. 512 thr = 8 waves (2x4), wave tile (BM/2)x64.
// Double-buffered LDS; tile kt+2's B staged at P1, A staged at P4 after the
// mid-barrier (which proves all waves consumed buf A-region at P2). Counted
// vmcnt(4) at P4 lands tile kt+1 while kt+2-B stays in flight. 2 s_barrier +
// 2 lgkm drains + 1 vmcnt per K-tile. XOR k-slot swizzle both-sides. Staging
// addresses hoisted to per-thread base pointers (+128B/tile).
template <int EPI, int BM>
__global__ __launch_bounds__(512, 1)
void gemm8p_k(const u16* __restrict__ A, const u16* __restrict__ Bm,
              int K, int ldc,
              u16* __restrict__ outB, float* __restrict__ outF,
              const float* __restrict__ bias, const float* __restrict__ resid,
              const float* __restrict__ cw, const float* __restrict__ cb,
              u16* __restrict__ ucout,
              int cr, int cc, int ncx) {
  constexpr int MR = BM / 32;
  constexpr int MH = MR / 2;
  constexpr int HA = BM / 2;
  constexpr int LA = BM / 128;           // A gloads per thread per half
  constexpr int PRO = 2 * LA + 4;        // gloads per thread per K-tile
  constexpr int BUFE = (BM + 256) * 64;
  __shared__ u16 smem[2 * BUFE];

  const int tid  = threadIdx.x;
  const int lane = tid & 63;
  const int wave = tid >> 6;
  const int wr = wave >> 2, wc = wave & 3;
  const int fr = lane & 15, fq = lane >> 4;

  const int bid = blockIdx.x;
  const int e = bid & 7, w = bid >> 3;
  const int row0 = ((e / ncx) * cr + (w % cr)) * BM;
  const int col0 = ((e % ncx) * cc + (w / cr)) * 256;

  f32x4 acc[MR][4] = {};
  bf16x8 bB[4][2], bA0[MH][2], bA1[MH][2];

  // hoisted staging addresses (global base ptrs + LDS offsets)
  const u16* gB[4]; int lBoff[4];
  const u16* gA[2 * LA]; int lAoff[2 * LA];
  {
    int c_ = tid, rih = c_ >> 3, p = c_ & 7;   // first 512-chunk
#pragma unroll
    for (int h = 0; h < 2; ++h)
#pragma unroll
      for (int l = 0; l < 2; ++l) {
        int cc2 = l * 512 + tid; int ri = cc2 >> 3; int pp = cc2 & 7;
        gB[h * 2 + l] = Bm + (size_t)(col0 + h * 128 + ri) * K + ((pp ^ (ri & 7)) * 8);
        lBoff[h * 2 + l] = BM * 64 + (h * 128 + ri) * 64 + pp * 8;
      }
#pragma unroll
    for (int h = 0; h < 2; ++h)
#pragma unroll
      for (int l = 0; l < LA; ++l) {
        int cc2 = l * 512 + tid; int ri = cc2 >> 3; int pp = cc2 & 7;
        gA[h * LA + l] = A + (size_t)(row0 + h * HA + ri) * K + ((pp ^ (ri & 7)) * 8);
        lAoff[h * LA + l] = (h * HA + ri) * 64 + pp * 8;
      }
    (void)c_; (void)rih; (void)p;
  }
  // hoisted fragment read offsets (u16 units)
  int offA[MR][2], offB[4][2];
#pragma unroll
  for (int m = 0; m < MR; ++m) {
    int rt = wr * HA + m * 16 + fr;
#pragma unroll
    for (int kk = 0; kk < 2; ++kk)
      offA[m][kk] = rt * 64 + (((kk * 4 + fq) ^ (rt & 7)) * 8);
  }
#pragma unroll
  for (int n = 0; n < 4; ++n) {
    int rt = wc * 64 + n * 16 + fr;
#pragma unroll
    for (int kk = 0; kk < 2; ++kk)
      offB[n][kk] = BM * 64 + rt * 64 + (((kk * 4 + fq) ^ (rt & 7)) * 8);
  }

  auto STAGE_B = [&](int kt) {
    const int ko = kt * 64;
    u16* base = smem + (kt & 1) * BUFE;
#pragma unroll
    for (int q = 0; q < 4; ++q) stage16(gB[q] + ko, base + lBoff[q]);
  };
  auto STAGE_A = [&](int kt) {
    const int ko = kt * 64;
    u16* base = smem + (kt & 1) * BUFE;
#pragma unroll
    for (int q = 0; q < 2 * LA; ++q) stage16(gA[q] + ko, base + lAoff[q]);
  };
  auto LD_A = [&](int m, int kk, int bi) {
    return *reinterpret_cast<const bf16x8*>(smem + bi * BUFE + offA[m][kk]);
  };
  auto LD_B = [&](int n, int kk, int bi) {
    return *reinterpret_cast<const bf16x8*>(smem + bi * BUFE + offB[n][kk]);
  };

  const int nk = K >> 6;
  // ---- prologue
  STAGE_B(0); STAGE_A(0);
  if (nk > 1) { STAGE_B(1); STAGE_A(1); }
  if (nk > 1) asm volatile("s_waitcnt vmcnt(%0)" :: "i"(PRO) : "memory");
  else        asm volatile("s_waitcnt vmcnt(0)" ::: "memory");
  __builtin_amdgcn_s_barrier();
  __builtin_amdgcn_sched_barrier(0);
#pragma unroll
  for (int n = 0; n < 4; ++n) { bB[n][0] = LD_B(n, 0, 0); bB[n][1] = LD_B(n, 1, 0); }
#pragma unroll
  for (int m = 0; m < MH; ++m) { bA0[m][0] = LD_A(m, 0, 0); bA0[m][1] = LD_A(m, 1, 0); }
  asm volatile("s_waitcnt lgkmcnt(0)" ::: "memory");
  __builtin_amdgcn_s_barrier();
  __builtin_amdgcn_sched_barrier(0);

  for (int kt = 0; kt < nk; ++kt) {
    const int bi = kt & 1;
    // P1: stage B(kt+2) | Q00
    if (kt + 2 < nk) STAGE_B(kt + 2);
    __builtin_amdgcn_s_setprio(1);
#pragma unroll
    for (int m = 0; m < MH; ++m)
#pragma unroll
      for (int n = 0; n < 2; ++n)
#pragma unroll
        for (int kk = 0; kk < 2; ++kk)
          acc[m][n] = __builtin_amdgcn_mfma_f32_16x16x32_bf16(bA0[m][kk], bB[n][kk], acc[m][n], 0, 0, 0);
    __builtin_amdgcn_s_setprio(0);
    __builtin_amdgcn_sched_barrier(0);
    // P2: read A-mh1 | Q01
#pragma unroll
    for (int m = 0; m < MH; ++m) { bA1[m][0] = LD_A(MH + m, 0, bi); bA1[m][1] = LD_A(MH + m, 1, bi); }
    __builtin_amdgcn_s_setprio(1);
#pragma unroll
    for (int m = 0; m < MH; ++m)
#pragma unroll
      for (int n = 2; n < 4; ++n)
#pragma unroll
        for (int kk = 0; kk < 2; ++kk)
          acc[m][n] = __builtin_amdgcn_mfma_f32_16x16x32_bf16(bA0[m][kk], bB[n][kk], acc[m][n], 0, 0, 0);
    __builtin_amdgcn_s_setprio(0);
    __builtin_amdgcn_sched_barrier(0);
    // P3: wait A-mh1 | Q10
    asm volatile("s_waitcnt lgkmcnt(0)" ::: "memory");
    __builtin_amdgcn_sched_barrier(0);
    __builtin_amdgcn_s_setprio(1);
#pragma unroll
    for (int m = 0; m < MH; ++m)
#pragma unroll
      for (int n = 0; n < 2; ++n)
#pragma unroll
        for (int kk = 0; kk < 2; ++kk)
          acc[MH + m][n] = __builtin_amdgcn_mfma_f32_16x16x32_bf16(bA1[m][kk], bB[n][kk], acc[MH + m][n], 0, 0, 0);
    __builtin_amdgcn_s_setprio(0);
    __builtin_amdgcn_sched_barrier(0);
    // P4: land kt+1; stage A(kt+2); pre-read next tile | Q11
    if (kt + 1 < nk) {
      if (kt + 2 < nk) asm volatile("s_waitcnt vmcnt(4)" ::: "memory");
      else             asm volatile("s_waitcnt vmcnt(0)" ::: "memory");
      __builtin_amdgcn_s_barrier();         // all waves past P2 reads; kt+1 landed
      __builtin_amdgcn_sched_barrier(0);
      if (kt + 2 < nk) STAGE_A(kt + 2);
#pragma unroll
      for (int n = 0; n < 2; ++n) { bB[n][0] = LD_B(n, 0, bi ^ 1); bB[n][1] = LD_B(n, 1, bi ^ 1); }
#pragma unroll
      for (int m = 0; m < MH; ++m) { bA0[m][0] = LD_A(m, 0, bi ^ 1); bA0[m][1] = LD_A(m, 1, bi ^ 1); }
    }
    __builtin_amdgcn_s_setprio(1);
#pragma unroll
    for (int m = 0; m < MH; ++m)
#pragma unroll
      for (int n = 2; n < 4; ++n)
#pragma unroll
        for (int kk = 0; kk < 2; ++kk)
          acc[MH + m][n] = __builtin_amdgcn_mfma_f32_16x16x32_bf16(bA1[m][kk], bB[n][kk], acc[MH + m][n], 0, 0, 0);
    __builtin_amdgcn_s_setprio(0);
    if (kt + 1 < nk) {
#pragma unroll
      for (int n = 2; n < 4; ++n) { bB[n][0] = LD_B(n, 0, bi ^ 1); bB[n][1] = LD_B(n, 1, bi ^ 1); }
    }
    asm volatile("s_waitcnt lgkmcnt(0)" ::: "memory");
    __builtin_amdgcn_s_barrier();           // tile end
    __builtin_amdgcn_sched_barrier(0);
  }

  // ---------------- epilogues ----------------
  if constexpr (EPI == EPI_CONV || EPI == EPI_SP_BF16) {
    const bool zblk = (EPI == EPI_CONV) && (col0 >= NB_H);
    u16* wv = smem + wave * 1152;   // 16 x 72 u16 per wave (bank-balanced)
#pragma unroll
    for (int m = 0; m < MR; ++m) {
#pragma unroll
      for (int n = 0; n < 4; ++n) {
        const int c = col0 + wc * 64 + n * 16 + fr;
        float bv = (EPI == EPI_SP_BF16) ? bias[c] : 0.f;
#pragma unroll
        for (int j = 0; j < 4; ++j) {
          float v = acc[m][n][j];
          if (EPI == EPI_SP_BF16) {
            float xx = v + bv;
            float t = __expf(xx);
            float sp = (xx > -5.f) ? log1pf(t) : t;
            v = (xx > 20.f) ? xx : sp;
          } else if (zblk) {
            v = v / (1.f + __expf(-v));     // store silu(z)
          }
          wv[(fq * 4 + j) * 72 + n * 16 + fr] = f2b(v);
        }
      }
#pragma unroll
      for (int p = 0; p < 2; ++p) {
        const int rf = p * 8 + (lane >> 3);
        const int c0 = (lane & 7) * 8;
        u16x8 ov = *reinterpret_cast<const u16x8*>(wv + rf * 72 + c0);
        const int grow = row0 + wr * HA + m * 16 + rf;
        const int gcol = col0 + wc * 64 + c0;
        *reinterpret_cast<u16x8*>(&outB[(size_t)grow * ldc + gcol]) = ov;
      }
    }
    // fused depthwise conv (k=3) + silu -> uc, interior rows only
    if (EPI == EPI_CONV && !zblk) {
#pragma unroll
      for (int n = 0; n < 4; ++n) {
        const int c = col0 + wc * 64 + n * 16 + fr;
        const float w0 = cw[c * 3 + 0], w1 = cw[c * 3 + 1], w2 = cw[c * 3 + 2];
        const float bb = cb[c];
        float p3[MR], q0[MR];
#pragma unroll
        for (int m = 0; m < MR; ++m) {
          p3[m] = __shfl(acc[m][n][3], (lane + 48) & 63, 64);
          q0[m] = __shfl(acc[m][n][0], (lane + 16) & 63, 64);
        }
#pragma unroll
        for (int m = 0; m < MR; ++m) {
          const int rbase = row0 + wr * HA + m * 16 + fq * 4;
          float um1 = (fq == 0) ? ((m > 0) ? p3[m - 1] : 0.f) : p3[m];
          float up1 = (fq == 3) ? ((m < MR - 1) ? q0[m + 1] : 0.f) : q0[m];
#pragma unroll
          for (int j = 0; j < 4; ++j) {
            const int r = rbase + j;
            const int rm = r & 127;
            if (rm == 0 || rm == 127) continue;      // seams -> fixup kernel
            float prv = (j > 0) ? acc[m][n][j - 1] : um1;
            float nxt = (j < 3) ? acc[m][n][j + 1] : up1;
            float av = bb;
            av = __builtin_fmaf(w0, prv, av);
            av = __builtin_fmaf(w1, acc[m][n][j], av);
            av = __builtin_fmaf(w2, nxt, av);
            float s = av / (1.f + __expf(-av));
            ucout[(size_t)r * NB_H + c] = f2b(s);
          }
        }
      }
    }
  } else {
#pragma unroll
    for (int m = 0; m < MR; ++m) {
      const int r = row0 + wr * HA + m * 16 + fq * 4;
#pragma unroll
      for (int n = 0; n < 4; ++n) {
        const int c = col0 + wc * 64 + n * 16 + fr;
#pragma unroll
        for (int j = 0; j < 4; ++j) {
          size_t o = (size_t)(r + j) * ldc + c;
          if (EPI == EPI_F32) outF[o] = acc[m][n][j];
          else                outF[o] = acc[m][n][j] + resid[o];
        }
      }
    }
  }
}

// conv seam fixup: rows with (r & 127) in {0,127}
__global__ void conv_fix_k(const u16* __restrict__ xz, const float* __restrict__ cw,
                           const float* __restrict__ cb, u16* __restrict__ uc) {
  int i = blockIdx.x * 256 + threadIdx.x;   // 128 segs x 256 h-groups
  int h0 = (i & 255) * 8;
  int seg = i >> 8;
  int r = (seg >> 1) * 128 + (seg & 1) * 127;
  int l = r & (NB_L - 1);
  const u16* base = xz + (size_t)r * 4096 + h0;
  u16x8 vm = *reinterpret_cast<const u16x8*>(base);
  u16x8 vq = {}, vp = {};
  if (l > 0)          vq = *reinterpret_cast<const u16x8*>(base - 4096);
  if (l < NB_L - 1)   vp = *reinterpret_cast<const u16x8*>(base + 4096);
  u16x8 o;
#pragma unroll
  for (int j = 0; j < 8; ++j) {
    int h = h0 + j;
    float acc = cb[h];
    acc = __builtin_fmaf(b2f(vq[j]), cw[h * 3 + 0], acc);
    acc = __builtin_fmaf(b2f(vm[j]), cw[h * 3 + 1], acc);
    acc = __builtin_fmaf(b2f(vp[j]), cw[h * 3 + 2], acc);
    float s = acc / (1.f + __expf(-acc));
    o[j] = f2b(s);
  }
  *reinterpret_cast<u16x8*>(uc + (size_t)r * NB_H + h0) = o;
}

// ---------------- legacy 64x64 GEMM (GEMM2: xdbl f32 + dtp bf16) ----------
template <int BM, int BN>
__global__ __launch_bounds__(256)
void gemm2_k(const u16* __restrict__ A, const u16* __restrict__ Bm,
             int K, int ldc, float* __restrict__ outF, u16* __restrict__ dtp) {
  constexpr int MR = BM / 32, NR = BN / 32;
  __shared__ u16 smem[(BM + BN) * 32];
  u16* As = smem;
  u16* Bs = smem + BM * 32;
  const int tid  = threadIdx.x;
  const int lane = tid & 63;
  const int wave = tid >> 6;
  const int wr = wave >> 1, wc = wave & 1;
  const int row0 = blockIdx.x * BM;
  const int col0 = blockIdx.y * BN;
  f32x4 acc[MR][NR] = {};

  const int r_ld = tid >> 2;
  const int kb   = (((tid & 3) ^ ((tid >> 3) & 3)) * 8);
  const size_t a_base = (size_t)(row0 + r_ld) * K + kb;
  const size_t b_base = (size_t)(col0 + r_ld) * K + kb;
  u16* lA = As + tid * 8;
  u16* lB = Bs + tid * 8;

  const int fr = lane & 15;
  const int fq = lane >> 4;
  const int fkx = ((fq ^ ((fr >> 1) & 3)) * 8);

  const int nk = K >> 5;
  for (int kt = 0; kt < nk; ++kt) {
    const int k0 = kt * 32;
    __syncthreads();
#pragma unroll
    for (int hh = 0; hh < BM / 64; ++hh)
      stage16(A + a_base + (size_t)(hh * 64) * K + k0, lA + hh * 64 * 32);
#pragma unroll
    for (int hh = 0; hh < BN / 64; ++hh)
      stage16(Bm + b_base + (size_t)(hh * 64) * K + k0, lB + hh * 64 * 32);
    __syncthreads();
    bf16x8 af[MR], bfr[NR];
#pragma unroll
    for (int m = 0; m < MR; ++m)
      af[m] = *reinterpret_cast<const bf16x8*>(&As[(wr * (BM / 2) + m * 16 + fr) * 32 + fkx]);
#pragma unroll
    for (int n = 0; n < NR; ++n)
      bfr[n] = *reinterpret_cast<const bf16x8*>(&Bs[(wc * (BN / 2) + n * 16 + fr) * 32 + fkx]);
#pragma unroll
    for (int m = 0; m < MR; ++m)
#pragma unroll
      for (int n = 0; n < NR; ++n)
        acc[m][n] = __builtin_amdgcn_mfma_f32_16x16x32_bf16(af[m], bfr[n], acc[m][n], 0, 0, 0);
  }

#pragma unroll
  for (int m = 0; m < MR; ++m) {
    const int r = row0 + wr * (BM / 2) + m * 16 + fq * 4;
#pragma unroll
    for (int n = 0; n < NR; ++n) {
      const int c = col0 + wc * (BN / 2) + n * 16 + fr;
#pragma unroll
      for (int j = 0; j < 4; ++j) {
        float v = acc[m][n][j];
        outF[(size_t)(r + j) * ldc + c] = v;
        if (c < NB_DTR) dtp[(size_t)(r + j) * NB_DTR + c] = f2b(v);
      }
    }
  }
}

// ---------------- chunked selective scan (summaries in bf16) ----------------
__global__ __launch_bounds__(256)
void scan_passA_k(const u16* __restrict__ dt, const u16* __restrict__ uc,
                  const float* __restrict__ xdbl, const float* __restrict__ A_log,
                  u16* __restrict__ dPout, u16* __restrict__ Sout) {
  __shared__ float bc[CLEN][32];
  const int tid = threadIdx.x;
  int idx = blockIdx.x * 256 + tid;   // 4*64*2048
  int h = idx & (NB_H - 1);
  int ck = (idx >> 11) & (NCHUNK - 1);
  int b = idx >> 17;
  const int t0 = b * NB_L + ck * CLEN;
  {
    int r = tid >> 3, q = tid & 7;
    *reinterpret_cast<float4*>(&bc[r][q * 4]) =
        *reinterpret_cast<const float4*>(xdbl + (size_t)(t0 + r) * 128 + 64 + q * 4);
  }
  float An[NB_NS];
#pragma unroll
  for (int n = 0; n < NB_NS; ++n) An[n] = -__expf(A_log[n]);
  float P[NB_NS], S[NB_NS];
#pragma unroll
  for (int n = 0; n < NB_NS; ++n) { P[n] = 1.f; S[n] = 0.f; }
  __syncthreads();
  const u16* up = uc + (size_t)t0 * NB_H + h;
  const u16* dp = dt + (size_t)t0 * NB_H + h;
  float uA = b2f(up[0]),       dA = b2f(dp[0]);
  float uB = b2f(up[NB_H]),    dB = b2f(dp[NB_H]);
  for (int tt = 0; tt < CLEN; ++tt) {
    float uC = 0.f, dC = 0.f;
    if (tt + 2 < CLEN) { uC = b2f(up[2 * NB_H]); dC = b2f(dp[2 * NB_H]); }
    up += NB_H; dp += NB_H;
    float4 B0 = *reinterpret_cast<const float4*>(&bc[tt][0]);
    float4 B1 = *reinterpret_cast<const float4*>(&bc[tt][4]);
    float4 B2 = *reinterpret_cast<const float4*>(&bc[tt][8]);
    float4 B3 = *reinterpret_cast<const float4*>(&bc[tt][12]);
    const float Bf[NB_NS] = {B0.x, B0.y, B0.z, B0.w, B1.x, B1.y, B1.z, B1.w,
                             B2.x, B2.y, B2.z, B2.w, B3.x, B3.y, B3.z, B3.w};
#pragma unroll
    for (int n = 0; n < NB_NS; ++n) {
      float e = exp_small(dA * An[n]);
      P[n] *= e;
      S[n] = __builtin_fmaf(e, S[n], Bf[n] * uA);
    }
    uA = uB; dA = dB; uB = uC; dB = dC;
  }
#pragma unroll
  for (int n = 0; n < NB_NS; ++n) {
    size_t o = ((((size_t)b * NCHUNK + ck) * NB_NS + n) * NB_H + h);
    dPout[o] = f2b(1.0f - P[n]);
    Sout[o]  = f2b(S[n]);
  }
}

__global__ void scan_passB_k(u16* __restrict__ dP, const u16* __restrict__ S) {
  int idx = blockIdx.x * 256 + threadIdx.x;   // 4*16*2048
  int h = idx & (NB_H - 1);
  int n = (idx >> 11) & (NB_NS - 1);
  int b = idx >> 15;
  const size_t stride = (size_t)NB_NS * NB_H;
  size_t o = ((size_t)b * NCHUNK * NB_NS + n) * NB_H + h;
  float hs = 0.f;
  float p0 = 1.f - b2f(dP[o]), s0 = b2f(S[o]);
  for (int ck = 0; ck < NCHUNK; ++ck) {
    float p1 = 1.f, s1 = 0.f;
    if (ck + 1 < NCHUNK) { p1 = 1.f - b2f(dP[o + stride]); s1 = b2f(S[o + stride]); }
    dP[o] = f2b(hs);                 // Hst
    hs = __builtin_fmaf(p0, hs, s0);
    o += stride; p0 = p1; s0 = s1;
  }
}

__global__ __launch_bounds__(256)
void scan_passC_k(const u16* __restrict__ dt, const u16* __restrict__ uc,
                  const float* __restrict__ xdbl, const u16* __restrict__ xz,
                  const float* __restrict__ A_log, const float* __restrict__ Dp,
                  const u16* __restrict__ Hst, u16* __restrict__ ybf) {
  __shared__ float bc[CLEN][32];
  const int tid = threadIdx.x;
  int idx = blockIdx.x * 256 + tid;   // 4*64*2048
  int h = idx & (NB_H - 1);
  int ck = (idx >> 11) & (NCHUNK - 1);
  int b = idx >> 17;
  const int t0 = b * NB_L + ck * CLEN;
  {
    int r = tid >> 3, q = tid & 7;
    *reinterpret_cast<float4*>(&bc[r][q * 4]) =
        *reinterpret_cast<const float4*>(xdbl + (size_t)(t0 + r) * 128 + 64 + q * 4);
  }
  float An[NB_NS];
#pragma unroll
  for (int n = 0; n < NB_NS; ++n) An[n] = -__expf(A_log[n]);
  float s[NB_NS];
#pragma unroll
  for (int n = 0; n < NB_NS; ++n)
    s[n] = b2f(Hst[((((size_t)b * NCHUNK + ck) * NB_NS + n) * NB_H + h)]);
  const float Dh = Dp[h];
  __syncthreads();
  const u16* up = uc + (size_t)t0 * NB_H + h;
  const u16* dp = dt + (size_t)t0 * NB_H + h;
  const u16* zp = xz + (size_t)t0 * 4096 + NB_H + h;   // holds silu(z) already
  u16* yp = ybf + (size_t)t0 * NB_H + h;
  float uA = b2f(up[0]),    dA = b2f(dp[0]),    zA = b2f(zp[0]);
  float uB = b2f(up[NB_H]), dB = b2f(dp[NB_H]), zB = b2f(zp[4096]);
  for (int tt = 0; tt < CLEN; ++tt) {
    float uC = 0.f, dC = 0.f, zC = 0.f;
    if (tt + 2 < CLEN) {
      uC = b2f(up[2 * NB_H]); dC = b2f(dp[2 * NB_H]); zC = b2f(zp[2 * 4096]);
    }
    up += NB_H; dp += NB_H; zp += 4096;
    float4 B0 = *reinterpret_cast<const float4*>(&bc[tt][0]);
    float4 B1 = *reinterpret_cast<const float4*>(&bc[tt][4]);
    float4 B2 = *reinterpret_cast<const float4*>(&bc[tt][8]);
    float4 B3 = *reinterpret_cast<const float4*>(&bc[tt][12]);
    float4 C0 = *reinterpret_cast<const float4*>(&bc[tt][16]);
    float4 C1 = *reinterpret_cast<const float4*>(&bc[tt][20]);
    float4 C2 = *reinterpret_cast<const float4*>(&bc[tt][24]);
    float4 C3 = *reinterpret_cast<const float4*>(&bc[tt][28]);
    const float Bf[NB_NS] = {B0.x, B0.y, B0.z, B0.w, B1.x, B1.y, B1.z, B1.w,
                             B2.x, B2.y, B2.z, B2.w, B3.x, B3.y, B3.z, B3.w};
    const float Cf[NB_NS] = {C0.x, C0.y, C0.z, C0.w, C1.x, C1.y, C1.z, C1.w,
                             C2.x, C2.y, C2.z, C2.w, C3.x, C3.y, C3.z, C3.w};
    float y = 0.f;
#pragma unroll
    for (int n = 0; n < NB_NS; ++n) {
      float e = exp_small(dA * An[n]);
      s[n] = __builtin_fmaf(e, s[n], Bf[n] * uA);
      y = __builtin_fmaf(Cf[n], s[n], y);
    }
    float v = __builtin_fmaf(Dh, uA, y);
    *yp = f2b(v * zA);               // zA = silu(z) precomputed in GEMM1
    yp += NB_H;
    uA = uB; dA = dB; zA = zB; uB = uC; dB = dC; zB = zC;
  }
}

// ---------------- launcher ----------------
extern "C" void kernel_launch(void* const* d_in, const int* in_sizes, int n_in,
                              void* d_out, int out_size, void* d_ws, size_t ws_size,
                              hipStream_t stream) {
  const float* x      = (const float*)d_in[0];
  const float* W_in   = (const float*)d_in[1];
  const float* conv_w = (const float*)d_in[2];
  const float* conv_b = (const float*)d_in[3];
  const float* W_xprj = (const float*)d_in[4];
  const float* W_dt   = (const float*)d_in[5];
  const float* b_dt   = (const float*)d_in[6];
  const float* A_log  = (const float*)d_in[7];
  const float* Dp     = (const float*)d_in[8];
  const float* W_out  = (const float*)d_in[9];
  float* out = (float*)d_out;

  char* ws = (char*)d_ws;
  size_t off = 0;
  auto alloc = [&](size_t bytes) {
    void* p = ws + off;
    off += (bytes + 255) & ~(size_t)255;
    return p;
  };
  u16*   xz_b   = (u16*)alloc((size_t)NB_TOK * 4096 * 2);     // 64MB (u raw | silu z)
  u16*   x_b    = (u16*)alloc((size_t)NB_TOK * NB_DIM * 2);   // 16MB
  u16*   win_b  = (u16*)alloc((size_t)4096 * NB_DIM * 2);     // 8MB
  u16*   wxp_b  = (u16*)alloc((size_t)128 * NB_H * 2);        // 512KB
  u16*   wdt_b  = (u16*)alloc((size_t)NB_H * NB_DTR * 2);     // 256KB
  u16*   wout_b = (u16*)alloc((size_t)NB_DIM * NB_H * 2);     // 4MB
  u16*   uc_b   = (u16*)alloc((size_t)NB_TOK * NB_H * 2);     // 32MB
  float* xdbl   = (float*)alloc((size_t)NB_TOK * 128 * 4);    // 4MB
  u16*   dtp_b  = (u16*)alloc((size_t)NB_TOK * NB_DTR * 2);   // 1MB
  u16*   dt_b   = (u16*)alloc((size_t)NB_TOK * NB_H * 2);     // 32MB
  u16*   scdP   = (u16*)alloc((size_t)NB_B * NCHUNK * NB_NS * NB_H * 2); // 16MB (dP -> Hst)
  u16*   scS    = (u16*)alloc((size_t)NB_B * NCHUNK * NB_NS * NB_H * 2); // 16MB
  u16*   y_b    = (u16*)alloc((size_t)NB_TOK * NB_H * 2);     // 32MB
  (void)ws_size; (void)in_sizes; (void)n_in; (void)out_size;

  cvt_all_k<<<(CVT_N5 + 255) / 256, 256, 0, stream>>>(
      x, W_in, W_dt, W_out, W_xprj, x_b, win_b, wdt_b, wout_b, wxp_b);

  // GEMM1: xz = x @ W_in^T + fused conv/silu (tiles 32x16, XCD chunks 8x8)
  gemm8p_k<EPI_CONV, 256><<<512, 512, 0, stream>>>(
      x_b, win_b, NB_DIM, 4096, xz_b, nullptr, nullptr, nullptr,
      conv_w, conv_b, uc_b, 8, 8, 2);

  conv_fix_k<<<128, 256, 0, stream>>>(xz_b, conv_w, conv_b, uc_b);

  // GEMM2: x_dbl = uc @ W_xproj^T -> f32 + dtp bf16
  gemm2_k<64, 64><<<dim3(128, 2), 256, 0, stream>>>(
      uc_b, wxp_b, NB_H, 128, xdbl, dtp_b);

  // GEMM3: dt = softplus(dtp @ W_dt^T + b_dt)  (tiles 32x8, chunks 4x8)
  gemm8p_k<EPI_SP_BF16, 256><<<256, 512, 0, stream>>>(
      dtp_b, wdt_b, NB_DTR, NB_H, dt_b, nullptr, b_dt, nullptr,
      nullptr, nullptr, nullptr, 4, 8, 1);

  scan_passA_k<<<(NB_B * NCHUNK * NB_H) / 256, 256, 0, stream>>>(dt_b, uc_b, xdbl, A_log, scdP, scS);
  scan_passB_k<<<(NB_B * NB_NS * NB_H) / 256, 256, 0, stream>>>(scdP, scS);
  scan_passC_k<<<(NB_B * NCHUNK * NB_H) / 256, 256, 0, stream>>>(dt_b, uc_b, xdbl, xz_b, A_log, Dp, scdP, y_b);

  // GEMM4: out = y @ W_out^T + x  (tiles 64x4, BM=128, chunks 8x4)
  gemm8p_k<EPI_RES_F32, 128><<<256, 512, 0, stream>>>(
      y_b, wout_b, NB_H, NB_DIM, nullptr, out, nullptr, x,
      nullptr, nullptr, nullptr, 8, 4, 1);
}

// Round 9
// 405.544 us; speedup vs baseline: 1.0260x; 1.0260x over previous
//
#include <hip/hip_runtime.h>
#include <cmath>

typedef unsigned short u16;
typedef __bf16 bf16x8 __attribute__((ext_vector_type(8)));
typedef float f32x4 __attribute__((ext_vector_type(4)));
typedef unsigned short u16x8 __attribute__((ext_vector_type(8)));

#define NB_B   4
#define NB_L   2048
#define NB_DIM 1024
#define NB_H   2048
#define NB_NS  16
#define NB_DTR 64
#define NB_TOK (NB_B * NB_L)   // 8192
#define NCHUNK 64
#define CLEN   32              // NB_L / NCHUNK

__device__ __forceinline__ u16 f2b(float f) {
  union { float f; unsigned u; } v; v.f = f;
  unsigned r = v.u + 0x7fffu + ((v.u >> 16) & 1u);
  return (u16)(r >> 16);
}
__device__ __forceinline__ float b2f(u16 h) {
  union { unsigned u; float f; } v; v.u = ((unsigned)h) << 16;
  return v.f;
}
// exp(w) for |w| <= ~2e-4 here: 1 + w + w^2/2, err ~ |w|^3/6
__device__ __forceinline__ float exp_small(float w) {
  return __builtin_fmaf(w, __builtin_fmaf(w, 0.5f, 1.0f), 1.0f);
}

// ---------------- fused converts (x, W_in, W_dt, W_out, W_xproj+pad) --------
#define CVT_N0 2097152                      // x          f4
#define CVT_N1 (CVT_N0 + 1048576)           // W_in       f4
#define CVT_N2 (CVT_N1 + 32768)             // W_dt       f4
#define CVT_N3 (CVT_N2 + 524288)            // W_out      f4
#define CVT_N4 (CVT_N3 + 49152)             // W_xproj    f4 (96*2048/4)
#define CVT_N5 (CVT_N4 + 8192)              // xproj pad  u16x8 (32*2048/8)
__global__ void cvt_all_k(const float* __restrict__ x, const float* __restrict__ W_in,
                          const float* __restrict__ W_dt, const float* __restrict__ W_out,
                          const float* __restrict__ W_xp,
                          u16* __restrict__ xb, u16* __restrict__ winb,
                          u16* __restrict__ wdtb, u16* __restrict__ woutb,
                          u16* __restrict__ wxpb) {
  int i = blockIdx.x * 256 + threadIdx.x;
  if (i >= CVT_N5) return;
  if (i >= CVT_N4) {   // zero pad rows 96..127 of wxp
    int q = i - CVT_N4;
    u16x8 z = {};
    *reinterpret_cast<u16x8*>(wxpb + 96 * 2048 + q * 8) = z;
    return;
  }
  const float* src; u16* dst; int off;
  if (i < CVT_N0)      { src = x;     dst = xb;    off = i; }
  else if (i < CVT_N1) { src = W_in;  dst = winb;  off = i - CVT_N0; }
  else if (i < CVT_N2) { src = W_dt;  dst = wdtb;  off = i - CVT_N1; }
  else if (i < CVT_N3) { src = W_out; dst = woutb; off = i - CVT_N2; }
  else                 { src = W_xp;  dst = wxpb;  off = i - CVT_N3; }
  float4 v = reinterpret_cast<const float4*>(src)[off];
  ushort4 o;
  o.x = f2b(v.x); o.y = f2b(v.y); o.z = f2b(v.z); o.w = f2b(v.w);
  reinterpret_cast<ushort4*>(dst)[off] = o;
}

#define EPI_CONV    0   // GEMM1: xz store (u raw / silu z) + fused dwconv->uc
#define EPI_F32     1   // GEMM2
#define EPI_SP_BF16 2   // GEMM3: softplus
#define EPI_RES_F32 3   // GEMM4: +residual f32

__device__ __forceinline__ void stage16(const u16* g, u16* l) {
  __builtin_amdgcn_global_load_lds(
      (const __attribute__((address_space(1))) unsigned int*)g,
      (__attribute__((address_space(3))) unsigned int*)l, 16, 0, 0);
}

// ============ 2-barrier/K-tile pipelined GEMM (BK=64, BN=256) ==============
// C = A(MxK)*B(NxK)^T bf16. 512 thr = 8 waves (2x4), wave tile (BM/2)x64.
// Double-buffered LDS; tile kt+2's B staged at P1, A staged at P4 after the
// mid-barrier. Counted vmcnt(4) at P4 lands tile kt+1 while kt+2-B stays in
// flight. XOR k-slot swizzle both-sides. Staging addresses hoisted.
// EPI_CONV epilogue: xz via LDS bounce (coalesced u16x8); fused dwconv+silu
// computed from f32 acc (shfl for cross-fq rows), also via LDS bounce to a
// DISJOINT region -> coalesced stores (round-8's scalar-scatter was 2x cost).
template <int EPI, int BM>
__global__ __launch_bounds__(512, 1)
void gemm8p_k(const u16* __restrict__ A, const u16* __restrict__ Bm,
              int K, int ldc,
              u16* __restrict__ outB, float* __restrict__ outF,
              const float* __restrict__ bias, const float* __restrict__ resid,
              const float* __restrict__ cw, const float* __restrict__ cb,
              u16* __restrict__ ucout,
              int cr, int cc, int ncx) {
  constexpr int MR = BM / 32;
  constexpr int MH = MR / 2;
  constexpr int HA = BM / 2;
  constexpr int LA = BM / 128;           // A gloads per thread per half
  constexpr int PRO = 2 * LA + 4;        // gloads per thread per K-tile
  constexpr int BUFE = (BM + 256) * 64;
  __shared__ u16 smem[2 * BUFE];

  const int tid  = threadIdx.x;
  const int lane = tid & 63;
  const int wave = tid >> 6;
  const int wr = wave >> 2, wc = wave & 3;
  const int fr = lane & 15, fq = lane >> 4;

  const int bid = blockIdx.x;
  const int e = bid & 7, w = bid >> 3;
  const int row0 = ((e / ncx) * cr + (w % cr)) * BM;
  const int col0 = ((e % ncx) * cc + (w / cr)) * 256;

  f32x4 acc[MR][4] = {};
  bf16x8 bB[4][2], bA0[MH][2], bA1[MH][2];

  // hoisted staging addresses
  const u16* gB[4]; int lBoff[4];
  const u16* gA[2 * LA]; int lAoff[2 * LA];
  {
#pragma unroll
    for (int h = 0; h < 2; ++h)
#pragma unroll
      for (int l = 0; l < 2; ++l) {
        int cc2 = l * 512 + tid; int ri = cc2 >> 3; int pp = cc2 & 7;
        gB[h * 2 + l] = Bm + (size_t)(col0 + h * 128 + ri) * K + ((pp ^ (ri & 7)) * 8);
        lBoff[h * 2 + l] = BM * 64 + (h * 128 + ri) * 64 + pp * 8;
      }
#pragma unroll
    for (int h = 0; h < 2; ++h)
#pragma unroll
      for (int l = 0; l < LA; ++l) {
        int cc2 = l * 512 + tid; int ri = cc2 >> 3; int pp = cc2 & 7;
        gA[h * LA + l] = A + (size_t)(row0 + h * HA + ri) * K + ((pp ^ (ri & 7)) * 8);
        lAoff[h * LA + l] = (h * HA + ri) * 64 + pp * 8;
      }
  }
  // hoisted fragment read offsets (u16 units)
  int offA[MR][2], offB[4][2];
#pragma unroll
  for (int m = 0; m < MR; ++m) {
    int rt = wr * HA + m * 16 + fr;
#pragma unroll
    for (int kk = 0; kk < 2; ++kk)
      offA[m][kk] = rt * 64 + (((kk * 4 + fq) ^ (rt & 7)) * 8);
  }
#pragma unroll
  for (int n = 0; n < 4; ++n) {
    int rt = wc * 64 + n * 16 + fr;
#pragma unroll
    for (int kk = 0; kk < 2; ++kk)
      offB[n][kk] = BM * 64 + rt * 64 + (((kk * 4 + fq) ^ (rt & 7)) * 8);
  }

  auto STAGE_B = [&](int kt) {
    const int ko = kt * 64;
    u16* base = smem + (kt & 1) * BUFE;
#pragma unroll
    for (int q = 0; q < 4; ++q) stage16(gB[q] + ko, base + lBoff[q]);
  };
  auto STAGE_A = [&](int kt) {
    const int ko = kt * 64;
    u16* base = smem + (kt & 1) * BUFE;
#pragma unroll
    for (int q = 0; q < 2 * LA; ++q) stage16(gA[q] + ko, base + lAoff[q]);
  };
  auto LD_A = [&](int m, int kk, int bi) {
    return *reinterpret_cast<const bf16x8*>(smem + bi * BUFE + offA[m][kk]);
  };
  auto LD_B = [&](int n, int kk, int bi) {
    return *reinterpret_cast<const bf16x8*>(smem + bi * BUFE + offB[n][kk]);
  };

  const int nk = K >> 6;
  // ---- prologue
  STAGE_B(0); STAGE_A(0);
  if (nk > 1) { STAGE_B(1); STAGE_A(1); }
  if (nk > 1) asm volatile("s_waitcnt vmcnt(%0)" :: "i"(PRO) : "memory");
  else        asm volatile("s_waitcnt vmcnt(0)" ::: "memory");
  __builtin_amdgcn_s_barrier();
  __builtin_amdgcn_sched_barrier(0);
#pragma unroll
  for (int n = 0; n < 4; ++n) { bB[n][0] = LD_B(n, 0, 0); bB[n][1] = LD_B(n, 1, 0); }
#pragma unroll
  for (int m = 0; m < MH; ++m) { bA0[m][0] = LD_A(m, 0, 0); bA0[m][1] = LD_A(m, 1, 0); }
  asm volatile("s_waitcnt lgkmcnt(0)" ::: "memory");
  __builtin_amdgcn_s_barrier();
  __builtin_amdgcn_sched_barrier(0);

  for (int kt = 0; kt < nk; ++kt) {
    const int bi = kt & 1;
    // P1: stage B(kt+2) | Q00
    if (kt + 2 < nk) STAGE_B(kt + 2);
    __builtin_amdgcn_s_setprio(1);
#pragma unroll
    for (int m = 0; m < MH; ++m)
#pragma unroll
      for (int n = 0; n < 2; ++n)
#pragma unroll
        for (int kk = 0; kk < 2; ++kk)
          acc[m][n] = __builtin_amdgcn_mfma_f32_16x16x32_bf16(bA0[m][kk], bB[n][kk], acc[m][n], 0, 0, 0);
    __builtin_amdgcn_s_setprio(0);
    __builtin_amdgcn_sched_barrier(0);
    // P2: read A-mh1 | Q01
#pragma unroll
    for (int m = 0; m < MH; ++m) { bA1[m][0] = LD_A(MH + m, 0, bi); bA1[m][1] = LD_A(MH + m, 1, bi); }
    __builtin_amdgcn_s_setprio(1);
#pragma unroll
    for (int m = 0; m < MH; ++m)
#pragma unroll
      for (int n = 2; n < 4; ++n)
#pragma unroll
        for (int kk = 0; kk < 2; ++kk)
          acc[m][n] = __builtin_amdgcn_mfma_f32_16x16x32_bf16(bA0[m][kk], bB[n][kk], acc[m][n], 0, 0, 0);
    __builtin_amdgcn_s_setprio(0);
    __builtin_amdgcn_sched_barrier(0);
    // P3: wait A-mh1 | Q10
    asm volatile("s_waitcnt lgkmcnt(0)" ::: "memory");
    __builtin_amdgcn_sched_barrier(0);
    __builtin_amdgcn_s_setprio(1);
#pragma unroll
    for (int m = 0; m < MH; ++m)
#pragma unroll
      for (int n = 0; n < 2; ++n)
#pragma unroll
        for (int kk = 0; kk < 2; ++kk)
          acc[MH + m][n] = __builtin_amdgcn_mfma_f32_16x16x32_bf16(bA1[m][kk], bB[n][kk], acc[MH + m][n], 0, 0, 0);
    __builtin_amdgcn_s_setprio(0);
    __builtin_amdgcn_sched_barrier(0);
    // P4: land kt+1; stage A(kt+2); pre-read next tile | Q11
    if (kt + 1 < nk) {
      if (kt + 2 < nk) asm volatile("s_waitcnt vmcnt(4)" ::: "memory");
      else             asm volatile("s_waitcnt vmcnt(0)" ::: "memory");
      __builtin_amdgcn_s_barrier();
      __builtin_amdgcn_sched_barrier(0);
      if (kt + 2 < nk) STAGE_A(kt + 2);
#pragma unroll
      for (int n = 0; n < 2; ++n) { bB[n][0] = LD_B(n, 0, bi ^ 1); bB[n][1] = LD_B(n, 1, bi ^ 1); }
#pragma unroll
      for (int m = 0; m < MH; ++m) { bA0[m][0] = LD_A(m, 0, bi ^ 1); bA0[m][1] = LD_A(m, 1, bi ^ 1); }
    }
    __builtin_amdgcn_s_setprio(1);
#pragma unroll
    for (int m = 0; m < MH; ++m)
#pragma unroll
      for (int n = 2; n < 4; ++n)
#pragma unroll
        for (int kk = 0; kk < 2; ++kk)
          acc[MH + m][n] = __builtin_amdgcn_mfma_f32_16x16x32_bf16(bA1[m][kk], bB[n][kk], acc[MH + m][n], 0, 0, 0);
    __builtin_amdgcn_s_setprio(0);
    if (kt + 1 < nk) {
#pragma unroll
      for (int n = 2; n < 4; ++n) { bB[n][0] = LD_B(n, 0, bi ^ 1); bB[n][1] = LD_B(n, 1, bi ^ 1); }
    }
    asm volatile("s_waitcnt lgkmcnt(0)" ::: "memory");
    __builtin_amdgcn_s_barrier();
    __builtin_amdgcn_sched_barrier(0);
  }

  // ---------------- epilogues ----------------
  if constexpr (EPI == EPI_CONV || EPI == EPI_SP_BF16) {
    const bool zblk = (EPI == EPI_CONV) && (col0 >= NB_H);
    u16* wv = smem + wave * 1152;   // 16 x 72 u16 per wave (bank-balanced)
#pragma unroll
    for (int m = 0; m < MR; ++m) {
#pragma unroll
      for (int n = 0; n < 4; ++n) {
        const int c = col0 + wc * 64 + n * 16 + fr;
        float bv = (EPI == EPI_SP_BF16) ? bias[c] : 0.f;
#pragma unroll
        for (int j = 0; j < 4; ++j) {
          float v = acc[m][n][j];
          if (EPI == EPI_SP_BF16) {
            float xx = v + bv;
            float t = __expf(xx);
            float sp = (xx > -5.f) ? log1pf(t) : t;
            v = (xx > 20.f) ? xx : sp;
          } else if (zblk) {
            v = v / (1.f + __expf(-v));     // store silu(z)
          }
          wv[(fq * 4 + j) * 72 + n * 16 + fr] = f2b(v);
        }
      }
#pragma unroll
      for (int p = 0; p < 2; ++p) {
        const int rf = p * 8 + (lane >> 3);
        const int c0 = (lane & 7) * 8;
        u16x8 ov = *reinterpret_cast<const u16x8*>(wv + rf * 72 + c0);
        const int grow = row0 + wr * HA + m * 16 + rf;
        const int gcol = col0 + wc * 64 + c0;
        *reinterpret_cast<u16x8*>(&outB[(size_t)grow * ldc + gcol]) = ov;
      }
    }
    // fused depthwise conv (k=3) + silu -> uc (u-blocks only), from f32 acc.
    // Seam rows (r&127 in {0,127}) get placeholder values; conv_fix_k
    // overwrites them afterwards. Bounce via DISJOINT LDS region -> coalesced.
    if (EPI == EPI_CONV && !zblk) {
      u16* wv2 = smem + 8 * 1152 + wave * 1152;
#pragma unroll
      for (int m = 0; m < MR; ++m) {
#pragma unroll
        for (int n = 0; n < 4; ++n) {
          const int c = col0 + wc * 64 + n * 16 + fr;
          const float w0 = cw[c * 3 + 0], w1 = cw[c * 3 + 1], w2 = cw[c * 3 + 2];
          const float bb = cb[c];
          float p3m  = __shfl(acc[m][n][3], (lane + 48) & 63, 64);
          float q0m  = __shfl(acc[m][n][0], (lane + 16) & 63, 64);
          float p3m1 = __shfl((m > 0)      ? acc[m - 1][n][3] : 0.f, (lane + 48) & 63, 64);
          float q0m1 = __shfl((m < MR - 1) ? acc[m + 1][n][0] : 0.f, (lane + 16) & 63, 64);
          const float um1 = (fq == 0) ? p3m1 : p3m;
          const float up1 = (fq == 3) ? q0m1 : q0m;
#pragma unroll
          for (int j = 0; j < 4; ++j) {
            float prv = (j > 0) ? acc[m][n][j - 1] : um1;
            float nxt = (j < 3) ? acc[m][n][j + 1] : up1;
            float av = bb;
            av = __builtin_fmaf(w0, prv, av);
            av = __builtin_fmaf(w1, acc[m][n][j], av);
            av = __builtin_fmaf(w2, nxt, av);
            float s = av / (1.f + __expf(-av));
            wv2[(fq * 4 + j) * 72 + n * 16 + fr] = f2b(s);
          }
        }
#pragma unroll
        for (int p = 0; p < 2; ++p) {
          const int rf = p * 8 + (lane >> 3);
          const int c0 = (lane & 7) * 8;
          u16x8 ov = *reinterpret_cast<const u16x8*>(wv2 + rf * 72 + c0);
          const int grow = row0 + wr * HA + m * 16 + rf;
          const int gcol = col0 + wc * 64 + c0;
          *reinterpret_cast<u16x8*>(&ucout[(size_t)grow * NB_H + gcol]) = ov;
        }
      }
    }
  } else {
#pragma unroll
    for (int m = 0; m < MR; ++m) {
      const int r = row0 + wr * HA + m * 16 + fq * 4;
#pragma unroll
      for (int n = 0; n < 4; ++n) {
        const int c = col0 + wc * 64 + n * 16 + fr;
#pragma unroll
        for (int j = 0; j < 4; ++j) {
          size_t o = (size_t)(r + j) * ldc + c;
          if (EPI == EPI_F32) outF[o] = acc[m][n][j];
          else                outF[o] = acc[m][n][j] + resid[o];
        }
      }
    }
  }
}

// conv seam fixup: rows with (r & 127) in {0,127}
__global__ void conv_fix_k(const u16* __restrict__ xz, const float* __restrict__ cw,
                           const float* __restrict__ cb, u16* __restrict__ uc) {
  int i = blockIdx.x * 256 + threadIdx.x;   // 128 segs x 256 h-groups
  int h0 = (i & 255) * 8;
  int seg = i >> 8;
  int r = (seg >> 1) * 128 + (seg & 1) * 127;
  int l = r & (NB_L - 1);
  const u16* base = xz + (size_t)r * 4096 + h0;
  u16x8 vm = *reinterpret_cast<const u16x8*>(base);
  u16x8 vq = {}, vp = {};
  if (l > 0)          vq = *reinterpret_cast<const u16x8*>(base - 4096);
  if (l < NB_L - 1)   vp = *reinterpret_cast<const u16x8*>(base + 4096);
  u16x8 o;
#pragma unroll
  for (int j = 0; j < 8; ++j) {
    int h = h0 + j;
    float acc = cb[h];
    acc = __builtin_fmaf(b2f(vq[j]), cw[h * 3 + 0], acc);
    acc = __builtin_fmaf(b2f(vm[j]), cw[h * 3 + 1], acc);
    acc = __builtin_fmaf(b2f(vp[j]), cw[h * 3 + 2], acc);
    float s = acc / (1.f + __expf(-acc));
    o[j] = f2b(s);
  }
  *reinterpret_cast<u16x8*>(uc + (size_t)r * NB_H + h0) = o;
}

// ---------------- legacy 64x64 GEMM (GEMM2: xdbl f32 + dtp bf16) ----------
template <int BM, int BN>
__global__ __launch_bounds__(256)
void gemm2_k(const u16* __restrict__ A, const u16* __restrict__ Bm,
             int K, int ldc, float* __restrict__ outF, u16* __restrict__ dtp) {
  constexpr int MR = BM / 32, NR = BN / 32;
  __shared__ u16 smem[(BM + BN) * 32];
  u16* As = smem;
  u16* Bs = smem + BM * 32;
  const int tid  = threadIdx.x;
  const int lane = tid & 63;
  const int wave = tid >> 6;
  const int wr = wave >> 1, wc = wave & 1;
  const int row0 = blockIdx.x * BM;
  const int col0 = blockIdx.y * BN;
  f32x4 acc[MR][NR] = {};

  const int r_ld = tid >> 2;
  const int kb   = (((tid & 3) ^ ((tid >> 3) & 3)) * 8);
  const size_t a_base = (size_t)(row0 + r_ld) * K + kb;
  const size_t b_base = (size_t)(col0 + r_ld) * K + kb;
  u16* lA = As + tid * 8;
  u16* lB = Bs + tid * 8;

  const int fr = lane & 15;
  const int fq = lane >> 4;
  const int fkx = ((fq ^ ((fr >> 1) & 3)) * 8);

  const int nk = K >> 5;
  for (int kt = 0; kt < nk; ++kt) {
    const int k0 = kt * 32;
    __syncthreads();
#pragma unroll
    for (int hh = 0; hh < BM / 64; ++hh)
      stage16(A + a_base + (size_t)(hh * 64) * K + k0, lA + hh * 64 * 32);
#pragma unroll
    for (int hh = 0; hh < BN / 64; ++hh)
      stage16(Bm + b_base + (size_t)(hh * 64) * K + k0, lB + hh * 64 * 32);
    __syncthreads();
    bf16x8 af[MR], bfr[NR];
#pragma unroll
    for (int m = 0; m < MR; ++m)
      af[m] = *reinterpret_cast<const bf16x8*>(&As[(wr * (BM / 2) + m * 16 + fr) * 32 + fkx]);
#pragma unroll
    for (int n = 0; n < NR; ++n)
      bfr[n] = *reinterpret_cast<const bf16x8*>(&Bs[(wc * (BN / 2) + n * 16 + fr) * 32 + fkx]);
#pragma unroll
    for (int m = 0; m < MR; ++m)
#pragma unroll
      for (int n = 0; n < NR; ++n)
        acc[m][n] = __builtin_amdgcn_mfma_f32_16x16x32_bf16(af[m], bfr[n], acc[m][n], 0, 0, 0);
  }

#pragma unroll
  for (int m = 0; m < MR; ++m) {
    const int r = row0 + wr * (BM / 2) + m * 16 + fq * 4;
#pragma unroll
    for (int n = 0; n < NR; ++n) {
      const int c = col0 + wc * (BN / 2) + n * 16 + fr;
#pragma unroll
      for (int j = 0; j < 4; ++j) {
        float v = acc[m][n][j];
        outF[(size_t)(r + j) * ldc + c] = v;
        if (c < NB_DTR) dtp[(size_t)(r + j) * NB_DTR + c] = f2b(v);
      }
    }
  }
}

// ---------------- chunked selective scan (summaries in bf16) ----------------
__global__ __launch_bounds__(256)
void scan_passA_k(const u16* __restrict__ dt, const u16* __restrict__ uc,
                  const float* __restrict__ xdbl, const float* __restrict__ A_log,
                  u16* __restrict__ dPout, u16* __restrict__ Sout) {
  __shared__ float bc[CLEN][32];
  const int tid = threadIdx.x;
  int idx = blockIdx.x * 256 + tid;   // 4*64*2048
  int h = idx & (NB_H - 1);
  int ck = (idx >> 11) & (NCHUNK - 1);
  int b = idx >> 17;
  const int t0 = b * NB_L + ck * CLEN;
  {
    int r = tid >> 3, q = tid & 7;
    *reinterpret_cast<float4*>(&bc[r][q * 4]) =
        *reinterpret_cast<const float4*>(xdbl + (size_t)(t0 + r) * 128 + 64 + q * 4);
  }
  float An[NB_NS];
#pragma unroll
  for (int n = 0; n < NB_NS; ++n) An[n] = -__expf(A_log[n]);
  float P[NB_NS], S[NB_NS];
#pragma unroll
  for (int n = 0; n < NB_NS; ++n) { P[n] = 1.f; S[n] = 0.f; }
  __syncthreads();
  const u16* up = uc + (size_t)t0 * NB_H + h;
  const u16* dp = dt + (size_t)t0 * NB_H + h;
  float uA = b2f(up[0]),       dA = b2f(dp[0]);
  float uB = b2f(up[NB_H]),    dB = b2f(dp[NB_H]);
  for (int tt = 0; tt < CLEN; ++tt) {
    float uC = 0.f, dC = 0.f;
    if (tt + 2 < CLEN) { uC = b2f(up[2 * NB_H]); dC = b2f(dp[2 * NB_H]); }
    up += NB_H; dp += NB_H;
    float4 B0 = *reinterpret_cast<const float4*>(&bc[tt][0]);
    float4 B1 = *reinterpret_cast<const float4*>(&bc[tt][4]);
    float4 B2 = *reinterpret_cast<const float4*>(&bc[tt][8]);
    float4 B3 = *reinterpret_cast<const float4*>(&bc[tt][12]);
    const float Bf[NB_NS] = {B0.x, B0.y, B0.z, B0.w, B1.x, B1.y, B1.z, B1.w,
                             B2.x, B2.y, B2.z, B2.w, B3.x, B3.y, B3.z, B3.w};
#pragma unroll
    for (int n = 0; n < NB_NS; ++n) {
      float e = exp_small(dA * An[n]);
      P[n] *= e;
      S[n] = __builtin_fmaf(e, S[n], Bf[n] * uA);
    }
    uA = uB; dA = dB; uB = uC; dB = dC;
  }
#pragma unroll
  for (int n = 0; n < NB_NS; ++n) {
    size_t o = ((((size_t)b * NCHUNK + ck) * NB_NS + n) * NB_H + h);
    dPout[o] = f2b(1.0f - P[n]);
    Sout[o]  = f2b(S[n]);
  }
}

__global__ void scan_passB_k(u16* __restrict__ dP, const u16* __restrict__ S) {
  int idx = blockIdx.x * 256 + threadIdx.x;   // 4*16*2048
  int h = idx & (NB_H - 1);
  int n = (idx >> 11) & (NB_NS - 1);
  int b = idx >> 15;
  const size_t stride = (size_t)NB_NS * NB_H;
  size_t o = ((size_t)b * NCHUNK * NB_NS + n) * NB_H + h;
  float hs = 0.f;
  float p0 = 1.f - b2f(dP[o]), s0 = b2f(S[o]);
  for (int ck = 0; ck < NCHUNK; ++ck) {
    float p1 = 1.f, s1 = 0.f;
    if (ck + 1 < NCHUNK) { p1 = 1.f - b2f(dP[o + stride]); s1 = b2f(S[o + stride]); }
    dP[o] = f2b(hs);                 // Hst
    hs = __builtin_fmaf(p0, hs, s0);
    o += stride; p0 = p1; s0 = s1;
  }
}

__global__ __launch_bounds__(256)
void scan_passC_k(const u16* __restrict__ dt, const u16* __restrict__ uc,
                  const float* __restrict__ xdbl, const u16* __restrict__ xz,
                  const float* __restrict__ A_log, const float* __restrict__ Dp,
                  const u16* __restrict__ Hst, u16* __restrict__ ybf) {
  __shared__ float bc[CLEN][32];
  const int tid = threadIdx.x;
  int idx = blockIdx.x * 256 + tid;   // 4*64*2048
  int h = idx & (NB_H - 1);
  int ck = (idx >> 11) & (NCHUNK - 1);
  int b = idx >> 17;
  const int t0 = b * NB_L + ck * CLEN;
  {
    int r = tid >> 3, q = tid & 7;
    *reinterpret_cast<float4*>(&bc[r][q * 4]) =
        *reinterpret_cast<const float4*>(xdbl + (size_t)(t0 + r) * 128 + 64 + q * 4);
  }
  float An[NB_NS];
#pragma unroll
  for (int n = 0; n < NB_NS; ++n) An[n] = -__expf(A_log[n]);
  float s[NB_NS];
#pragma unroll
  for (int n = 0; n < NB_NS; ++n)
    s[n] = b2f(Hst[((((size_t)b * NCHUNK + ck) * NB_NS + n) * NB_H + h)]);
  const float Dh = Dp[h];
  __syncthreads();
  const u16* up = uc + (size_t)t0 * NB_H + h;
  const u16* dp = dt + (size_t)t0 * NB_H + h;
  const u16* zp = xz + (size_t)t0 * 4096 + NB_H + h;   // holds silu(z) already
  u16* yp = ybf + (size_t)t0 * NB_H + h;
  float uA = b2f(up[0]),    dA = b2f(dp[0]),    zA = b2f(zp[0]);
  float uB = b2f(up[NB_H]), dB = b2f(dp[NB_H]), zB = b2f(zp[4096]);
  for (int tt = 0; tt < CLEN; ++tt) {
    float uC = 0.f, dC = 0.f, zC = 0.f;
    if (tt + 2 < CLEN) {
      uC = b2f(up[2 * NB_H]); dC = b2f(dp[2 * NB_H]); zC = b2f(zp[2 * 4096]);
    }
    up += NB_H; dp += NB_H; zp += 4096;
    float4 B0 = *reinterpret_cast<const float4*>(&bc[tt][0]);
    float4 B1 = *reinterpret_cast<const float4*>(&bc[tt][4]);
    float4 B2 = *reinterpret_cast<const float4*>(&bc[tt][8]);
    float4 B3 = *reinterpret_cast<const float4*>(&bc[tt][12]);
    float4 C0 = *reinterpret_cast<const float4*>(&bc[tt][16]);
    float4 C1 = *reinterpret_cast<const float4*>(&bc[tt][20]);
    float4 C2 = *reinterpret_cast<const float4*>(&bc[tt][24]);
    float4 C3 = *reinterpret_cast<const float4*>(&bc[tt][28]);
    const float Bf[NB_NS] = {B0.x, B0.y, B0.z, B0.w, B1.x, B1.y, B1.z, B1.w,
                             B2.x, B2.y, B2.z, B2.w, B3.x, B3.y, B3.z, B3.w};
    const float Cf[NB_NS] = {C0.x, C0.y, C0.z, C0.w, C1.x, C1.y, C1.z, C1.w,
                             C2.x, C2.y, C2.z, C2.w, C3.x, C3.y, C3.z, C3.w};
    float y = 0.f;
#pragma unroll
    for (int n = 0; n < NB_NS; ++n) {
      float e = exp_small(dA * An[n]);
      s[n] = __builtin_fmaf(e, s[n], Bf[n] * uA);
      y = __builtin_fmaf(Cf[n], s[n], y);
    }
    float v = __builtin_fmaf(Dh, uA, y);
    *yp = f2b(v * zA);               // zA = silu(z) precomputed in GEMM1
    yp += NB_H;
    uA = uB; dA = dB; zA = zB; uB = uC; dB = dC; zB = zC;
  }
}

// ---------------- launcher ----------------
extern "C" void kernel_launch(void* const* d_in, const int* in_sizes, int n_in,
                              void* d_out, int out_size, void* d_ws, size_t ws_size,
                              hipStream_t stream) {
  const float* x      = (const float*)d_in[0];
  const float* W_in   = (const float*)d_in[1];
  const float* conv_w = (const float*)d_in[2];
  const float* conv_b = (const float*)d_in[3];
  const float* W_xprj = (const float*)d_in[4];
  const float* W_dt   = (const float*)d_in[5];
  const float* b_dt   = (const float*)d_in[6];
  const float* A_log  = (const float*)d_in[7];
  const float* Dp     = (const float*)d_in[8];
  const float* W_out  = (const float*)d_in[9];
  float* out = (float*)d_out;

  char* ws = (char*)d_ws;
  size_t off = 0;
  auto alloc = [&](size_t bytes) {
    void* p = ws + off;
    off += (bytes + 255) & ~(size_t)255;
    return p;
  };
  u16*   xz_b   = (u16*)alloc((size_t)NB_TOK * 4096 * 2);     // 64MB (u raw | silu z)
  u16*   x_b    = (u16*)alloc((size_t)NB_TOK * NB_DIM * 2);   // 16MB
  u16*   win_b  = (u16*)alloc((size_t)4096 * NB_DIM * 2);     // 8MB
  u16*   wxp_b  = (u16*)alloc((size_t)128 * NB_H * 2);        // 512KB
  u16*   wdt_b  = (u16*)alloc((size_t)NB_H * NB_DTR * 2);     // 256KB
  u16*   wout_b = (u16*)alloc((size_t)NB_DIM * NB_H * 2);     // 4MB
  u16*   uc_b   = (u16*)alloc((size_t)NB_TOK * NB_H * 2);     // 32MB
  float* xdbl   = (float*)alloc((size_t)NB_TOK * 128 * 4);    // 4MB
  u16*   dtp_b  = (u16*)alloc((size_t)NB_TOK * NB_DTR * 2);   // 1MB
  u16*   dt_b   = (u16*)alloc((size_t)NB_TOK * NB_H * 2);     // 32MB
  u16*   scdP   = (u16*)alloc((size_t)NB_B * NCHUNK * NB_NS * NB_H * 2); // 16MB (dP -> Hst)
  u16*   scS    = (u16*)alloc((size_t)NB_B * NCHUNK * NB_NS * NB_H * 2); // 16MB
  u16*   y_b    = (u16*)alloc((size_t)NB_TOK * NB_H * 2);     // 32MB
  (void)ws_size; (void)in_sizes; (void)n_in; (void)out_size;

  cvt_all_k<<<(CVT_N5 + 255) / 256, 256, 0, stream>>>(
      x, W_in, W_dt, W_out, W_xprj, x_b, win_b, wdt_b, wout_b, wxp_b);

  // GEMM1: xz = x @ W_in^T + fused conv/silu (tiles 32x16, XCD chunks 8x8)
  gemm8p_k<EPI_CONV, 256><<<512, 512, 0, stream>>>(
      x_b, win_b, NB_DIM, 4096, xz_b, nullptr, nullptr, nullptr,
      conv_w, conv_b, uc_b, 8, 8, 2);

  conv_fix_k<<<128, 256, 0, stream>>>(xz_b, conv_w, conv_b, uc_b);

  // GEMM2: x_dbl = uc @ W_xproj^T -> f32 + dtp bf16
  gemm2_k<64, 64><<<dim3(128, 2), 256, 0, stream>>>(
      uc_b, wxp_b, NB_H, 128, xdbl, dtp_b);

  // GEMM3: dt = softplus(dtp @ W_dt^T + b_dt)  (tiles 32x8, chunks 4x8)
  gemm8p_k<EPI_SP_BF16, 256><<<256, 512, 0, stream>>>(
      dtp_b, wdt_b, NB_DTR, NB_H, dt_b, nullptr, b_dt, nullptr,
      nullptr, nullptr, nullptr, 4, 8, 1);

  scan_passA_k<<<(NB_B * NCHUNK * NB_H) / 256, 256, 0, stream>>>(dt_b, uc_b, xdbl, A_log, scdP, scS);
  scan_passB_k<<<(NB_B * NB_NS * NB_H) / 256, 256, 0, stream>>>(scdP, scS);
  scan_passC_k<<<(NB_B * NCHUNK * NB_H) / 256, 256, 0, stream>>>(dt_b, uc_b, xdbl, xz_b, A_log, Dp, scdP, y_b);

  // GEMM4: out = y @ W_out^T + x  (tiles 64x4, BM=128, chunks 8x4)
  gemm8p_k<EPI_RES_F32, 128><<<256, 512, 0, stream>>>(
      y_b, wout_b, NB_H, NB_DIM, nullptr, out, nullptr, x,
      nullptr, nullptr, nullptr, 8, 4, 1);
}

// Round 10
// 329.515 us; speedup vs baseline: 1.2628x; 1.2307x over previous
//
#include <hip/hip_runtime.h>
#include <cmath>

typedef unsigned short u16;
typedef __bf16 bf16x8 __attribute__((ext_vector_type(8)));
typedef float f32x4 __attribute__((ext_vector_type(4)));
typedef unsigned short u16x8 __attribute__((ext_vector_type(8)));

#define NB_B   4
#define NB_L   2048
#define NB_DIM 1024
#define NB_H   2048
#define NB_NS  16
#define NB_DTR 64
#define NB_TOK (NB_B * NB_L)   // 8192
#define NCHUNK 64
#define CLEN   32              // NB_L / NCHUNK

__device__ __forceinline__ u16 f2b(float f) {
  union { float f; unsigned u; } v; v.f = f;
  unsigned r = v.u + 0x7fffu + ((v.u >> 16) & 1u);
  return (u16)(r >> 16);
}
__device__ __forceinline__ float b2f(u16 h) {
  union { unsigned u; float f; } v; v.u = ((unsigned)h) << 16;
  return v.f;
}
// exp(w) for |w| <= ~2e-4 here: 1 + w + w^2/2, err ~ |w|^3/6
__device__ __forceinline__ float exp_small(float w) {
  return __builtin_fmaf(w, __builtin_fmaf(w, 0.5f, 1.0f), 1.0f);
}

// ---------------- fused converts (x, W_in, W_dt, W_out, W_xproj+pad) --------
#define CVT_N0 2097152                      // x          f4
#define CVT_N1 (CVT_N0 + 1048576)           // W_in       f4
#define CVT_N2 (CVT_N1 + 32768)             // W_dt       f4
#define CVT_N3 (CVT_N2 + 524288)            // W_out      f4
#define CVT_N4 (CVT_N3 + 49152)             // W_xproj    f4 (96*2048/4)
#define CVT_N5 (CVT_N4 + 8192)              // xproj pad  u16x8 (32*2048/8)
__global__ void cvt_all_k(const float* __restrict__ x, const float* __restrict__ W_in,
                          const float* __restrict__ W_dt, const float* __restrict__ W_out,
                          const float* __restrict__ W_xp,
                          u16* __restrict__ xb, u16* __restrict__ winb,
                          u16* __restrict__ wdtb, u16* __restrict__ woutb,
                          u16* __restrict__ wxpb) {
  int i = blockIdx.x * 256 + threadIdx.x;
  if (i >= CVT_N5) return;
  if (i >= CVT_N4) {   // zero pad rows 96..127 of wxp
    int q = i - CVT_N4;
    u16x8 z = {};
    *reinterpret_cast<u16x8*>(wxpb + 96 * 2048 + q * 8) = z;
    return;
  }
  const float* src; u16* dst; int off;
  if (i < CVT_N0)      { src = x;     dst = xb;    off = i; }
  else if (i < CVT_N1) { src = W_in;  dst = winb;  off = i - CVT_N0; }
  else if (i < CVT_N2) { src = W_dt;  dst = wdtb;  off = i - CVT_N1; }
  else if (i < CVT_N3) { src = W_out; dst = woutb; off = i - CVT_N2; }
  else                 { src = W_xp;  dst = wxpb;  off = i - CVT_N3; }
  float4 v = reinterpret_cast<const float4*>(src)[off];
  ushort4 o;
  o.x = f2b(v.x); o.y = f2b(v.y); o.z = f2b(v.z); o.w = f2b(v.w);
  reinterpret_cast<ushort4*>(dst)[off] = o;
}

#define EPI_BF16    0
#define EPI_F32     1
#define EPI_SP_BF16 2
#define EPI_RES_F32 3

__device__ __forceinline__ void stage16(const u16* g, u16* l) {
  __builtin_amdgcn_global_load_lds(
      (const __attribute__((address_space(1))) unsigned int*)g,
      (__attribute__((address_space(3))) unsigned int*)l, 16, 0, 0);
}

// =================== 4-phase/K-tile pipelined GEMM (BK=64, BN=256) ==========
// (round-7 structure, verbatim: measured 84.7us GEMM1, MfmaUtil 31%)
// C = A(MxK) * B(NxK)^T, bf16 K-contig. 512 thr = 8 waves (2 wr x 4 wc),
// wave tile (BM/2) x 64. 2 LDS buffers; tile kt+2 staged during tile kt;
// counted vmcnt(L) lands tile kt+1 while kt+2 stays in flight. XOR slot
// swizzle both-sides. XCD chunking: each XCD (bid&7) owns a cr x cc tile
// rectangle -> per-XCD operand footprint is O(cr+cc) panels.
template <int EPI, int BM>
__global__ __launch_bounds__(512, 1)
void gemm8p_k(const u16* __restrict__ A, const u16* __restrict__ Bm,
              int K, int ldc,
              u16* __restrict__ outB, float* __restrict__ outF,
              const float* __restrict__ bias, const float* __restrict__ resid,
              int cr, int cc, int ncx) {
  constexpr int MR = BM / 32;          // m-frags per wave
  constexpr int MH = MR / 2;
  constexpr int HA = BM / 2;           // A staging-half rows
  constexpr int LA = BM / 128;         // gloads per thread per A-half
  constexpr int L  = 2 * LA + 4;       // gloads per thread per K-tile
  constexpr int BUFE = (BM + 256) * 64; // u16 per buffer
  __shared__ u16 smem[2 * BUFE];

  const int tid  = threadIdx.x;
  const int lane = tid & 63;
  const int wave = tid >> 6;
  const int wr = wave >> 2, wc = wave & 3;
  const int fr = lane & 15, fq = lane >> 4;

  const int bid = blockIdx.x;
  const int e = bid & 7, w = bid >> 3;
  const int row0 = ((e / ncx) * cr + (w % cr)) * BM;
  const int col0 = ((e % ncx) * cc + (w / cr)) * 256;

  f32x4 acc[MR][4] = {};
  bf16x8 bB[4][2], bA0[MH][2], bA1[MH][2];

  auto STAGE_B = [&](int kt) {
    const int k0 = kt * 64;
    u16* base = smem + (kt & 1) * BUFE + BM * 64;
#pragma unroll
    for (int h = 0; h < 2; ++h)
#pragma unroll
      for (int l = 0; l < 2; ++l) {
        int c = l * 512 + tid;
        int rih = c >> 3, p = c & 7;
        stage16(Bm + (size_t)(col0 + h * 128 + rih) * K + k0 + ((p ^ (rih & 7)) * 8),
                base + (h * 128 + rih) * 64 + p * 8);
      }
  };
  auto STAGE_A = [&](int kt) {
    const int k0 = kt * 64;
    u16* base = smem + (kt & 1) * BUFE;
#pragma unroll
    for (int h = 0; h < 2; ++h)
#pragma unroll
      for (int l = 0; l < LA; ++l) {
        int c = l * 512 + tid;
        int rih = c >> 3, p = c & 7;
        stage16(A + (size_t)(row0 + h * HA + rih) * K + k0 + ((p ^ (rih & 7)) * 8),
                base + (h * HA + rih) * 64 + p * 8);
      }
  };
  auto LD_A = [&](int m, int kk, int bi) {
    int rt = wr * HA + m * 16 + fr;
    int p = (kk * 4 + fq) ^ (rt & 7);
    return *reinterpret_cast<const bf16x8*>(smem + bi * BUFE + rt * 64 + p * 8);
  };
  auto LD_B = [&](int n, int kk, int bi) {
    int rt = wc * 64 + n * 16 + fr;
    int p = (kk * 4 + fq) ^ (rt & 7);
    return *reinterpret_cast<const bf16x8*>(smem + bi * BUFE + BM * 64 + rt * 64 + p * 8);
  };

  const int nk = K >> 6;
  // ---- prologue: stage tiles 0,1; land tile 0; pre-read tile 0 (B all + A mh0)
  STAGE_B(0); STAGE_A(0);
  if (nk > 1) { STAGE_B(1); STAGE_A(1); }
  if (nk > 1) asm volatile("s_waitcnt vmcnt(%0)" :: "i"(L) : "memory");
  else        asm volatile("s_waitcnt vmcnt(0)" ::: "memory");
  __builtin_amdgcn_s_barrier();
  __builtin_amdgcn_sched_barrier(0);
#pragma unroll
  for (int n = 0; n < 4; ++n) { bB[n][0] = LD_B(n, 0, 0); bB[n][1] = LD_B(n, 1, 0); }
#pragma unroll
  for (int m = 0; m < MH; ++m) { bA0[m][0] = LD_A(m, 0, 0); bA0[m][1] = LD_A(m, 1, 0); }
  asm volatile("s_waitcnt lgkmcnt(0)" ::: "memory");
  __builtin_amdgcn_s_barrier();
  __builtin_amdgcn_sched_barrier(0);

  for (int kt = 0; kt < nk; ++kt) {
    const int bi = kt & 1;
    // ---- P1: stage B(kt+2) | MFMA Q00 (A-mh0 x B-nh0)
    if (kt + 2 < nk) STAGE_B(kt + 2);
    __builtin_amdgcn_s_setprio(1);
#pragma unroll
    for (int m = 0; m < MH; ++m)
#pragma unroll
      for (int n = 0; n < 2; ++n)
#pragma unroll
        for (int kk = 0; kk < 2; ++kk)
          acc[m][n] = __builtin_amdgcn_mfma_f32_16x16x32_bf16(bA0[m][kk], bB[n][kk], acc[m][n], 0, 0, 0);
    __builtin_amdgcn_s_setprio(0);
    __builtin_amdgcn_sched_barrier(0);
    // ---- P2: read A-mh1(kt) | MFMA Q01 (A-mh0 x B-nh1)
#pragma unroll
    for (int m = 0; m < MH; ++m) { bA1[m][0] = LD_A(MH + m, 0, bi); bA1[m][1] = LD_A(MH + m, 1, bi); }
    __builtin_amdgcn_s_setprio(1);
#pragma unroll
    for (int m = 0; m < MH; ++m)
#pragma unroll
      for (int n = 2; n < 4; ++n)
#pragma unroll
        for (int kk = 0; kk < 2; ++kk)
          acc[m][n] = __builtin_amdgcn_mfma_f32_16x16x32_bf16(bA0[m][kk], bB[n][kk], acc[m][n], 0, 0, 0);
    __builtin_amdgcn_s_setprio(0);
    asm volatile("s_waitcnt lgkmcnt(0)" ::: "memory");
    __builtin_amdgcn_s_barrier();            // A-region of buf[bi] fully consumed
    __builtin_amdgcn_sched_barrier(0);
    // ---- P3: stage A(kt+2) | MFMA Q10 (A-mh1 x B-nh0)
    if (kt + 2 < nk) STAGE_A(kt + 2);
    __builtin_amdgcn_s_setprio(1);
#pragma unroll
    for (int m = 0; m < MH; ++m)
#pragma unroll
      for (int n = 0; n < 2; ++n)
#pragma unroll
        for (int kk = 0; kk < 2; ++kk)
          acc[MH + m][n] = __builtin_amdgcn_mfma_f32_16x16x32_bf16(bA1[m][kk], bB[n][kk], acc[MH + m][n], 0, 0, 0);
    __builtin_amdgcn_s_setprio(0);
    __builtin_amdgcn_sched_barrier(0);
    // ---- P4: land tile kt+1 (vmcnt L, kt+2 stays in flight) -> read its
    //          B-nh0 + A-mh0 | MFMA Q11 (A-mh1 x B-nh1) | read its B-nh1
    if (kt + 1 < nk) {
      if (kt + 2 < nk) asm volatile("s_waitcnt vmcnt(%0)" :: "i"(L) : "memory");
      else             asm volatile("s_waitcnt vmcnt(0)" ::: "memory");
      __builtin_amdgcn_s_barrier();
      __builtin_amdgcn_sched_barrier(0);
#pragma unroll
      for (int n = 0; n < 2; ++n) { bB[n][0] = LD_B(n, 0, bi ^ 1); bB[n][1] = LD_B(n, 1, bi ^ 1); }
#pragma unroll
      for (int m = 0; m < MH; ++m) { bA0[m][0] = LD_A(m, 0, bi ^ 1); bA0[m][1] = LD_A(m, 1, bi ^ 1); }
    }
    __builtin_amdgcn_s_setprio(1);
#pragma unroll
    for (int m = 0; m < MH; ++m)
#pragma unroll
      for (int n = 2; n < 4; ++n)
#pragma unroll
        for (int kk = 0; kk < 2; ++kk)
          acc[MH + m][n] = __builtin_amdgcn_mfma_f32_16x16x32_bf16(bA1[m][kk], bB[n][kk], acc[MH + m][n], 0, 0, 0);
    __builtin_amdgcn_s_setprio(0);
    if (kt + 1 < nk) {
#pragma unroll
      for (int n = 2; n < 4; ++n) { bB[n][0] = LD_B(n, 0, bi ^ 1); bB[n][1] = LD_B(n, 1, bi ^ 1); }
    }
    asm volatile("s_waitcnt lgkmcnt(0)" ::: "memory");
    __builtin_amdgcn_s_barrier();            // tile boundary
    __builtin_amdgcn_sched_barrier(0);
  }

  // ---- epilogue. bf16 paths: per-wave LDS bounce in bf16, row stride 72 u16
  // (144B) -> read lanes balance across all 8 bank-quads (no 16-way conflict).
  if constexpr (EPI == EPI_BF16 || EPI == EPI_SP_BF16) {
    u16* wv = smem + wave * 1152;   // 16 rows x 72 u16 per wave
#pragma unroll
    for (int m = 0; m < MR; ++m) {
#pragma unroll
      for (int n = 0; n < 4; ++n) {
        const int c = col0 + wc * 64 + n * 16 + fr;
        float bv = (EPI == EPI_SP_BF16) ? bias[c] : 0.f;
#pragma unroll
        for (int j = 0; j < 4; ++j) {
          float v = acc[m][n][j];
          if (EPI == EPI_SP_BF16) {
            float xx = v + bv;
            float t = __expf(xx);
            float sp = (xx > -5.f) ? log1pf(t) : t;
            v = (xx > 20.f) ? xx : sp;
          }
          wv[(fq * 4 + j) * 72 + n * 16 + fr] = f2b(v);
        }
      }
#pragma unroll
      for (int p = 0; p < 2; ++p) {
        const int rf = p * 8 + (lane >> 3);
        const int c0 = (lane & 7) * 8;
        u16x8 ov = *reinterpret_cast<const u16x8*>(wv + rf * 72 + c0);
        const int grow = row0 + wr * HA + m * 16 + rf;
        const int gcol = col0 + wc * 64 + c0;
        *reinterpret_cast<u16x8*>(&outB[(size_t)grow * ldc + gcol]) = ov;
      }
    }
  } else {
#pragma unroll
    for (int m = 0; m < MR; ++m) {
      const int r = row0 + wr * HA + m * 16 + fq * 4;
#pragma unroll
      for (int n = 0; n < 4; ++n) {
        const int c = col0 + wc * 64 + n * 16 + fr;
#pragma unroll
        for (int j = 0; j < 4; ++j) {
          size_t o = (size_t)(r + j) * ldc + c;
          if (EPI == EPI_F32) outF[o] = acc[m][n][j];
          else                outF[o] = acc[m][n][j] + resid[o];
        }
      }
    }
  }
}

// ---------------- legacy 64x64 GEMM (GEMM2: xdbl f32 + dtp bf16) ----------
template <int BM, int BN>
__global__ __launch_bounds__(256)
void gemm2_k(const u16* __restrict__ A, const u16* __restrict__ Bm,
             int K, int ldc, float* __restrict__ outF, u16* __restrict__ dtp) {
  constexpr int MR = BM / 32, NR = BN / 32;
  __shared__ u16 smem[(BM + BN) * 32];
  u16* As = smem;
  u16* Bs = smem + BM * 32;
  const int tid  = threadIdx.x;
  const int lane = tid & 63;
  const int wave = tid >> 6;
  const int wr = wave >> 1, wc = wave & 1;
  const int row0 = blockIdx.x * BM;
  const int col0 = blockIdx.y * BN;
  f32x4 acc[MR][NR] = {};

  const int r_ld = tid >> 2;
  const int kb   = (((tid & 3) ^ ((tid >> 3) & 3)) * 8);
  const size_t a_base = (size_t)(row0 + r_ld) * K + kb;
  const size_t b_base = (size_t)(col0 + r_ld) * K + kb;
  u16* lA = As + tid * 8;
  u16* lB = Bs + tid * 8;

  const int fr = lane & 15;
  const int fq = lane >> 4;
  const int fkx = ((fq ^ ((fr >> 1) & 3)) * 8);

  const int nk = K >> 5;
  for (int kt = 0; kt < nk; ++kt) {
    const int k0 = kt * 32;
    __syncthreads();
#pragma unroll
    for (int hh = 0; hh < BM / 64; ++hh)
      stage16(A + a_base + (size_t)(hh * 64) * K + k0, lA + hh * 64 * 32);
#pragma unroll
    for (int hh = 0; hh < BN / 64; ++hh)
      stage16(Bm + b_base + (size_t)(hh * 64) * K + k0, lB + hh * 64 * 32);
    __syncthreads();
    bf16x8 af[MR], bfr[NR];
#pragma unroll
    for (int m = 0; m < MR; ++m)
      af[m] = *reinterpret_cast<const bf16x8*>(&As[(wr * (BM / 2) + m * 16 + fr) * 32 + fkx]);
#pragma unroll
    for (int n = 0; n < NR; ++n)
      bfr[n] = *reinterpret_cast<const bf16x8*>(&Bs[(wc * (BN / 2) + n * 16 + fr) * 32 + fkx]);
#pragma unroll
    for (int m = 0; m < MR; ++m)
#pragma unroll
      for (int n = 0; n < NR; ++n)
        acc[m][n] = __builtin_amdgcn_mfma_f32_16x16x32_bf16(af[m], bfr[n], acc[m][n], 0, 0, 0);
  }

#pragma unroll
  for (int m = 0; m < MR; ++m) {
    const int r = row0 + wr * (BM / 2) + m * 16 + fq * 4;
#pragma unroll
    for (int n = 0; n < NR; ++n) {
      const int c = col0 + wc * (BN / 2) + n * 16 + fr;
#pragma unroll
      for (int j = 0; j < 4; ++j) {
        float v = acc[m][n][j];
        outF[(size_t)(r + j) * ldc + c] = v;
        if (c < NB_DTR) dtp[(size_t)(r + j) * NB_DTR + c] = f2b(v);
      }
    }
  }
}

// ---------------- depthwise conv (k=3, pad 1) + silu ----------------
__global__ void dwconv_silu_k(const u16* __restrict__ xz, const float* __restrict__ cw,
                              const float* __restrict__ cb, u16* __restrict__ uc) {
  int i = blockIdx.x * 256 + threadIdx.x;     // over 8192*2048/8
  int hb = i & (NB_H / 8 - 1);
  int t = i >> 8;
  int l = t & (NB_L - 1);
  int h0 = hb * 8;
  const u16* base = xz + (size_t)t * 4096 + h0;
  u16x8 vm = *reinterpret_cast<const u16x8*>(base);
  u16x8 vq = {}, vp = {};
  if (l > 0)          vq = *reinterpret_cast<const u16x8*>(base - 4096);
  if (l < NB_L - 1)   vp = *reinterpret_cast<const u16x8*>(base + 4096);
  u16x8 o;
#pragma unroll
  for (int j = 0; j < 8; ++j) {
    int h = h0 + j;
    float acc = cb[h];
    acc = __builtin_fmaf(b2f(vq[j]), cw[h * 3 + 0], acc);
    acc = __builtin_fmaf(b2f(vm[j]), cw[h * 3 + 1], acc);
    acc = __builtin_fmaf(b2f(vp[j]), cw[h * 3 + 2], acc);
    float s = acc / (1.f + __expf(-acc));
    o[j] = f2b(s);
  }
  *reinterpret_cast<u16x8*>(uc + (size_t)t * NB_H + h0) = o;
}

// ---------------- chunked selective scan (summaries in bf16) ----------------
// dP = 1-P (P in [~0.9995,1] -> bf16(P) would round to 1.0; 1-P keeps 0.4%
// relative accuracy), S and Hst plain bf16.
__global__ __launch_bounds__(256)
void scan_passA_k(const u16* __restrict__ dt, const u16* __restrict__ uc,
                  const float* __restrict__ xdbl, const float* __restrict__ A_log,
                  u16* __restrict__ dPout, u16* __restrict__ Sout) {
  __shared__ float bc[CLEN][32];
  const int tid = threadIdx.x;
  int idx = blockIdx.x * 256 + tid;   // 4*64*2048
  int h = idx & (NB_H - 1);
  int ck = (idx >> 11) & (NCHUNK - 1);
  int b = idx >> 17;
  const int t0 = b * NB_L + ck * CLEN;
  {
    int r = tid >> 3, q = tid & 7;
    *reinterpret_cast<float4*>(&bc[r][q * 4]) =
        *reinterpret_cast<const float4*>(xdbl + (size_t)(t0 + r) * 128 + 64 + q * 4);
  }
  float An[NB_NS];
#pragma unroll
  for (int n = 0; n < NB_NS; ++n) An[n] = -__expf(A_log[n]);
  float P[NB_NS], S[NB_NS];
#pragma unroll
  for (int n = 0; n < NB_NS; ++n) { P[n] = 1.f; S[n] = 0.f; }
  __syncthreads();
  const u16* up = uc + (size_t)t0 * NB_H + h;
  const u16* dp = dt + (size_t)t0 * NB_H + h;
  float uA = b2f(up[0]),       dA = b2f(dp[0]);
  float uB = b2f(up[NB_H]),    dB = b2f(dp[NB_H]);
  for (int tt = 0; tt < CLEN; ++tt) {
    float uC = 0.f, dC = 0.f;
    if (tt + 2 < CLEN) { uC = b2f(up[2 * NB_H]); dC = b2f(dp[2 * NB_H]); }
    up += NB_H; dp += NB_H;
    float4 B0 = *reinterpret_cast<const float4*>(&bc[tt][0]);
    float4 B1 = *reinterpret_cast<const float4*>(&bc[tt][4]);
    float4 B2 = *reinterpret_cast<const float4*>(&bc[tt][8]);
    float4 B3 = *reinterpret_cast<const float4*>(&bc[tt][12]);
    const float Bf[NB_NS] = {B0.x, B0.y, B0.z, B0.w, B1.x, B1.y, B1.z, B1.w,
                             B2.x, B2.y, B2.z, B2.w, B3.x, B3.y, B3.z, B3.w};
#pragma unroll
    for (int n = 0; n < NB_NS; ++n) {
      float e = exp_small(dA * An[n]);
      P[n] *= e;
      S[n] = __builtin_fmaf(e, S[n], Bf[n] * uA);
    }
    uA = uB; dA = dB; uB = uC; dB = dC;
  }
#pragma unroll
  for (int n = 0; n < NB_NS; ++n) {
    size_t o = ((((size_t)b * NCHUNK + ck) * NB_NS + n) * NB_H + h);
    dPout[o] = f2b(1.0f - P[n]);
    Sout[o]  = f2b(S[n]);
  }
}

// pass B: sequential combine over chunks; Hst (bf16) written in-place over dP.
__global__ void scan_passB_k(u16* __restrict__ dP, const u16* __restrict__ S) {
  int idx = blockIdx.x * 256 + threadIdx.x;   // 4*16*2048
  int h = idx & (NB_H - 1);
  int n = (idx >> 11) & (NB_NS - 1);
  int b = idx >> 15;
  const size_t stride = (size_t)NB_NS * NB_H;
  size_t o = ((size_t)b * NCHUNK * NB_NS + n) * NB_H + h;
  float hs = 0.f;
  float p0 = 1.f - b2f(dP[o]), s0 = b2f(S[o]);
  for (int ck = 0; ck < NCHUNK; ++ck) {
    float p1 = 1.f, s1 = 0.f;
    if (ck + 1 < NCHUNK) { p1 = 1.f - b2f(dP[o + stride]); s1 = b2f(S[o + stride]); }
    dP[o] = f2b(hs);                 // Hst
    hs = __builtin_fmaf(p0, hs, s0);
    o += stride; p0 = p1; s0 = s1;
  }
}

__global__ __launch_bounds__(256)
void scan_passC_k(const u16* __restrict__ dt, const u16* __restrict__ uc,
                  const float* __restrict__ xdbl, const u16* __restrict__ xz,
                  const float* __restrict__ A_log, const float* __restrict__ Dp,
                  const u16* __restrict__ Hst, u16* __restrict__ ybf) {
  __shared__ float bc[CLEN][32];
  const int tid = threadIdx.x;
  int idx = blockIdx.x * 256 + tid;   // 4*64*2048
  int h = idx & (NB_H - 1);
  int ck = (idx >> 11) & (NCHUNK - 1);
  int b = idx >> 17;
  const int t0 = b * NB_L + ck * CLEN;
  {
    int r = tid >> 3, q = tid & 7;
    *reinterpret_cast<float4*>(&bc[r][q * 4]) =
        *reinterpret_cast<const float4*>(xdbl + (size_t)(t0 + r) * 128 + 64 + q * 4);
  }
  float An[NB_NS];
#pragma unroll
  for (int n = 0; n < NB_NS; ++n) An[n] = -__expf(A_log[n]);
  float s[NB_NS];
#pragma unroll
  for (int n = 0; n < NB_NS; ++n)
    s[n] = b2f(Hst[((((size_t)b * NCHUNK + ck) * NB_NS + n) * NB_H + h)]);
  const float Dh = Dp[h];
  __syncthreads();
  const u16* up = uc + (size_t)t0 * NB_H + h;
  const u16* dp = dt + (size_t)t0 * NB_H + h;
  const u16* zp = xz + (size_t)t0 * 4096 + NB_H + h;
  u16* yp = ybf + (size_t)t0 * NB_H + h;
  float uA = b2f(up[0]),    dA = b2f(dp[0]),    zA = b2f(zp[0]);
  float uB = b2f(up[NB_H]), dB = b2f(dp[NB_H]), zB = b2f(zp[4096]);
  for (int tt = 0; tt < CLEN; ++tt) {
    float uC = 0.f, dC = 0.f, zC = 0.f;
    if (tt + 2 < CLEN) {
      uC = b2f(up[2 * NB_H]); dC = b2f(dp[2 * NB_H]); zC = b2f(zp[2 * 4096]);
    }
    up += NB_H; dp += NB_H; zp += 4096;
    float4 B0 = *reinterpret_cast<const float4*>(&bc[tt][0]);
    float4 B1 = *reinterpret_cast<const float4*>(&bc[tt][4]);
    float4 B2 = *reinterpret_cast<const float4*>(&bc[tt][8]);
    float4 B3 = *reinterpret_cast<const float4*>(&bc[tt][12]);
    float4 C0 = *reinterpret_cast<const float4*>(&bc[tt][16]);
    float4 C1 = *reinterpret_cast<const float4*>(&bc[tt][20]);
    float4 C2 = *reinterpret_cast<const float4*>(&bc[tt][24]);
    float4 C3 = *reinterpret_cast<const float4*>(&bc[tt][28]);
    const float Bf[NB_NS] = {B0.x, B0.y, B0.z, B0.w, B1.x, B1.y, B1.z, B1.w,
                             B2.x, B2.y, B2.z, B2.w, B3.x, B3.y, B3.z, B3.w};
    const float Cf[NB_NS] = {C0.x, C0.y, C0.z, C0.w, C1.x, C1.y, C1.z, C1.w,
                             C2.x, C2.y, C2.z, C2.w, C3.x, C3.y, C3.z, C3.w};
    float y = 0.f;
#pragma unroll
    for (int n = 0; n < NB_NS; ++n) {
      float e = exp_small(dA * An[n]);
      s[n] = __builtin_fmaf(e, s[n], Bf[n] * uA);
      y = __builtin_fmaf(Cf[n], s[n], y);
    }
    float v = __builtin_fmaf(Dh, uA, y);
    float g = zA / (1.f + __expf(-zA));
    *yp = f2b(v * g);
    yp += NB_H;
    uA = uB; dA = dB; zA = zB; uB = uC; dB = dC; zB = zC;
  }
}

// ---------------- launcher ----------------
extern "C" void kernel_launch(void* const* d_in, const int* in_sizes, int n_in,
                              void* d_out, int out_size, void* d_ws, size_t ws_size,
                              hipStream_t stream) {
  const float* x      = (const float*)d_in[0];
  const float* W_in   = (const float*)d_in[1];
  const float* conv_w = (const float*)d_in[2];
  const float* conv_b = (const float*)d_in[3];
  const float* W_xprj = (const float*)d_in[4];
  const float* W_dt   = (const float*)d_in[5];
  const float* b_dt   = (const float*)d_in[6];
  const float* A_log  = (const float*)d_in[7];
  const float* Dp     = (const float*)d_in[8];
  const float* W_out  = (const float*)d_in[9];
  float* out = (float*)d_out;

  char* ws = (char*)d_ws;
  size_t off = 0;
  auto alloc = [&](size_t bytes) {
    void* p = ws + off;
    off += (bytes + 255) & ~(size_t)255;
    return p;
  };
  u16*   xz_b   = (u16*)alloc((size_t)NB_TOK * 4096 * 2);     // 64MB
  u16*   x_b    = (u16*)alloc((size_t)NB_TOK * NB_DIM * 2);   // 16MB
  u16*   win_b  = (u16*)alloc((size_t)4096 * NB_DIM * 2);     // 8MB
  u16*   wxp_b  = (u16*)alloc((size_t)128 * NB_H * 2);        // 512KB
  u16*   wdt_b  = (u16*)alloc((size_t)NB_H * NB_DTR * 2);     // 256KB
  u16*   wout_b = (u16*)alloc((size_t)NB_DIM * NB_H * 2);     // 4MB
  u16*   uc_b   = (u16*)alloc((size_t)NB_TOK * NB_H * 2);     // 32MB
  float* xdbl   = (float*)alloc((size_t)NB_TOK * 128 * 4);    // 4MB
  u16*   dtp_b  = (u16*)alloc((size_t)NB_TOK * NB_DTR * 2);   // 1MB
  u16*   dt_b   = (u16*)alloc((size_t)NB_TOK * NB_H * 2);     // 32MB
  u16*   scdP   = (u16*)alloc((size_t)NB_B * NCHUNK * NB_NS * NB_H * 2); // 16MB (dP -> Hst)
  u16*   scS    = (u16*)alloc((size_t)NB_B * NCHUNK * NB_NS * NB_H * 2); // 16MB
  u16*   y_b    = (u16*)alloc((size_t)NB_TOK * NB_H * 2);     // 32MB
  (void)ws_size; (void)in_sizes; (void)n_in; (void)out_size;

  cvt_all_k<<<(CVT_N5 + 255) / 256, 256, 0, stream>>>(
      x, W_in, W_dt, W_out, W_xprj, x_b, win_b, wdt_b, wout_b, wxp_b);

  // GEMM1: xz = x @ W_in^T  (tiles 32x16): XCD chunks 8x8, chunk grid 4x2
  gemm8p_k<EPI_BF16, 256><<<512, 512, 0, stream>>>(
      x_b, win_b, NB_DIM, 4096, xz_b, nullptr, nullptr, nullptr, 8, 8, 2);

  dwconv_silu_k<<<(NB_TOK * NB_H / 8) / 256, 256, 0, stream>>>(xz_b, conv_w, conv_b, uc_b);

  // GEMM2: x_dbl = uc @ W_xproj^T -> f32 + dtp bf16
  gemm2_k<64, 64><<<dim3(128, 2), 256, 0, stream>>>(
      uc_b, wxp_b, NB_H, 128, xdbl, dtp_b);

  // GEMM3: dt = softplus(dtp @ W_dt^T + b_dt)  (tiles 32x8): chunks 4x8
  gemm8p_k<EPI_SP_BF16, 256><<<256, 512, 0, stream>>>(
      dtp_b, wdt_b, NB_DTR, NB_H, dt_b, nullptr, b_dt, nullptr, 4, 8, 1);

  scan_passA_k<<<(NB_B * NCHUNK * NB_H) / 256, 256, 0, stream>>>(dt_b, uc_b, xdbl, A_log, scdP, scS);
  scan_passB_k<<<(NB_B * NB_NS * NB_H) / 256, 256, 0, stream>>>(scdP, scS);
  scan_passC_k<<<(NB_B * NCHUNK * NB_H) / 256, 256, 0, stream>>>(dt_b, uc_b, xdbl, xz_b, A_log, Dp, scdP, y_b);

  // GEMM4: out = y @ W_out^T + x  (tiles 64x4, BM=128): chunks 8x4
  gemm8p_k<EPI_RES_F32, 128><<<256, 512, 0, stream>>>(
      y_b, wout_b, NB_H, NB_DIM, nullptr, out, nullptr, x, 8, 4, 1);
}

// Round 11
// 309.448 us; speedup vs baseline: 1.3447x; 1.0649x over previous
//
#include <hip/hip_runtime.h>
#include <cmath>

typedef unsigned short u16;
typedef __bf16 bf16x8 __attribute__((ext_vector_type(8)));
typedef float f32x4 __attribute__((ext_vector_type(4)));
typedef unsigned short u16x8 __attribute__((ext_vector_type(8)));

#define NB_B   4
#define NB_L   2048
#define NB_DIM 1024
#define NB_H   2048
#define NB_NS  16
#define NB_DTR 64
#define NB_TOK (NB_B * NB_L)   // 8192
#define NCHUNK 64
#define CLEN   32              // NB_L / NCHUNK

__device__ __forceinline__ u16 f2b(float f) {
  union { float f; unsigned u; } v; v.f = f;
  unsigned r = v.u + 0x7fffu + ((v.u >> 16) & 1u);
  return (u16)(r >> 16);
}
__device__ __forceinline__ float b2f(u16 h) {
  union { unsigned u; float f; } v; v.u = ((unsigned)h) << 16;
  return v.f;
}
// exp(w) for |w| <= ~2e-4 here: 1 + w + w^2/2, err ~ |w|^3/6
__device__ __forceinline__ float exp_small(float w) {
  return __builtin_fmaf(w, __builtin_fmaf(w, 0.5f, 1.0f), 1.0f);
}

// ---------------- fused converts (x, W_in, W_dt, W_out, W_xproj+pad) --------
#define CVT_N0 2097152                      // x          f4
#define CVT_N1 (CVT_N0 + 1048576)           // W_in       f4
#define CVT_N2 (CVT_N1 + 32768)             // W_dt       f4
#define CVT_N3 (CVT_N2 + 524288)            // W_out      f4
#define CVT_N4 (CVT_N3 + 49152)             // W_xproj    f4 (96*2048/4)
#define CVT_N5 (CVT_N4 + 8192)              // xproj pad  u16x8 (32*2048/8)
__global__ void cvt_all_k(const float* __restrict__ x, const float* __restrict__ W_in,
                          const float* __restrict__ W_dt, const float* __restrict__ W_out,
                          const float* __restrict__ W_xp,
                          u16* __restrict__ xb, u16* __restrict__ winb,
                          u16* __restrict__ wdtb, u16* __restrict__ woutb,
                          u16* __restrict__ wxpb) {
  int i = blockIdx.x * 256 + threadIdx.x;
  if (i >= CVT_N5) return;
  if (i >= CVT_N4) {   // zero pad rows 96..127 of wxp
    int q = i - CVT_N4;
    u16x8 z = {};
    *reinterpret_cast<u16x8*>(wxpb + 96 * 2048 + q * 8) = z;
    return;
  }
  const float* src; u16* dst; int off;
  if (i < CVT_N0)      { src = x;     dst = xb;    off = i; }
  else if (i < CVT_N1) { src = W_in;  dst = winb;  off = i - CVT_N0; }
  else if (i < CVT_N2) { src = W_dt;  dst = wdtb;  off = i - CVT_N1; }
  else if (i < CVT_N3) { src = W_out; dst = woutb; off = i - CVT_N2; }
  else                 { src = W_xp;  dst = wxpb;  off = i - CVT_N3; }
  float4 v = reinterpret_cast<const float4*>(src)[off];
  ushort4 o;
  o.x = f2b(v.x); o.y = f2b(v.y); o.z = f2b(v.z); o.w = f2b(v.w);
  reinterpret_cast<ushort4*>(dst)[off] = o;
}

#define EPI_BF16    0
#define EPI_F32     1
#define EPI_SP_BF16 2
#define EPI_RES_F32 3

__device__ __forceinline__ void stage16(const u16* g, u16* l) {
  __builtin_amdgcn_global_load_lds(
      (const __attribute__((address_space(1))) unsigned int*)g,
      (__attribute__((address_space(3))) unsigned int*)l, 16, 0, 0);
}

// =================== 4-phase/K-tile pipelined GEMM (BK=64, BN=256) ==========
// (round-7 structure, verbatim: measured 84.7us GEMM1, MfmaUtil 33%)
template <int EPI, int BM>
__global__ __launch_bounds__(512, 1)
void gemm8p_k(const u16* __restrict__ A, const u16* __restrict__ Bm,
              int K, int ldc,
              u16* __restrict__ outB, float* __restrict__ outF,
              const float* __restrict__ bias, const float* __restrict__ resid,
              int cr, int cc, int ncx) {
  constexpr int MR = BM / 32;          // m-frags per wave
  constexpr int MH = MR / 2;
  constexpr int HA = BM / 2;           // A staging-half rows
  constexpr int LA = BM / 128;         // gloads per thread per A-half
  constexpr int L  = 2 * LA + 4;       // gloads per thread per K-tile
  constexpr int BUFE = (BM + 256) * 64; // u16 per buffer
  __shared__ u16 smem[2 * BUFE];

  const int tid  = threadIdx.x;
  const int lane = tid & 63;
  const int wave = tid >> 6;
  const int wr = wave >> 2, wc = wave & 3;
  const int fr = lane & 15, fq = lane >> 4;

  const int bid = blockIdx.x;
  const int e = bid & 7, w = bid >> 3;
  const int row0 = ((e / ncx) * cr + (w % cr)) * BM;
  const int col0 = ((e % ncx) * cc + (w / cr)) * 256;

  f32x4 acc[MR][4] = {};
  bf16x8 bB[4][2], bA0[MH][2], bA1[MH][2];

  auto STAGE_B = [&](int kt) {
    const int k0 = kt * 64;
    u16* base = smem + (kt & 1) * BUFE + BM * 64;
#pragma unroll
    for (int h = 0; h < 2; ++h)
#pragma unroll
      for (int l = 0; l < 2; ++l) {
        int c = l * 512 + tid;
        int rih = c >> 3, p = c & 7;
        stage16(Bm + (size_t)(col0 + h * 128 + rih) * K + k0 + ((p ^ (rih & 7)) * 8),
                base + (h * 128 + rih) * 64 + p * 8);
      }
  };
  auto STAGE_A = [&](int kt) {
    const int k0 = kt * 64;
    u16* base = smem + (kt & 1) * BUFE;
#pragma unroll
    for (int h = 0; h < 2; ++h)
#pragma unroll
      for (int l = 0; l < LA; ++l) {
        int c = l * 512 + tid;
        int rih = c >> 3, p = c & 7;
        stage16(A + (size_t)(row0 + h * HA + rih) * K + k0 + ((p ^ (rih & 7)) * 8),
                base + (h * HA + rih) * 64 + p * 8);
      }
  };
  auto LD_A = [&](int m, int kk, int bi) {
    int rt = wr * HA + m * 16 + fr;
    int p = (kk * 4 + fq) ^ (rt & 7);
    return *reinterpret_cast<const bf16x8*>(smem + bi * BUFE + rt * 64 + p * 8);
  };
  auto LD_B = [&](int n, int kk, int bi) {
    int rt = wc * 64 + n * 16 + fr;
    int p = (kk * 4 + fq) ^ (rt & 7);
    return *reinterpret_cast<const bf16x8*>(smem + bi * BUFE + BM * 64 + rt * 64 + p * 8);
  };

  const int nk = K >> 6;
  // ---- prologue
  STAGE_B(0); STAGE_A(0);
  if (nk > 1) { STAGE_B(1); STAGE_A(1); }
  if (nk > 1) asm volatile("s_waitcnt vmcnt(%0)" :: "i"(L) : "memory");
  else        asm volatile("s_waitcnt vmcnt(0)" ::: "memory");
  __builtin_amdgcn_s_barrier();
  __builtin_amdgcn_sched_barrier(0);
#pragma unroll
  for (int n = 0; n < 4; ++n) { bB[n][0] = LD_B(n, 0, 0); bB[n][1] = LD_B(n, 1, 0); }
#pragma unroll
  for (int m = 0; m < MH; ++m) { bA0[m][0] = LD_A(m, 0, 0); bA0[m][1] = LD_A(m, 1, 0); }
  asm volatile("s_waitcnt lgkmcnt(0)" ::: "memory");
  __builtin_amdgcn_s_barrier();
  __builtin_amdgcn_sched_barrier(0);

  for (int kt = 0; kt < nk; ++kt) {
    const int bi = kt & 1;
    // P1: stage B(kt+2) | Q00
    if (kt + 2 < nk) STAGE_B(kt + 2);
    __builtin_amdgcn_s_setprio(1);
#pragma unroll
    for (int m = 0; m < MH; ++m)
#pragma unroll
      for (int n = 0; n < 2; ++n)
#pragma unroll
        for (int kk = 0; kk < 2; ++kk)
          acc[m][n] = __builtin_amdgcn_mfma_f32_16x16x32_bf16(bA0[m][kk], bB[n][kk], acc[m][n], 0, 0, 0);
    __builtin_amdgcn_s_setprio(0);
    __builtin_amdgcn_sched_barrier(0);
    // P2: read A-mh1 | Q01
#pragma unroll
    for (int m = 0; m < MH; ++m) { bA1[m][0] = LD_A(MH + m, 0, bi); bA1[m][1] = LD_A(MH + m, 1, bi); }
    __builtin_amdgcn_s_setprio(1);
#pragma unroll
    for (int m = 0; m < MH; ++m)
#pragma unroll
      for (int n = 2; n < 4; ++n)
#pragma unroll
        for (int kk = 0; kk < 2; ++kk)
          acc[m][n] = __builtin_amdgcn_mfma_f32_16x16x32_bf16(bA0[m][kk], bB[n][kk], acc[m][n], 0, 0, 0);
    __builtin_amdgcn_s_setprio(0);
    asm volatile("s_waitcnt lgkmcnt(0)" ::: "memory");
    __builtin_amdgcn_s_barrier();            // A-region of buf[bi] fully consumed
    __builtin_amdgcn_sched_barrier(0);
    // P3: stage A(kt+2) | Q10
    if (kt + 2 < nk) STAGE_A(kt + 2);
    __builtin_amdgcn_s_setprio(1);
#pragma unroll
    for (int m = 0; m < MH; ++m)
#pragma unroll
      for (int n = 0; n < 2; ++n)
#pragma unroll
        for (int kk = 0; kk < 2; ++kk)
          acc[MH + m][n] = __builtin_amdgcn_mfma_f32_16x16x32_bf16(bA1[m][kk], bB[n][kk], acc[MH + m][n], 0, 0, 0);
    __builtin_amdgcn_s_setprio(0);
    __builtin_amdgcn_sched_barrier(0);
    // P4: land kt+1 (vmcnt L keeps kt+2 in flight) -> read next tile | Q11
    if (kt + 1 < nk) {
      if (kt + 2 < nk) asm volatile("s_waitcnt vmcnt(%0)" :: "i"(L) : "memory");
      else             asm volatile("s_waitcnt vmcnt(0)" ::: "memory");
      __builtin_amdgcn_s_barrier();
      __builtin_amdgcn_sched_barrier(0);
#pragma unroll
      for (int n = 0; n < 2; ++n) { bB[n][0] = LD_B(n, 0, bi ^ 1); bB[n][1] = LD_B(n, 1, bi ^ 1); }
#pragma unroll
      for (int m = 0; m < MH; ++m) { bA0[m][0] = LD_A(m, 0, bi ^ 1); bA0[m][1] = LD_A(m, 1, bi ^ 1); }
    }
    __builtin_amdgcn_s_setprio(1);
#pragma unroll
    for (int m = 0; m < MH; ++m)
#pragma unroll
      for (int n = 2; n < 4; ++n)
#pragma unroll
        for (int kk = 0; kk < 2; ++kk)
          acc[MH + m][n] = __builtin_amdgcn_mfma_f32_16x16x32_bf16(bA1[m][kk], bB[n][kk], acc[MH + m][n], 0, 0, 0);
    __builtin_amdgcn_s_setprio(0);
    if (kt + 1 < nk) {
#pragma unroll
      for (int n = 2; n < 4; ++n) { bB[n][0] = LD_B(n, 0, bi ^ 1); bB[n][1] = LD_B(n, 1, bi ^ 1); }
    }
    asm volatile("s_waitcnt lgkmcnt(0)" ::: "memory");
    __builtin_amdgcn_s_barrier();            // tile boundary
    __builtin_amdgcn_sched_barrier(0);
  }

  // ---- epilogue
  if constexpr (EPI == EPI_BF16 || EPI == EPI_SP_BF16) {
    u16* wv = smem + wave * 1152;   // 16 rows x 72 u16 per wave
#pragma unroll
    for (int m = 0; m < MR; ++m) {
#pragma unroll
      for (int n = 0; n < 4; ++n) {
        const int c = col0 + wc * 64 + n * 16 + fr;
        float bv = (EPI == EPI_SP_BF16) ? bias[c] : 0.f;
#pragma unroll
        for (int j = 0; j < 4; ++j) {
          float v = acc[m][n][j];
          if (EPI == EPI_SP_BF16) {
            float xx = v + bv;
            float t = __expf(xx);
            float sp = (xx > -5.f) ? log1pf(t) : t;
            v = (xx > 20.f) ? xx : sp;
          }
          wv[(fq * 4 + j) * 72 + n * 16 + fr] = f2b(v);
        }
      }
#pragma unroll
      for (int p = 0; p < 2; ++p) {
        const int rf = p * 8 + (lane >> 3);
        const int c0 = (lane & 7) * 8;
        u16x8 ov = *reinterpret_cast<const u16x8*>(wv + rf * 72 + c0);
        const int grow = row0 + wr * HA + m * 16 + rf;
        const int gcol = col0 + wc * 64 + c0;
        *reinterpret_cast<u16x8*>(&outB[(size_t)grow * ldc + gcol]) = ov;
      }
    }
  } else {
#pragma unroll
    for (int m = 0; m < MR; ++m) {
      const int r = row0 + wr * HA + m * 16 + fq * 4;
#pragma unroll
      for (int n = 0; n < 4; ++n) {
        const int c = col0 + wc * 64 + n * 16 + fr;
#pragma unroll
        for (int j = 0; j < 4; ++j) {
          size_t o = (size_t)(r + j) * ldc + c;
          if (EPI == EPI_F32) outF[o] = acc[m][n][j];
          else                outF[o] = acc[m][n][j] + resid[o];
        }
      }
    }
  }
}

// ---------------- GEMM2 split-K: partial[z] = uc[:,zK:(z+1)K] @ Wxp^T ------
// BM=64, BN=128, 256 thr (4 waves 2x2), K-chunk 256 (8 BK=32 tiles).
// grid (128, 1, 8). 1024 blocks -> 4/CU, 16 waves/CU: latency hidden
// (old single-chunk version was 1 wave/SIMD with 64 exposed drains).
__global__ __launch_bounds__(256)
void gemm2sk_k(const u16* __restrict__ A, const u16* __restrict__ Bm,
               float* __restrict__ partial) {
  constexpr int K = NB_H;
  __shared__ u16 smem[(64 + 128) * 32];
  u16* As = smem;
  u16* Bs = smem + 64 * 32;
  const int tid  = threadIdx.x;
  const int lane = tid & 63;
  const int wave = tid >> 6;
  const int wr = wave >> 1, wc = wave & 1;
  const int row0 = blockIdx.x * 64;
  const int z = blockIdx.z;
  f32x4 acc[2][4] = {};

  const int r_ld = tid >> 2;            // 0..63
  const int kb   = (((tid & 3) ^ ((tid >> 3) & 3)) * 8);
  const size_t a_base = (size_t)(row0 + r_ld) * K + kb;
  const size_t b_base = (size_t)r_ld * K + kb;
  u16* lA = As + tid * 8;
  u16* lB = Bs + tid * 8;

  const int fr = lane & 15;
  const int fq = lane >> 4;
  const int fkx = ((fq ^ ((fr >> 1) & 3)) * 8);

  for (int kt = 0; kt < 8; ++kt) {
    const int k0 = z * 256 + kt * 32;
    __syncthreads();
    stage16(A + a_base + k0, lA);
#pragma unroll
    for (int hh = 0; hh < 2; ++hh)
      stage16(Bm + b_base + (size_t)(hh * 64) * K + k0, lB + hh * 64 * 32);
    __syncthreads();
    bf16x8 af[2], bfr[4];
#pragma unroll
    for (int m = 0; m < 2; ++m)
      af[m] = *reinterpret_cast<const bf16x8*>(&As[(wr * 32 + m * 16 + fr) * 32 + fkx]);
#pragma unroll
    for (int n = 0; n < 4; ++n)
      bfr[n] = *reinterpret_cast<const bf16x8*>(&Bs[(wc * 64 + n * 16 + fr) * 32 + fkx]);
#pragma unroll
    for (int m = 0; m < 2; ++m)
#pragma unroll
      for (int n = 0; n < 4; ++n)
        acc[m][n] = __builtin_amdgcn_mfma_f32_16x16x32_bf16(af[m], bfr[n], acc[m][n], 0, 0, 0);
  }

  float* outp = partial + (size_t)z * (NB_TOK * 128);
#pragma unroll
  for (int m = 0; m < 2; ++m) {
    const int r = row0 + wr * 32 + m * 16 + fq * 4;
#pragma unroll
    for (int n = 0; n < 4; ++n) {
      const int c = wc * 64 + n * 16 + fr;
#pragma unroll
      for (int j = 0; j < 4; ++j)
        outp[(size_t)(r + j) * 128 + c] = acc[m][n][j];
    }
  }
}

// reduce 8 partials -> xdbl f32 + dtp bf16 (cols<64)
__global__ void reduce_xdbl_k(const float* __restrict__ partial,
                              float* __restrict__ xdbl, u16* __restrict__ dtp) {
  int i = blockIdx.x * 256 + threadIdx.x;   // 8192*128
  float s = 0.f;
#pragma unroll
  for (int zz = 0; zz < 8; ++zz) s += partial[(size_t)zz * (NB_TOK * 128) + i];
  xdbl[i] = s;
  int col = i & 127;
  if (col < NB_DTR) dtp[(size_t)(i >> 7) * NB_DTR + col] = f2b(s);
}

// ---------------- depthwise conv (k=3, pad 1) + silu ----------------
__global__ void dwconv_silu_k(const u16* __restrict__ xz, const float* __restrict__ cw,
                              const float* __restrict__ cb, u16* __restrict__ uc) {
  int i = blockIdx.x * 256 + threadIdx.x;     // over 8192*2048/8
  int hb = i & (NB_H / 8 - 1);
  int t = i >> 8;
  int l = t & (NB_L - 1);
  int h0 = hb * 8;
  const u16* base = xz + (size_t)t * 4096 + h0;
  u16x8 vm = *reinterpret_cast<const u16x8*>(base);
  u16x8 vq = {}, vp = {};
  if (l > 0)          vq = *reinterpret_cast<const u16x8*>(base - 4096);
  if (l < NB_L - 1)   vp = *reinterpret_cast<const u16x8*>(base + 4096);
  u16x8 o;
#pragma unroll
  for (int j = 0; j < 8; ++j) {
    int h = h0 + j;
    float acc = cb[h];
    acc = __builtin_fmaf(b2f(vq[j]), cw[h * 3 + 0], acc);
    acc = __builtin_fmaf(b2f(vm[j]), cw[h * 3 + 1], acc);
    acc = __builtin_fmaf(b2f(vp[j]), cw[h * 3 + 2], acc);
    float s = acc / (1.f + __expf(-acc));
    o[j] = f2b(s);
  }
  *reinterpret_cast<u16x8*>(uc + (size_t)t * NB_H + h0) = o;
}

// ---------------- chunked selective scan (summaries in bf16) ----------------
__global__ __launch_bounds__(256)
void scan_passA_k(const u16* __restrict__ dt, const u16* __restrict__ uc,
                  const float* __restrict__ xdbl, const float* __restrict__ A_log,
                  u16* __restrict__ dPout, u16* __restrict__ Sout) {
  __shared__ float bc[CLEN][32];
  const int tid = threadIdx.x;
  int idx = blockIdx.x * 256 + tid;   // 4*64*2048
  int h = idx & (NB_H - 1);
  int ck = (idx >> 11) & (NCHUNK - 1);
  int b = idx >> 17;
  const int t0 = b * NB_L + ck * CLEN;
  {
    int r = tid >> 3, q = tid & 7;
    *reinterpret_cast<float4*>(&bc[r][q * 4]) =
        *reinterpret_cast<const float4*>(xdbl + (size_t)(t0 + r) * 128 + 64 + q * 4);
  }
  float An[NB_NS];
#pragma unroll
  for (int n = 0; n < NB_NS; ++n) An[n] = -__expf(A_log[n]);
  float P[NB_NS], S[NB_NS];
#pragma unroll
  for (int n = 0; n < NB_NS; ++n) { P[n] = 1.f; S[n] = 0.f; }
  __syncthreads();
  const u16* up = uc + (size_t)t0 * NB_H + h;
  const u16* dp = dt + (size_t)t0 * NB_H + h;
  float uA = b2f(up[0]),       dA = b2f(dp[0]);
  float uB = b2f(up[NB_H]),    dB = b2f(dp[NB_H]);
  for (int tt = 0; tt < CLEN; ++tt) {
    float uC = 0.f, dC = 0.f;
    if (tt + 2 < CLEN) { uC = b2f(up[2 * NB_H]); dC = b2f(dp[2 * NB_H]); }
    up += NB_H; dp += NB_H;
    float4 B0 = *reinterpret_cast<const float4*>(&bc[tt][0]);
    float4 B1 = *reinterpret_cast<const float4*>(&bc[tt][4]);
    float4 B2 = *reinterpret_cast<const float4*>(&bc[tt][8]);
    float4 B3 = *reinterpret_cast<const float4*>(&bc[tt][12]);
    const float Bf[NB_NS] = {B0.x, B0.y, B0.z, B0.w, B1.x, B1.y, B1.z, B1.w,
                             B2.x, B2.y, B2.z, B2.w, B3.x, B3.y, B3.z, B3.w};
#pragma unroll
    for (int n = 0; n < NB_NS; ++n) {
      float e = exp_small(dA * An[n]);
      P[n] *= e;
      S[n] = __builtin_fmaf(e, S[n], Bf[n] * uA);
    }
    uA = uB; dA = dB; uB = uC; dB = dC;
  }
#pragma unroll
  for (int n = 0; n < NB_NS; ++n) {
    size_t o = ((((size_t)b * NCHUNK + ck) * NB_NS + n) * NB_H + h);
    dPout[o] = f2b(1.0f - P[n]);
    Sout[o]  = f2b(S[n]);
  }
}

// pass B: sequential combine over chunks; Hst (bf16) written in-place over dP.
__global__ void scan_passB_k(u16* __restrict__ dP, const u16* __restrict__ S) {
  int idx = blockIdx.x * 256 + threadIdx.x;   // 4*16*2048
  int h = idx & (NB_H - 1);
  int n = (idx >> 11) & (NB_NS - 1);
  int b = idx >> 15;
  const size_t stride = (size_t)NB_NS * NB_H;
  size_t o = ((size_t)b * NCHUNK * NB_NS + n) * NB_H + h;
  float hs = 0.f;
  float p0 = 1.f - b2f(dP[o]), s0 = b2f(S[o]);
  for (int ck = 0; ck < NCHUNK; ++ck) {
    float p1 = 1.f, s1 = 0.f;
    if (ck + 1 < NCHUNK) { p1 = 1.f - b2f(dP[o + stride]); s1 = b2f(S[o + stride]); }
    dP[o] = f2b(hs);                 // Hst
    hs = __builtin_fmaf(p0, hs, s0);
    o += stride; p0 = p1; s0 = s1;
  }
}

__global__ __launch_bounds__(256)
void scan_passC_k(const u16* __restrict__ dt, const u16* __restrict__ uc,
                  const float* __restrict__ xdbl, const u16* __restrict__ xz,
                  const float* __restrict__ A_log, const float* __restrict__ Dp,
                  const u16* __restrict__ Hst, u16* __restrict__ ybf) {
  __shared__ float bc[CLEN][32];
  const int tid = threadIdx.x;
  int idx = blockIdx.x * 256 + tid;   // 4*64*2048
  int h = idx & (NB_H - 1);
  int ck = (idx >> 11) & (NCHUNK - 1);
  int b = idx >> 17;
  const int t0 = b * NB_L + ck * CLEN;
  {
    int r = tid >> 3, q = tid & 7;
    *reinterpret_cast<float4*>(&bc[r][q * 4]) =
        *reinterpret_cast<const float4*>(xdbl + (size_t)(t0 + r) * 128 + 64 + q * 4);
  }
  float An[NB_NS];
#pragma unroll
  for (int n = 0; n < NB_NS; ++n) An[n] = -__expf(A_log[n]);
  float s[NB_NS];
#pragma unroll
  for (int n = 0; n < NB_NS; ++n)
    s[n] = b2f(Hst[((((size_t)b * NCHUNK + ck) * NB_NS + n) * NB_H + h)]);
  const float Dh = Dp[h];
  __syncthreads();
  const u16* up = uc + (size_t)t0 * NB_H + h;
  const u16* dp = dt + (size_t)t0 * NB_H + h;
  const u16* zp = xz + (size_t)t0 * 4096 + NB_H + h;
  u16* yp = ybf + (size_t)t0 * NB_H + h;
  float uA = b2f(up[0]),    dA = b2f(dp[0]),    zA = b2f(zp[0]);
  float uB = b2f(up[NB_H]), dB = b2f(dp[NB_H]), zB = b2f(zp[4096]);
  for (int tt = 0; tt < CLEN; ++tt) {
    float uC = 0.f, dC = 0.f, zC = 0.f;
    if (tt + 2 < CLEN) {
      uC = b2f(up[2 * NB_H]); dC = b2f(dp[2 * NB_H]); zC = b2f(zp[2 * 4096]);
    }
    up += NB_H; dp += NB_H; zp += 4096;
    float4 B0 = *reinterpret_cast<const float4*>(&bc[tt][0]);
    float4 B1 = *reinterpret_cast<const float4*>(&bc[tt][4]);
    float4 B2 = *reinterpret_cast<const float4*>(&bc[tt][8]);
    float4 B3 = *reinterpret_cast<const float4*>(&bc[tt][12]);
    float4 C0 = *reinterpret_cast<const float4*>(&bc[tt][16]);
    float4 C1 = *reinterpret_cast<const float4*>(&bc[tt][20]);
    float4 C2 = *reinterpret_cast<const float4*>(&bc[tt][24]);
    float4 C3 = *reinterpret_cast<const float4*>(&bc[tt][28]);
    const float Bf[NB_NS] = {B0.x, B0.y, B0.z, B0.w, B1.x, B1.y, B1.z, B1.w,
                             B2.x, B2.y, B2.z, B2.w, B3.x, B3.y, B3.z, B3.w};
    const float Cf[NB_NS] = {C0.x, C0.y, C0.z, C0.w, C1.x, C1.y, C1.z, C1.w,
                             C2.x, C2.y, C2.z, C2.w, C3.x, C3.y, C3.z, C3.w};
    float y = 0.f;
#pragma unroll
    for (int n = 0; n < NB_NS; ++n) {
      float e = exp_small(dA * An[n]);
      s[n] = __builtin_fmaf(e, s[n], Bf[n] * uA);
      y = __builtin_fmaf(Cf[n], s[n], y);
    }
    float v = __builtin_fmaf(Dh, uA, y);
    float g = zA / (1.f + __expf(-zA));
    *yp = f2b(v * g);
    yp += NB_H;
    uA = uB; dA = dB; zA = zB; uB = uC; dB = dC; zB = zC;
  }
}

// ---------------- launcher ----------------
extern "C" void kernel_launch(void* const* d_in, const int* in_sizes, int n_in,
                              void* d_out, int out_size, void* d_ws, size_t ws_size,
                              hipStream_t stream) {
  const float* x      = (const float*)d_in[0];
  const float* W_in   = (const float*)d_in[1];
  const float* conv_w = (const float*)d_in[2];
  const float* conv_b = (const float*)d_in[3];
  const float* W_xprj = (const float*)d_in[4];
  const float* W_dt   = (const float*)d_in[5];
  const float* b_dt   = (const float*)d_in[6];
  const float* A_log  = (const float*)d_in[7];
  const float* Dp     = (const float*)d_in[8];
  const float* W_out  = (const float*)d_in[9];
  float* out = (float*)d_out;

  char* ws = (char*)d_ws;
  size_t off = 0;
  auto alloc = [&](size_t bytes) {
    void* p = ws + off;
    off += (bytes + 255) & ~(size_t)255;
    return p;
  };
  u16*   xz_b   = (u16*)alloc((size_t)NB_TOK * 4096 * 2);     // 64MB
  u16*   x_b    = (u16*)alloc((size_t)NB_TOK * NB_DIM * 2);   // 16MB
  u16*   win_b  = (u16*)alloc((size_t)4096 * NB_DIM * 2);     // 8MB
  u16*   wxp_b  = (u16*)alloc((size_t)128 * NB_H * 2);        // 512KB
  u16*   wdt_b  = (u16*)alloc((size_t)NB_H * NB_DTR * 2);     // 256KB
  u16*   wout_b = (u16*)alloc((size_t)NB_DIM * NB_H * 2);     // 4MB
  u16*   uc_b   = (u16*)alloc((size_t)NB_TOK * NB_H * 2);     // 32MB
  float* xdbl   = (float*)alloc((size_t)NB_TOK * 128 * 4);    // 4MB
  u16*   dtp_b  = (u16*)alloc((size_t)NB_TOK * NB_DTR * 2);   // 1MB
  u16*   dt_b   = (u16*)alloc((size_t)NB_TOK * NB_H * 2);     // 32MB
  u16*   scdP   = (u16*)alloc((size_t)NB_B * NCHUNK * NB_NS * NB_H * 2); // 16MB (dP -> Hst)
  u16*   scS    = (u16*)alloc((size_t)NB_B * NCHUNK * NB_NS * NB_H * 2); // 16MB
  u16*   y_b    = (u16*)alloc((size_t)NB_TOK * NB_H * 2);     // 32MB
  // split-K partials (32MB) alias scdP+scS: consumed by reduce_xdbl_k BEFORE
  // scan_passA_k writes scdP/scS (stream-ordered).
  float* g2part = (float*)scdP;
  (void)ws_size; (void)in_sizes; (void)n_in; (void)out_size;

  cvt_all_k<<<(CVT_N5 + 255) / 256, 256, 0, stream>>>(
      x, W_in, W_dt, W_out, W_xprj, x_b, win_b, wdt_b, wout_b, wxp_b);

  // GEMM1: xz = x @ W_in^T  (tiles 32x16): XCD chunks 8x8, chunk grid 4x2
  gemm8p_k<EPI_BF16, 256><<<512, 512, 0, stream>>>(
      x_b, win_b, NB_DIM, 4096, xz_b, nullptr, nullptr, nullptr, 8, 8, 2);

  dwconv_silu_k<<<(NB_TOK * NB_H / 8) / 256, 256, 0, stream>>>(xz_b, conv_w, conv_b, uc_b);

  // GEMM2 split-K=8 -> partials; reduce -> xdbl f32 + dtp bf16
  gemm2sk_k<<<dim3(128, 1, 8), 256, 0, stream>>>(uc_b, wxp_b, g2part);
  reduce_xdbl_k<<<(NB_TOK * 128) / 256, 256, 0, stream>>>(g2part, xdbl, dtp_b);

  // GEMM3: dt = softplus(dtp @ W_dt^T + b_dt)  (BM=128: tiles 64x8, chunks 8x8)
  gemm8p_k<EPI_SP_BF16, 128><<<512, 512, 0, stream>>>(
      dtp_b, wdt_b, NB_DTR, NB_H, dt_b, nullptr, b_dt, nullptr, 8, 8, 1);

  scan_passA_k<<<(NB_B * NCHUNK * NB_H) / 256, 256, 0, stream>>>(dt_b, uc_b, xdbl, A_log, scdP, scS);
  scan_passB_k<<<(NB_B * NB_NS * NB_H) / 256, 256, 0, stream>>>(scdP, scS);
  scan_passC_k<<<(NB_B * NCHUNK * NB_H) / 256, 256, 0, stream>>>(dt_b, uc_b, xdbl, xz_b, A_log, Dp, scdP, y_b);

  // GEMM4: out = y @ W_out^T + x  (tiles 64x4, BM=128): chunks 8x4
  gemm8p_k<EPI_RES_F32, 128><<<256, 512, 0, stream>>>(
      y_b, wout_b, NB_H, NB_DIM, nullptr, out, nullptr, x, 8, 4, 1);
}

// Round 12
// 303.436 us; speedup vs baseline: 1.3713x; 1.0198x over previous
//
#include <hip/hip_runtime.h>
#include <cmath>

typedef unsigned short u16;
typedef __bf16 bf16x8 __attribute__((ext_vector_type(8)));
typedef float f32x4 __attribute__((ext_vector_type(4)));
typedef unsigned short u16x8 __attribute__((ext_vector_type(8)));

#define NB_B   4
#define NB_L   2048
#define NB_DIM 1024
#define NB_H   2048
#define NB_NS  16
#define NB_DTR 64
#define NB_TOK (NB_B * NB_L)   // 8192
#define NCHUNK 64
#define CLEN   32              // NB_L / NCHUNK

__device__ __forceinline__ u16 f2b(float f) {
  union { float f; unsigned u; } v; v.f = f;
  unsigned r = v.u + 0x7fffu + ((v.u >> 16) & 1u);
  return (u16)(r >> 16);
}
__device__ __forceinline__ float b2f(u16 h) {
  union { unsigned u; float f; } v; v.u = ((unsigned)h) << 16;
  return v.f;
}
// exp(w) for |w| <= ~2e-4 here: 1 + w + w^2/2, err ~ |w|^3/6
__device__ __forceinline__ float exp_small(float w) {
  return __builtin_fmaf(w, __builtin_fmaf(w, 0.5f, 1.0f), 1.0f);
}

// ---------------- fused converts (x, W_in, W_dt, W_out, W_xproj+pad) --------
#define CVT_N0 2097152                      // x          f4
#define CVT_N1 (CVT_N0 + 1048576)           // W_in       f4
#define CVT_N2 (CVT_N1 + 32768)             // W_dt       f4
#define CVT_N3 (CVT_N2 + 524288)            // W_out      f4
#define CVT_N4 (CVT_N3 + 49152)             // W_xproj    f4 (96*2048/4)
#define CVT_N5 (CVT_N4 + 8192)              // xproj pad  u16x8 (32*2048/8)
__global__ void cvt_all_k(const float* __restrict__ x, const float* __restrict__ W_in,
                          const float* __restrict__ W_dt, const float* __restrict__ W_out,
                          const float* __restrict__ W_xp,
                          u16* __restrict__ xb, u16* __restrict__ winb,
                          u16* __restrict__ wdtb, u16* __restrict__ woutb,
                          u16* __restrict__ wxpb) {
  int i = blockIdx.x * 256 + threadIdx.x;
  if (i >= CVT_N5) return;
  if (i >= CVT_N4) {   // zero pad rows 96..127 of wxp
    int q = i - CVT_N4;
    u16x8 z = {};
    *reinterpret_cast<u16x8*>(wxpb + 96 * 2048 + q * 8) = z;
    return;
  }
  const float* src; u16* dst; int off;
  if (i < CVT_N0)      { src = x;     dst = xb;    off = i; }
  else if (i < CVT_N1) { src = W_in;  dst = winb;  off = i - CVT_N0; }
  else if (i < CVT_N2) { src = W_dt;  dst = wdtb;  off = i - CVT_N1; }
  else if (i < CVT_N3) { src = W_out; dst = woutb; off = i - CVT_N2; }
  else                 { src = W_xp;  dst = wxpb;  off = i - CVT_N3; }
  float4 v = reinterpret_cast<const float4*>(src)[off];
  ushort4 o;
  o.x = f2b(v.x); o.y = f2b(v.y); o.z = f2b(v.z); o.w = f2b(v.w);
  reinterpret_cast<ushort4*>(dst)[off] = o;
}

#define EPI_BF16    0
#define EPI_F32     1
#define EPI_SP_BF16 2
#define EPI_RES_F32 3

__device__ __forceinline__ void stage16(const u16* g, u16* l) {
  __builtin_amdgcn_global_load_lds(
      (const __attribute__((address_space(1))) unsigned int*)g,
      (__attribute__((address_space(3))) unsigned int*)l, 16, 0, 0);
}

// ============ 1-barrier/K-tile pipelined GEMM (BK=64, BN=256) ==============
// C = A(MxK)*B(NxK)^T bf16. 512 thr = 8 waves (2x4), wave tile (BM/2)x64.
// Tile kt lives in buf[kt&1]; tile kt+1 staged into buf[bi^1] DURING tile kt
// (issued right after kt's barrier -> a full tile body of latency cover).
// Invariants: (a) vmcnt(0)+s_barrier at tile start => all waves' tile-kt
// loads landed (each wave drains its own vmcnt BEFORE the barrier);
// (b) staging buf[bi^1] is safe because every wave passed kt's barrier only
// after its last lgkm(0) of tile kt-1 (all reads of buf[bi^1] retired).
// No mid-tile barriers: waves drift within a tile -> MFMA/mem overlap, and
// setprio has role diversity to arbitrate. sched_barrier(0) after each
// inline-asm wait per rule #18 (stops register-only MFMA hoisting).
template <int EPI, int BM>
__global__ __launch_bounds__(512, 1)
void gemm8p_k(const u16* __restrict__ A, const u16* __restrict__ Bm,
              int K, int ldc,
              u16* __restrict__ outB, float* __restrict__ outF,
              const float* __restrict__ bias, const float* __restrict__ resid,
              int cr, int cc, int ncx) {
  constexpr int MR = BM / 32;          // m-frags per wave
  constexpr int MH = MR / 2;
  constexpr int HA = BM / 2;           // A staging-half rows
  constexpr int LA = BM / 128;         // gloads per thread per A-half
  constexpr int BUFE = (BM + 256) * 64; // u16 per buffer
  __shared__ u16 smem[2 * BUFE];

  const int tid  = threadIdx.x;
  const int lane = tid & 63;
  const int wave = tid >> 6;
  const int wr = wave >> 2, wc = wave & 3;
  const int fr = lane & 15, fq = lane >> 4;

  const int bid = blockIdx.x;
  const int e = bid & 7, w = bid >> 3;
  const int row0 = ((e / ncx) * cr + (w % cr)) * BM;
  const int col0 = ((e % ncx) * cc + (w / cr)) * 256;

  f32x4 acc[MR][4] = {};
  bf16x8 bB[4][2], bA0[MH][2], bA1[MH][2];

  auto STAGE_B = [&](int kt) {
    const int k0 = kt * 64;
    u16* base = smem + (kt & 1) * BUFE + BM * 64;
#pragma unroll
    for (int h = 0; h < 2; ++h)
#pragma unroll
      for (int l = 0; l < 2; ++l) {
        int c = l * 512 + tid;
        int rih = c >> 3, p = c & 7;
        stage16(Bm + (size_t)(col0 + h * 128 + rih) * K + k0 + ((p ^ (rih & 7)) * 8),
                base + (h * 128 + rih) * 64 + p * 8);
      }
  };
  auto STAGE_A = [&](int kt) {
    const int k0 = kt * 64;
    u16* base = smem + (kt & 1) * BUFE;
#pragma unroll
    for (int h = 0; h < 2; ++h)
#pragma unroll
      for (int l = 0; l < LA; ++l) {
        int c = l * 512 + tid;
        int rih = c >> 3, p = c & 7;
        stage16(A + (size_t)(row0 + h * HA + rih) * K + k0 + ((p ^ (rih & 7)) * 8),
                base + (h * HA + rih) * 64 + p * 8);
      }
  };
  auto LD_A = [&](int m, int kk, int bi) {
    int rt = wr * HA + m * 16 + fr;
    int p = (kk * 4 + fq) ^ (rt & 7);
    return *reinterpret_cast<const bf16x8*>(smem + bi * BUFE + rt * 64 + p * 8);
  };
  auto LD_B = [&](int n, int kk, int bi) {
    int rt = wc * 64 + n * 16 + fr;
    int p = (kk * 4 + fq) ^ (rt & 7);
    return *reinterpret_cast<const bf16x8*>(smem + bi * BUFE + BM * 64 + rt * 64 + p * 8);
  };

  const int nk = K >> 6;
  // ---- prologue: stage tile 0 only (loop is self-contained)
  STAGE_B(0); STAGE_A(0);

  for (int kt = 0; kt < nk; ++kt) {
    const int bi = kt & 1;
    // tile gate: own loads drained BEFORE barrier -> after barrier, ALL
    // waves' tile-kt loads are in LDS, and buf[bi^1] is free to overwrite.
    asm volatile("s_waitcnt vmcnt(0)" ::: "memory");
    __builtin_amdgcn_s_barrier();
    __builtin_amdgcn_sched_barrier(0);
    // issue next tile's B (lands ~a full tile later)
    if (kt + 1 < nk) STAGE_B(kt + 1);
    // ds_read: all B frags + A-mh0 frags of tile kt
#pragma unroll
    for (int n = 0; n < 4; ++n) { bB[n][0] = LD_B(n, 0, bi); bB[n][1] = LD_B(n, 1, bi); }
#pragma unroll
    for (int m = 0; m < MH; ++m) { bA0[m][0] = LD_A(m, 0, bi); bA0[m][1] = LD_A(m, 1, bi); }
    asm volatile("s_waitcnt lgkmcnt(0)" ::: "memory");
    __builtin_amdgcn_sched_barrier(0);
    // Q0: A-mh0 x B-n{0,1}
    __builtin_amdgcn_s_setprio(1);
#pragma unroll
    for (int m = 0; m < MH; ++m)
#pragma unroll
      for (int n = 0; n < 2; ++n)
#pragma unroll
        for (int kk = 0; kk < 2; ++kk)
          acc[m][n] = __builtin_amdgcn_mfma_f32_16x16x32_bf16(bA0[m][kk], bB[n][kk], acc[m][n], 0, 0, 0);
    __builtin_amdgcn_s_setprio(0);
    // issue next tile's A; read A-mh1 of tile kt
    if (kt + 1 < nk) STAGE_A(kt + 1);
#pragma unroll
    for (int m = 0; m < MH; ++m) { bA1[m][0] = LD_A(MH + m, 0, bi); bA1[m][1] = LD_A(MH + m, 1, bi); }
    // Q1: A-mh0 x B-n{2,3} (operands already landed)
    __builtin_amdgcn_s_setprio(1);
#pragma unroll
    for (int m = 0; m < MH; ++m)
#pragma unroll
      for (int n = 2; n < 4; ++n)
#pragma unroll
        for (int kk = 0; kk < 2; ++kk)
          acc[m][n] = __builtin_amdgcn_mfma_f32_16x16x32_bf16(bA0[m][kk], bB[n][kk], acc[m][n], 0, 0, 0);
    __builtin_amdgcn_s_setprio(0);
    asm volatile("s_waitcnt lgkmcnt(0)" ::: "memory");
    __builtin_amdgcn_sched_barrier(0);
    // Q2 + Q3: A-mh1 x B-all (register-only from here)
    __builtin_amdgcn_s_setprio(1);
#pragma unroll
    for (int m = 0; m < MH; ++m)
#pragma unroll
      for (int n = 0; n < 2; ++n)
#pragma unroll
        for (int kk = 0; kk < 2; ++kk)
          acc[MH + m][n] = __builtin_amdgcn_mfma_f32_16x16x32_bf16(bA1[m][kk], bB[n][kk], acc[MH + m][n], 0, 0, 0);
#pragma unroll
    for (int m = 0; m < MH; ++m)
#pragma unroll
      for (int n = 2; n < 4; ++n)
#pragma unroll
        for (int kk = 0; kk < 2; ++kk)
          acc[MH + m][n] = __builtin_amdgcn_mfma_f32_16x16x32_bf16(bA1[m][kk], bB[n][kk], acc[MH + m][n], 0, 0, 0);
    __builtin_amdgcn_s_setprio(0);
  }

  __syncthreads();   // all waves' LDS reads retired before epilogue smem reuse

  // ---- epilogue. bf16 paths: per-wave LDS bounce in bf16, row stride 72 u16
  // (144B) -> read lanes balance across all 8 bank-quads (no 16-way conflict).
  if constexpr (EPI == EPI_BF16 || EPI == EPI_SP_BF16) {
    u16* wv = smem + wave * 1152;   // 16 rows x 72 u16 per wave
#pragma unroll
    for (int m = 0; m < MR; ++m) {
#pragma unroll
      for (int n = 0; n < 4; ++n) {
        const int c = col0 + wc * 64 + n * 16 + fr;
        float bv = (EPI == EPI_SP_BF16) ? bias[c] : 0.f;
#pragma unroll
        for (int j = 0; j < 4; ++j) {
          float v = acc[m][n][j];
          if (EPI == EPI_SP_BF16) {
            float xx = v + bv;
            float t = __expf(xx);
            float sp = (xx > -5.f) ? log1pf(t) : t;
            v = (xx > 20.f) ? xx : sp;
          }
          wv[(fq * 4 + j) * 72 + n * 16 + fr] = f2b(v);
        }
      }
#pragma unroll
      for (int p = 0; p < 2; ++p) {
        const int rf = p * 8 + (lane >> 3);
        const int c0 = (lane & 7) * 8;
        u16x8 ov = *reinterpret_cast<const u16x8*>(wv + rf * 72 + c0);
        const int grow = row0 + wr * HA + m * 16 + rf;
        const int gcol = col0 + wc * 64 + c0;
        *reinterpret_cast<u16x8*>(&outB[(size_t)grow * ldc + gcol]) = ov;
      }
    }
  } else {
#pragma unroll
    for (int m = 0; m < MR; ++m) {
      const int r = row0 + wr * HA + m * 16 + fq * 4;
#pragma unroll
      for (int n = 0; n < 4; ++n) {
        const int c = col0 + wc * 64 + n * 16 + fr;
#pragma unroll
        for (int j = 0; j < 4; ++j) {
          size_t o = (size_t)(r + j) * ldc + c;
          if (EPI == EPI_F32) outF[o] = acc[m][n][j];
          else                outF[o] = acc[m][n][j] + resid[o];
        }
      }
    }
  }
}

// ---------------- GEMM2 split-K: partial[z] = uc[:,zK:(z+1)K] @ Wxp^T ------
__global__ __launch_bounds__(256)
void gemm2sk_k(const u16* __restrict__ A, const u16* __restrict__ Bm,
               float* __restrict__ partial) {
  constexpr int K = NB_H;
  __shared__ u16 smem[(64 + 128) * 32];
  u16* As = smem;
  u16* Bs = smem + 64 * 32;
  const int tid  = threadIdx.x;
  const int lane = tid & 63;
  const int wave = tid >> 6;
  const int wr = wave >> 1, wc = wave & 1;
  const int row0 = blockIdx.x * 64;
  const int z = blockIdx.z;
  f32x4 acc[2][4] = {};

  const int r_ld = tid >> 2;            // 0..63
  const int kb   = (((tid & 3) ^ ((tid >> 3) & 3)) * 8);
  const size_t a_base = (size_t)(row0 + r_ld) * K + kb;
  const size_t b_base = (size_t)r_ld * K + kb;
  u16* lA = As + tid * 8;
  u16* lB = Bs + tid * 8;

  const int fr = lane & 15;
  const int fq = lane >> 4;
  const int fkx = ((fq ^ ((fr >> 1) & 3)) * 8);

  for (int kt = 0; kt < 8; ++kt) {
    const int k0 = z * 256 + kt * 32;
    __syncthreads();
    stage16(A + a_base + k0, lA);
#pragma unroll
    for (int hh = 0; hh < 2; ++hh)
      stage16(Bm + b_base + (size_t)(hh * 64) * K + k0, lB + hh * 64 * 32);
    __syncthreads();
    bf16x8 af[2], bfr[4];
#pragma unroll
    for (int m = 0; m < 2; ++m)
      af[m] = *reinterpret_cast<const bf16x8*>(&As[(wr * 32 + m * 16 + fr) * 32 + fkx]);
#pragma unroll
    for (int n = 0; n < 4; ++n)
      bfr[n] = *reinterpret_cast<const bf16x8*>(&Bs[(wc * 64 + n * 16 + fr) * 32 + fkx]);
#pragma unroll
    for (int m = 0; m < 2; ++m)
#pragma unroll
      for (int n = 0; n < 4; ++n)
        acc[m][n] = __builtin_amdgcn_mfma_f32_16x16x32_bf16(af[m], bfr[n], acc[m][n], 0, 0, 0);
  }

  float* outp = partial + (size_t)z * (NB_TOK * 128);
#pragma unroll
  for (int m = 0; m < 2; ++m) {
    const int r = row0 + wr * 32 + m * 16 + fq * 4;
#pragma unroll
    for (int n = 0; n < 4; ++n) {
      const int c = wc * 64 + n * 16 + fr;
#pragma unroll
      for (int j = 0; j < 4; ++j)
        outp[(size_t)(r + j) * 128 + c] = acc[m][n][j];
    }
  }
}

// reduce 8 partials -> xdbl f32 + dtp bf16 (cols<64)
__global__ void reduce_xdbl_k(const float* __restrict__ partial,
                              float* __restrict__ xdbl, u16* __restrict__ dtp) {
  int i = blockIdx.x * 256 + threadIdx.x;   // 8192*128
  float s = 0.f;
#pragma unroll
  for (int zz = 0; zz < 8; ++zz) s += partial[(size_t)zz * (NB_TOK * 128) + i];
  xdbl[i] = s;
  int col = i & 127;
  if (col < NB_DTR) dtp[(size_t)(i >> 7) * NB_DTR + col] = f2b(s);
}

// ---------------- depthwise conv (k=3, pad 1) + silu ----------------
__global__ void dwconv_silu_k(const u16* __restrict__ xz, const float* __restrict__ cw,
                              const float* __restrict__ cb, u16* __restrict__ uc) {
  int i = blockIdx.x * 256 + threadIdx.x;     // over 8192*2048/8
  int hb = i & (NB_H / 8 - 1);
  int t = i >> 8;
  int l = t & (NB_L - 1);
  int h0 = hb * 8;
  const u16* base = xz + (size_t)t * 4096 + h0;
  u16x8 vm = *reinterpret_cast<const u16x8*>(base);
  u16x8 vq = {}, vp = {};
  if (l > 0)          vq = *reinterpret_cast<const u16x8*>(base - 4096);
  if (l < NB_L - 1)   vp = *reinterpret_cast<const u16x8*>(base + 4096);
  u16x8 o;
#pragma unroll
  for (int j = 0; j < 8; ++j) {
    int h = h0 + j;
    float acc = cb[h];
    acc = __builtin_fmaf(b2f(vq[j]), cw[h * 3 + 0], acc);
    acc = __builtin_fmaf(b2f(vm[j]), cw[h * 3 + 1], acc);
    acc = __builtin_fmaf(b2f(vp[j]), cw[h * 3 + 2], acc);
    float s = acc / (1.f + __expf(-acc));
    o[j] = f2b(s);
  }
  *reinterpret_cast<u16x8*>(uc + (size_t)t * NB_H + h0) = o;
}

// ---------------- chunked selective scan (summaries in bf16) ----------------
__global__ __launch_bounds__(256)
void scan_passA_k(const u16* __restrict__ dt, const u16* __restrict__ uc,
                  const float* __restrict__ xdbl, const float* __restrict__ A_log,
                  u16* __restrict__ dPout, u16* __restrict__ Sout) {
  __shared__ float bc[CLEN][32];
  const int tid = threadIdx.x;
  int idx = blockIdx.x * 256 + tid;   // 4*64*2048
  int h = idx & (NB_H - 1);
  int ck = (idx >> 11) & (NCHUNK - 1);
  int b = idx >> 17;
  const int t0 = b * NB_L + ck * CLEN;
  {
    int r = tid >> 3, q = tid & 7;
    *reinterpret_cast<float4*>(&bc[r][q * 4]) =
        *reinterpret_cast<const float4*>(xdbl + (size_t)(t0 + r) * 128 + 64 + q * 4);
  }
  float An[NB_NS];
#pragma unroll
  for (int n = 0; n < NB_NS; ++n) An[n] = -__expf(A_log[n]);
  float P[NB_NS], S[NB_NS];
#pragma unroll
  for (int n = 0; n < NB_NS; ++n) { P[n] = 1.f; S[n] = 0.f; }
  __syncthreads();
  const u16* up = uc + (size_t)t0 * NB_H + h;
  const u16* dp = dt + (size_t)t0 * NB_H + h;
  float uA = b2f(up[0]),       dA = b2f(dp[0]);
  float uB = b2f(up[NB_H]),    dB = b2f(dp[NB_H]);
  for (int tt = 0; tt < CLEN; ++tt) {
    float uC = 0.f, dC = 0.f;
    if (tt + 2 < CLEN) { uC = b2f(up[2 * NB_H]); dC = b2f(dp[2 * NB_H]); }
    up += NB_H; dp += NB_H;
    float4 B0 = *reinterpret_cast<const float4*>(&bc[tt][0]);
    float4 B1 = *reinterpret_cast<const float4*>(&bc[tt][4]);
    float4 B2 = *reinterpret_cast<const float4*>(&bc[tt][8]);
    float4 B3 = *reinterpret_cast<const float4*>(&bc[tt][12]);
    const float Bf[NB_NS] = {B0.x, B0.y, B0.z, B0.w, B1.x, B1.y, B1.z, B1.w,
                             B2.x, B2.y, B2.z, B2.w, B3.x, B3.y, B3.z, B3.w};
#pragma unroll
    for (int n = 0; n < NB_NS; ++n) {
      float e = exp_small(dA * An[n]);
      P[n] *= e;
      S[n] = __builtin_fmaf(e, S[n], Bf[n] * uA);
    }
    uA = uB; dA = dB; uB = uC; dB = dC;
  }
#pragma unroll
  for (int n = 0; n < NB_NS; ++n) {
    size_t o = ((((size_t)b * NCHUNK + ck) * NB_NS + n) * NB_H + h);
    dPout[o] = f2b(1.0f - P[n]);
    Sout[o]  = f2b(S[n]);
  }
}

// pass B: sequential combine over chunks; Hst (bf16) written in-place over dP.
__global__ void scan_passB_k(u16* __restrict__ dP, const u16* __restrict__ S) {
  int idx = blockIdx.x * 256 + threadIdx.x;   // 4*16*2048
  int h = idx & (NB_H - 1);
  int n = (idx >> 11) & (NB_NS - 1);
  int b = idx >> 15;
  const size_t stride = (size_t)NB_NS * NB_H;
  size_t o = ((size_t)b * NCHUNK * NB_NS + n) * NB_H + h;
  float hs = 0.f;
  float p0 = 1.f - b2f(dP[o]), s0 = b2f(S[o]);
  for (int ck = 0; ck < NCHUNK; ++ck) {
    float p1 = 1.f, s1 = 0.f;
    if (ck + 1 < NCHUNK) { p1 = 1.f - b2f(dP[o + stride]); s1 = b2f(S[o + stride]); }
    dP[o] = f2b(hs);                 // Hst
    hs = __builtin_fmaf(p0, hs, s0);
    o += stride; p0 = p1; s0 = s1;
  }
}

__global__ __launch_bounds__(256)
void scan_passC_k(const u16* __restrict__ dt, const u16* __restrict__ uc,
                  const float* __restrict__ xdbl, const u16* __restrict__ xz,
                  const float* __restrict__ A_log, const float* __restrict__ Dp,
                  const u16* __restrict__ Hst, u16* __restrict__ ybf) {
  __shared__ float bc[CLEN][32];
  const int tid = threadIdx.x;
  int idx = blockIdx.x * 256 + tid;   // 4*64*2048
  int h = idx & (NB_H - 1);
  int ck = (idx >> 11) & (NCHUNK - 1);
  int b = idx >> 17;
  const int t0 = b * NB_L + ck * CLEN;
  {
    int r = tid >> 3, q = tid & 7;
    *reinterpret_cast<float4*>(&bc[r][q * 4]) =
        *reinterpret_cast<const float4*>(xdbl + (size_t)(t0 + r) * 128 + 64 + q * 4);
  }
  float An[NB_NS];
#pragma unroll
  for (int n = 0; n < NB_NS; ++n) An[n] = -__expf(A_log[n]);
  float s[NB_NS];
#pragma unroll
  for (int n = 0; n < NB_NS; ++n)
    s[n] = b2f(Hst[((((size_t)b * NCHUNK + ck) * NB_NS + n) * NB_H + h)]);
  const float Dh = Dp[h];
  __syncthreads();
  const u16* up = uc + (size_t)t0 * NB_H + h;
  const u16* dp = dt + (size_t)t0 * NB_H + h;
  const u16* zp = xz + (size_t)t0 * 4096 + NB_H + h;
  u16* yp = ybf + (size_t)t0 * NB_H + h;
  float uA = b2f(up[0]),    dA = b2f(dp[0]),    zA = b2f(zp[0]);
  float uB = b2f(up[NB_H]), dB = b2f(dp[NB_H]), zB = b2f(zp[4096]);
  for (int tt = 0; tt < CLEN; ++tt) {
    float uC = 0.f, dC = 0.f, zC = 0.f;
    if (tt + 2 < CLEN) {
      uC = b2f(up[2 * NB_H]); dC = b2f(dp[2 * NB_H]); zC = b2f(zp[2 * 4096]);
    }
    up += NB_H; dp += NB_H; zp += 4096;
    float4 B0 = *reinterpret_cast<const float4*>(&bc[tt][0]);
    float4 B1 = *reinterpret_cast<const float4*>(&bc[tt][4]);
    float4 B2 = *reinterpret_cast<const float4*>(&bc[tt][8]);
    float4 B3 = *reinterpret_cast<const float4*>(&bc[tt][12]);
    float4 C0 = *reinterpret_cast<const float4*>(&bc[tt][16]);
    float4 C1 = *reinterpret_cast<const float4*>(&bc[tt][20]);
    float4 C2 = *reinterpret_cast<const float4*>(&bc[tt][24]);
    float4 C3 = *reinterpret_cast<const float4*>(&bc[tt][28]);
    const float Bf[NB_NS] = {B0.x, B0.y, B0.z, B0.w, B1.x, B1.y, B1.z, B1.w,
                             B2.x, B2.y, B2.z, B2.w, B3.x, B3.y, B3.z, B3.w};
    const float Cf[NB_NS] = {C0.x, C0.y, C0.z, C0.w, C1.x, C1.y, C1.z, C1.w,
                             C2.x, C2.y, C2.z, C2.w, C3.x, C3.y, C3.z, C3.w};
    float y = 0.f;
#pragma unroll
    for (int n = 0; n < NB_NS; ++n) {
      float e = exp_small(dA * An[n]);
      s[n] = __builtin_fmaf(e, s[n], Bf[n] * uA);
      y = __builtin_fmaf(Cf[n], s[n], y);
    }
    float v = __builtin_fmaf(Dh, uA, y);
    float g = zA / (1.f + __expf(-zA));
    *yp = f2b(v * g);
    yp += NB_H;
    uA = uB; dA = dB; zA = zB; uB = uC; dB = dC; zB = zC;
  }
}

// ---------------- launcher ----------------
extern "C" void kernel_launch(void* const* d_in, const int* in_sizes, int n_in,
                              void* d_out, int out_size, void* d_ws, size_t ws_size,
                              hipStream_t stream) {
  const float* x      = (const float*)d_in[0];
  const float* W_in   = (const float*)d_in[1];
  const float* conv_w = (const float*)d_in[2];
  const float* conv_b = (const float*)d_in[3];
  const float* W_xprj = (const float*)d_in[4];
  const float* W_dt   = (const float*)d_in[5];
  const float* b_dt   = (const float*)d_in[6];
  const float* A_log  = (const float*)d_in[7];
  const float* Dp     = (const float*)d_in[8];
  const float* W_out  = (const float*)d_in[9];
  float* out = (float*)d_out;

  char* ws = (char*)d_ws;
  size_t off = 0;
  auto alloc = [&](size_t bytes) {
    void* p = ws + off;
    off += (bytes + 255) & ~(size_t)255;
    return p;
  };
  u16*   xz_b   = (u16*)alloc((size_t)NB_TOK * 4096 * 2);     // 64MB
  u16*   x_b    = (u16*)alloc((size_t)NB_TOK * NB_DIM * 2);   // 16MB
  u16*   win_b  = (u16*)alloc((size_t)4096 * NB_DIM * 2);     // 8MB
  u16*   wxp_b  = (u16*)alloc((size_t)128 * NB_H * 2);        // 512KB
  u16*   wdt_b  = (u16*)alloc((size_t)NB_H * NB_DTR * 2);     // 256KB
  u16*   wout_b = (u16*)alloc((size_t)NB_DIM * NB_H * 2);     // 4MB
  u16*   uc_b   = (u16*)alloc((size_t)NB_TOK * NB_H * 2);     // 32MB
  float* xdbl   = (float*)alloc((size_t)NB_TOK * 128 * 4);    // 4MB
  u16*   dtp_b  = (u16*)alloc((size_t)NB_TOK * NB_DTR * 2);   // 1MB
  u16*   dt_b   = (u16*)alloc((size_t)NB_TOK * NB_H * 2);     // 32MB
  u16*   scdP   = (u16*)alloc((size_t)NB_B * NCHUNK * NB_NS * NB_H * 2); // 16MB (dP -> Hst)
  u16*   scS    = (u16*)alloc((size_t)NB_B * NCHUNK * NB_NS * NB_H * 2); // 16MB
  u16*   y_b    = (u16*)alloc((size_t)NB_TOK * NB_H * 2);     // 32MB
  // split-K partials (32MB) alias scdP+scS: consumed by reduce_xdbl_k BEFORE
  // scan_passA_k writes scdP/scS (stream-ordered).
  float* g2part = (float*)scdP;
  (void)ws_size; (void)in_sizes; (void)n_in; (void)out_size;

  cvt_all_k<<<(CVT_N5 + 255) / 256, 256, 0, stream>>>(
      x, W_in, W_dt, W_out, W_xprj, x_b, win_b, wdt_b, wout_b, wxp_b);

  // GEMM1: xz = x @ W_in^T  (tiles 32x16): XCD chunks 8x8, chunk grid 4x2
  gemm8p_k<EPI_BF16, 256><<<512, 512, 0, stream>>>(
      x_b, win_b, NB_DIM, 4096, xz_b, nullptr, nullptr, nullptr, 8, 8, 2);

  dwconv_silu_k<<<(NB_TOK * NB_H / 8) / 256, 256, 0, stream>>>(xz_b, conv_w, conv_b, uc_b);

  // GEMM2 split-K=8 -> partials; reduce -> xdbl f32 + dtp bf16
  gemm2sk_k<<<dim3(128, 1, 8), 256, 0, stream>>>(uc_b, wxp_b, g2part);
  reduce_xdbl_k<<<(NB_TOK * 128) / 256, 256, 0, stream>>>(g2part, xdbl, dtp_b);

  // GEMM3: dt = softplus(dtp @ W_dt^T + b_dt)  (BM=128: tiles 64x8, chunks 8x8)
  gemm8p_k<EPI_SP_BF16, 128><<<512, 512, 0, stream>>>(
      dtp_b, wdt_b, NB_DTR, NB_H, dt_b, nullptr, b_dt, nullptr, 8, 8, 1);

  scan_passA_k<<<(NB_B * NCHUNK * NB_H) / 256, 256, 0, stream>>>(dt_b, uc_b, xdbl, A_log, scdP, scS);
  scan_passB_k<<<(NB_B * NB_NS * NB_H) / 256, 256, 0, stream>>>(scdP, scS);
  scan_passC_k<<<(NB_B * NCHUNK * NB_H) / 256, 256, 0, stream>>>(dt_b, uc_b, xdbl, xz_b, A_log, Dp, scdP, y_b);

  // GEMM4: out = y @ W_out^T + x  (tiles 64x4, BM=128): chunks 8x4
  gemm8p_k<EPI_RES_F32, 128><<<256, 512, 0, stream>>>(
      y_b, wout_b, NB_H, NB_DIM, nullptr, out, nullptr, x, 8, 4, 1);
}

// Round 13
// 298.543 us; speedup vs baseline: 1.3938x; 1.0164x over previous
//
#include <hip/hip_runtime.h>
#include <cmath>

typedef unsigned short u16;
typedef unsigned int u32;
typedef __bf16 bf16x8 __attribute__((ext_vector_type(8)));
typedef float f32x4 __attribute__((ext_vector_type(4)));
typedef unsigned short u16x8 __attribute__((ext_vector_type(8)));

#define NB_B   4
#define NB_L   2048
#define NB_DIM 1024
#define NB_H   2048
#define NB_NS  16
#define NB_DTR 64
#define NB_TOK (NB_B * NB_L)   // 8192
#define NCHUNK 64
#define CLEN   32              // NB_L / NCHUNK

__device__ __forceinline__ u16 f2b(float f) {
  union { float f; unsigned u; } v; v.f = f;
  unsigned r = v.u + 0x7fffu + ((v.u >> 16) & 1u);
  return (u16)(r >> 16);
}
__device__ __forceinline__ float b2f(u16 h) {
  union { unsigned u; float f; } v; v.u = ((unsigned)h) << 16;
  return v.f;
}
__device__ __forceinline__ float b2f_lo(u32 w) {
  union { unsigned u; float f; } v; v.u = w << 16;
  return v.f;
}
__device__ __forceinline__ float b2f_hi(u32 w) {
  union { unsigned u; float f; } v; v.u = w & 0xffff0000u;
  return v.f;
}
// exp(w) for |w| <= ~2e-4 here: 1 + w + w^2/2, err ~ |w|^3/6
__device__ __forceinline__ float exp_small(float w) {
  return __builtin_fmaf(w, __builtin_fmaf(w, 0.5f, 1.0f), 1.0f);
}

// ---------------- fused converts (x, W_in, W_dt, W_out, W_xproj+pad) --------
#define CVT_N0 2097152                      // x          f4
#define CVT_N1 (CVT_N0 + 1048576)           // W_in       f4
#define CVT_N2 (CVT_N1 + 32768)             // W_dt       f4
#define CVT_N3 (CVT_N2 + 524288)            // W_out      f4
#define CVT_N4 (CVT_N3 + 49152)             // W_xproj    f4 (96*2048/4)
#define CVT_N5 (CVT_N4 + 8192)              // xproj pad  u16x8 (32*2048/8)
__global__ void cvt_all_k(const float* __restrict__ x, const float* __restrict__ W_in,
                          const float* __restrict__ W_dt, const float* __restrict__ W_out,
                          const float* __restrict__ W_xp,
                          u16* __restrict__ xb, u16* __restrict__ winb,
                          u16* __restrict__ wdtb, u16* __restrict__ woutb,
                          u16* __restrict__ wxpb) {
  int i = blockIdx.x * 256 + threadIdx.x;
  if (i >= CVT_N5) return;
  if (i >= CVT_N4) {   // zero pad rows 96..127 of wxp
    int q = i - CVT_N4;
    u16x8 z = {};
    *reinterpret_cast<u16x8*>(wxpb + 96 * 2048 + q * 8) = z;
    return;
  }
  const float* src; u16* dst; int off;
  if (i < CVT_N0)      { src = x;     dst = xb;    off = i; }
  else if (i < CVT_N1) { src = W_in;  dst = winb;  off = i - CVT_N0; }
  else if (i < CVT_N2) { src = W_dt;  dst = wdtb;  off = i - CVT_N1; }
  else if (i < CVT_N3) { src = W_out; dst = woutb; off = i - CVT_N2; }
  else                 { src = W_xp;  dst = wxpb;  off = i - CVT_N3; }
  float4 v = reinterpret_cast<const float4*>(src)[off];
  ushort4 o;
  o.x = f2b(v.x); o.y = f2b(v.y); o.z = f2b(v.z); o.w = f2b(v.w);
  reinterpret_cast<ushort4*>(dst)[off] = o;
}

#define EPI_BF16    0
#define EPI_F32     1
#define EPI_SP_BF16 2
#define EPI_RES_F32 3

__device__ __forceinline__ void stage16(const u16* g, u16* l) {
  __builtin_amdgcn_global_load_lds(
      (const __attribute__((address_space(1))) unsigned int*)g,
      (__attribute__((address_space(3))) unsigned int*)l, 16, 0, 0);
}

// ============ 1-barrier/K-tile pipelined GEMM (BK=64, BN=256) ==============
// (round-12 structure, verbatim: GEMM1 75.5us / MfmaUtil 37% / ~910 TF)
template <int EPI, int BM>
__global__ __launch_bounds__(512, 1)
void gemm8p_k(const u16* __restrict__ A, const u16* __restrict__ Bm,
              int K, int ldc,
              u16* __restrict__ outB, float* __restrict__ outF,
              const float* __restrict__ bias, const float* __restrict__ resid,
              int cr, int cc, int ncx) {
  constexpr int MR = BM / 32;          // m-frags per wave
  constexpr int MH = MR / 2;
  constexpr int HA = BM / 2;           // A staging-half rows
  constexpr int LA = BM / 128;         // gloads per thread per A-half
  constexpr int BUFE = (BM + 256) * 64; // u16 per buffer
  __shared__ u16 smem[2 * BUFE];

  const int tid  = threadIdx.x;
  const int lane = tid & 63;
  const int wave = tid >> 6;
  const int wr = wave >> 2, wc = wave & 3;
  const int fr = lane & 15, fq = lane >> 4;

  const int bid = blockIdx.x;
  const int e = bid & 7, w = bid >> 3;
  const int row0 = ((e / ncx) * cr + (w % cr)) * BM;
  const int col0 = ((e % ncx) * cc + (w / cr)) * 256;

  f32x4 acc[MR][4] = {};
  bf16x8 bB[4][2], bA0[MH][2], bA1[MH][2];

  auto STAGE_B = [&](int kt) {
    const int k0 = kt * 64;
    u16* base = smem + (kt & 1) * BUFE + BM * 64;
#pragma unroll
    for (int h = 0; h < 2; ++h)
#pragma unroll
      for (int l = 0; l < 2; ++l) {
        int c = l * 512 + tid;
        int rih = c >> 3, p = c & 7;
        stage16(Bm + (size_t)(col0 + h * 128 + rih) * K + k0 + ((p ^ (rih & 7)) * 8),
                base + (h * 128 + rih) * 64 + p * 8);
      }
  };
  auto STAGE_A = [&](int kt) {
    const int k0 = kt * 64;
    u16* base = smem + (kt & 1) * BUFE;
#pragma unroll
    for (int h = 0; h < 2; ++h)
#pragma unroll
      for (int l = 0; l < LA; ++l) {
        int c = l * 512 + tid;
        int rih = c >> 3, p = c & 7;
        stage16(A + (size_t)(row0 + h * HA + rih) * K + k0 + ((p ^ (rih & 7)) * 8),
                base + (h * HA + rih) * 64 + p * 8);
      }
  };
  auto LD_A = [&](int m, int kk, int bi) {
    int rt = wr * HA + m * 16 + fr;
    int p = (kk * 4 + fq) ^ (rt & 7);
    return *reinterpret_cast<const bf16x8*>(smem + bi * BUFE + rt * 64 + p * 8);
  };
  auto LD_B = [&](int n, int kk, int bi) {
    int rt = wc * 64 + n * 16 + fr;
    int p = (kk * 4 + fq) ^ (rt & 7);
    return *reinterpret_cast<const bf16x8*>(smem + bi * BUFE + BM * 64 + rt * 64 + p * 8);
  };

  const int nk = K >> 6;
  STAGE_B(0); STAGE_A(0);

  for (int kt = 0; kt < nk; ++kt) {
    const int bi = kt & 1;
    asm volatile("s_waitcnt vmcnt(0)" ::: "memory");
    __builtin_amdgcn_s_barrier();
    __builtin_amdgcn_sched_barrier(0);
    if (kt + 1 < nk) STAGE_B(kt + 1);
#pragma unroll
    for (int n = 0; n < 4; ++n) { bB[n][0] = LD_B(n, 0, bi); bB[n][1] = LD_B(n, 1, bi); }
#pragma unroll
    for (int m = 0; m < MH; ++m) { bA0[m][0] = LD_A(m, 0, bi); bA0[m][1] = LD_A(m, 1, bi); }
    asm volatile("s_waitcnt lgkmcnt(0)" ::: "memory");
    __builtin_amdgcn_sched_barrier(0);
    __builtin_amdgcn_s_setprio(1);
#pragma unroll
    for (int m = 0; m < MH; ++m)
#pragma unroll
      for (int n = 0; n < 2; ++n)
#pragma unroll
        for (int kk = 0; kk < 2; ++kk)
          acc[m][n] = __builtin_amdgcn_mfma_f32_16x16x32_bf16(bA0[m][kk], bB[n][kk], acc[m][n], 0, 0, 0);
    __builtin_amdgcn_s_setprio(0);
    if (kt + 1 < nk) STAGE_A(kt + 1);
#pragma unroll
    for (int m = 0; m < MH; ++m) { bA1[m][0] = LD_A(MH + m, 0, bi); bA1[m][1] = LD_A(MH + m, 1, bi); }
    __builtin_amdgcn_s_setprio(1);
#pragma unroll
    for (int m = 0; m < MH; ++m)
#pragma unroll
      for (int n = 2; n < 4; ++n)
#pragma unroll
        for (int kk = 0; kk < 2; ++kk)
          acc[m][n] = __builtin_amdgcn_mfma_f32_16x16x32_bf16(bA0[m][kk], bB[n][kk], acc[m][n], 0, 0, 0);
    __builtin_amdgcn_s_setprio(0);
    asm volatile("s_waitcnt lgkmcnt(0)" ::: "memory");
    __builtin_amdgcn_sched_barrier(0);
    __builtin_amdgcn_s_setprio(1);
#pragma unroll
    for (int m = 0; m < MH; ++m)
#pragma unroll
      for (int n = 0; n < 2; ++n)
#pragma unroll
        for (int kk = 0; kk < 2; ++kk)
          acc[MH + m][n] = __builtin_amdgcn_mfma_f32_16x16x32_bf16(bA1[m][kk], bB[n][kk], acc[MH + m][n], 0, 0, 0);
#pragma unroll
    for (int m = 0; m < MH; ++m)
#pragma unroll
      for (int n = 2; n < 4; ++n)
#pragma unroll
        for (int kk = 0; kk < 2; ++kk)
          acc[MH + m][n] = __builtin_amdgcn_mfma_f32_16x16x32_bf16(bA1[m][kk], bB[n][kk], acc[MH + m][n], 0, 0, 0);
    __builtin_amdgcn_s_setprio(0);
  }

  __syncthreads();

  if constexpr (EPI == EPI_BF16 || EPI == EPI_SP_BF16) {
    u16* wv = smem + wave * 1152;   // 16 rows x 72 u16 per wave
#pragma unroll
    for (int m = 0; m < MR; ++m) {
#pragma unroll
      for (int n = 0; n < 4; ++n) {
        const int c = col0 + wc * 64 + n * 16 + fr;
        float bv = (EPI == EPI_SP_BF16) ? bias[c] : 0.f;
#pragma unroll
        for (int j = 0; j < 4; ++j) {
          float v = acc[m][n][j];
          if (EPI == EPI_SP_BF16) {
            float xx = v + bv;
            float t = __expf(xx);
            float sp = (xx > -5.f) ? log1pf(t) : t;
            v = (xx > 20.f) ? xx : sp;
          }
          wv[(fq * 4 + j) * 72 + n * 16 + fr] = f2b(v);
        }
      }
#pragma unroll
      for (int p = 0; p < 2; ++p) {
        const int rf = p * 8 + (lane >> 3);
        const int c0 = (lane & 7) * 8;
        u16x8 ov = *reinterpret_cast<const u16x8*>(wv + rf * 72 + c0);
        const int grow = row0 + wr * HA + m * 16 + rf;
        const int gcol = col0 + wc * 64 + c0;
        *reinterpret_cast<u16x8*>(&outB[(size_t)grow * ldc + gcol]) = ov;
      }
    }
  } else {
#pragma unroll
    for (int m = 0; m < MR; ++m) {
      const int r = row0 + wr * HA + m * 16 + fq * 4;
#pragma unroll
      for (int n = 0; n < 4; ++n) {
        const int c = col0 + wc * 64 + n * 16 + fr;
#pragma unroll
        for (int j = 0; j < 4; ++j) {
          size_t o = (size_t)(r + j) * ldc + c;
          if (EPI == EPI_F32) outF[o] = acc[m][n][j];
          else                outF[o] = acc[m][n][j] + resid[o];
        }
      }
    }
  }
}

// ---------------- GEMM2 split-K: partial[z] = uc[:,zK:(z+1)K] @ Wxp^T ------
__global__ __launch_bounds__(256)
void gemm2sk_k(const u16* __restrict__ A, const u16* __restrict__ Bm,
               float* __restrict__ partial) {
  constexpr int K = NB_H;
  __shared__ u16 smem[(64 + 128) * 32];
  u16* As = smem;
  u16* Bs = smem + 64 * 32;
  const int tid  = threadIdx.x;
  const int lane = tid & 63;
  const int wave = tid >> 6;
  const int wr = wave >> 1, wc = wave & 1;
  const int row0 = blockIdx.x * 64;
  const int z = blockIdx.z;
  f32x4 acc[2][4] = {};

  const int r_ld = tid >> 2;            // 0..63
  const int kb   = (((tid & 3) ^ ((tid >> 3) & 3)) * 8);
  const size_t a_base = (size_t)(row0 + r_ld) * K + kb;
  const size_t b_base = (size_t)r_ld * K + kb;
  u16* lA = As + tid * 8;
  u16* lB = Bs + tid * 8;

  const int fr = lane & 15;
  const int fq = lane >> 4;
  const int fkx = ((fq ^ ((fr >> 1) & 3)) * 8);

  for (int kt = 0; kt < 8; ++kt) {
    const int k0 = z * 256 + kt * 32;
    __syncthreads();
    stage16(A + a_base + k0, lA);
#pragma unroll
    for (int hh = 0; hh < 2; ++hh)
      stage16(Bm + b_base + (size_t)(hh * 64) * K + k0, lB + hh * 64 * 32);
    __syncthreads();
    bf16x8 af[2], bfr[4];
#pragma unroll
    for (int m = 0; m < 2; ++m)
      af[m] = *reinterpret_cast<const bf16x8*>(&As[(wr * 32 + m * 16 + fr) * 32 + fkx]);
#pragma unroll
    for (int n = 0; n < 4; ++n)
      bfr[n] = *reinterpret_cast<const bf16x8*>(&Bs[(wc * 64 + n * 16 + fr) * 32 + fkx]);
#pragma unroll
    for (int m = 0; m < 2; ++m)
#pragma unroll
      for (int n = 0; n < 4; ++n)
        acc[m][n] = __builtin_amdgcn_mfma_f32_16x16x32_bf16(af[m], bfr[n], acc[m][n], 0, 0, 0);
  }

  float* outp = partial + (size_t)z * (NB_TOK * 128);
#pragma unroll
  for (int m = 0; m < 2; ++m) {
    const int r = row0 + wr * 32 + m * 16 + fq * 4;
#pragma unroll
    for (int n = 0; n < 4; ++n) {
      const int c = wc * 64 + n * 16 + fr;
#pragma unroll
      for (int j = 0; j < 4; ++j)
        outp[(size_t)(r + j) * 128 + c] = acc[m][n][j];
    }
  }
}

// reduce 8 partials -> xdbl f32 + dtp bf16 (cols<64)
__global__ void reduce_xdbl_k(const float* __restrict__ partial,
                              float* __restrict__ xdbl, u16* __restrict__ dtp) {
  int i = blockIdx.x * 256 + threadIdx.x;   // 8192*128
  float s = 0.f;
#pragma unroll
  for (int zz = 0; zz < 8; ++zz) s += partial[(size_t)zz * (NB_TOK * 128) + i];
  xdbl[i] = s;
  int col = i & 127;
  if (col < NB_DTR) dtp[(size_t)(i >> 7) * NB_DTR + col] = f2b(s);
}

// ---------------- depthwise conv (k=3, pad 1) + silu ----------------
__global__ void dwconv_silu_k(const u16* __restrict__ xz, const float* __restrict__ cw,
                              const float* __restrict__ cb, u16* __restrict__ uc) {
  int i = blockIdx.x * 256 + threadIdx.x;     // over 8192*2048/8
  int hb = i & (NB_H / 8 - 1);
  int t = i >> 8;
  int l = t & (NB_L - 1);
  int h0 = hb * 8;
  const u16* base = xz + (size_t)t * 4096 + h0;
  u16x8 vm = *reinterpret_cast<const u16x8*>(base);
  u16x8 vq = {}, vp = {};
  if (l > 0)          vq = *reinterpret_cast<const u16x8*>(base - 4096);
  if (l < NB_L - 1)   vp = *reinterpret_cast<const u16x8*>(base + 4096);
  u16x8 o;
#pragma unroll
  for (int j = 0; j < 8; ++j) {
    int h = h0 + j;
    float acc = cb[h];
    acc = __builtin_fmaf(b2f(vq[j]), cw[h * 3 + 0], acc);
    acc = __builtin_fmaf(b2f(vm[j]), cw[h * 3 + 1], acc);
    acc = __builtin_fmaf(b2f(vp[j]), cw[h * 3 + 2], acc);
    float s = acc / (1.f + __expf(-acc));
    o[j] = f2b(s);
  }
  *reinterpret_cast<u16x8*>(uc + (size_t)t * NB_H + h0) = o;
}

// ---------------- chunked selective scan, h-PAIR vectorized ----------------
// Each thread owns TWO adjacent h (one u32 load per stream per step instead
// of two u16 loads; 2x ILP). Grid halves: 1024 blocks, 16 waves/CU,
// VGPR ~110 < 128 so 16 waves/CU is legal.
__global__ __launch_bounds__(256)
void scan_passA_k(const u16* __restrict__ dt, const u16* __restrict__ uc,
                  const float* __restrict__ xdbl, const float* __restrict__ A_log,
                  u16* __restrict__ dPout, u16* __restrict__ Sout) {
  __shared__ float bc[CLEN][32];
  const int tid = threadIdx.x;
  int idx = blockIdx.x * 256 + tid;   // 4*64*1024
  int hp = idx & 1023;
  int ck = (idx >> 10) & (NCHUNK - 1);
  int b = idx >> 16;
  int h0 = hp * 2;
  const int t0 = b * NB_L + ck * CLEN;
  {
    int r = tid >> 3, q = tid & 7;
    *reinterpret_cast<float4*>(&bc[r][q * 4]) =
        *reinterpret_cast<const float4*>(xdbl + (size_t)(t0 + r) * 128 + 64 + q * 4);
  }
  float An[NB_NS];
#pragma unroll
  for (int n = 0; n < NB_NS; ++n) An[n] = -__expf(A_log[n]);
  float P0[NB_NS], S0[NB_NS], P1[NB_NS], S1[NB_NS];
#pragma unroll
  for (int n = 0; n < NB_NS; ++n) { P0[n] = 1.f; S0[n] = 0.f; P1[n] = 1.f; S1[n] = 0.f; }
  __syncthreads();
  const u32* up = reinterpret_cast<const u32*>(uc + (size_t)t0 * NB_H + h0);
  const u32* dp = reinterpret_cast<const u32*>(dt + (size_t)t0 * NB_H + h0);
  const int STR = NB_H / 2;   // u32 stride per step
  u32 uA = up[0],   dA = dp[0];
  u32 uB = up[STR], dB = dp[STR];
  for (int tt = 0; tt < CLEN; ++tt) {
    u32 uC = 0, dC = 0;
    if (tt + 2 < CLEN) { uC = up[2 * STR]; dC = dp[2 * STR]; }
    up += STR; dp += STR;
    float u0 = b2f_lo(uA), u1 = b2f_hi(uA);
    float d0 = b2f_lo(dA), d1 = b2f_hi(dA);
    float4 B0 = *reinterpret_cast<const float4*>(&bc[tt][0]);
    float4 B1 = *reinterpret_cast<const float4*>(&bc[tt][4]);
    float4 B2 = *reinterpret_cast<const float4*>(&bc[tt][8]);
    float4 B3 = *reinterpret_cast<const float4*>(&bc[tt][12]);
    const float Bf[NB_NS] = {B0.x, B0.y, B0.z, B0.w, B1.x, B1.y, B1.z, B1.w,
                             B2.x, B2.y, B2.z, B2.w, B3.x, B3.y, B3.z, B3.w};
#pragma unroll
    for (int n = 0; n < NB_NS; ++n) {
      float e0 = exp_small(d0 * An[n]);
      float e1 = exp_small(d1 * An[n]);
      P0[n] *= e0;
      P1[n] *= e1;
      S0[n] = __builtin_fmaf(e0, S0[n], Bf[n] * u0);
      S1[n] = __builtin_fmaf(e1, S1[n], Bf[n] * u1);
    }
    uA = uB; dA = dB; uB = uC; dB = dC;
  }
#pragma unroll
  for (int n = 0; n < NB_NS; ++n) {
    size_t o = ((((size_t)b * NCHUNK + ck) * NB_NS + n) * NB_H + h0);
    *reinterpret_cast<u32*>(dPout + o) =
        (u32)f2b(1.0f - P0[n]) | ((u32)f2b(1.0f - P1[n]) << 16);
    *reinterpret_cast<u32*>(Sout + o) =
        (u32)f2b(S0[n]) | ((u32)f2b(S1[n]) << 16);
  }
}

// pass B: sequential combine over chunks; Hst (bf16) in-place over dP. h-pair.
__global__ void scan_passB_k(u16* __restrict__ dP, const u16* __restrict__ S) {
  int idx = blockIdx.x * 256 + threadIdx.x;   // 4*16*1024 = 65536
  int hp = idx & 1023;
  int n = (idx >> 10) & (NB_NS - 1);
  int b = idx >> 14;
  int h0 = hp * 2;
  const size_t stride = (size_t)NB_NS * NB_H;   // u16 units
  size_t o = ((size_t)b * NCHUNK * NB_NS + n) * NB_H + h0;
  float hs0 = 0.f, hs1 = 0.f;
  u32 pw = *reinterpret_cast<const u32*>(dP + o);
  u32 sw = *reinterpret_cast<const u32*>(S + o);
  for (int ck = 0; ck < NCHUNK; ++ck) {
    u32 pn = 0, sn = 0;
    if (ck + 1 < NCHUNK) {
      pn = *reinterpret_cast<const u32*>(dP + o + stride);
      sn = *reinterpret_cast<const u32*>(S + o + stride);
    }
    float p0 = 1.f - b2f_lo(pw), p1 = 1.f - b2f_hi(pw);
    float s0 = b2f_lo(sw),       s1 = b2f_hi(sw);
    *reinterpret_cast<u32*>(dP + o) = (u32)f2b(hs0) | ((u32)f2b(hs1) << 16);
    hs0 = __builtin_fmaf(p0, hs0, s0);
    hs1 = __builtin_fmaf(p1, hs1, s1);
    o += stride; pw = pn; sw = sn;
  }
}

// pass C: replay + gate, h-pair vectorized.
__global__ __launch_bounds__(256)
void scan_passC_k(const u16* __restrict__ dt, const u16* __restrict__ uc,
                  const float* __restrict__ xdbl, const u16* __restrict__ xz,
                  const float* __restrict__ A_log, const float* __restrict__ Dp,
                  const u16* __restrict__ Hst, u16* __restrict__ ybf) {
  __shared__ float bc[CLEN][32];
  const int tid = threadIdx.x;
  int idx = blockIdx.x * 256 + tid;   // 4*64*1024
  int hp = idx & 1023;
  int ck = (idx >> 10) & (NCHUNK - 1);
  int b = idx >> 16;
  int h0 = hp * 2;
  const int t0 = b * NB_L + ck * CLEN;
  {
    int r = tid >> 3, q = tid & 7;
    *reinterpret_cast<float4*>(&bc[r][q * 4]) =
        *reinterpret_cast<const float4*>(xdbl + (size_t)(t0 + r) * 128 + 64 + q * 4);
  }
  float An[NB_NS];
#pragma unroll
  for (int n = 0; n < NB_NS; ++n) An[n] = -__expf(A_log[n]);
  float s0[NB_NS], s1[NB_NS];
#pragma unroll
  for (int n = 0; n < NB_NS; ++n) {
    size_t o = ((((size_t)b * NCHUNK + ck) * NB_NS + n) * NB_H + h0);
    u32 hw = *reinterpret_cast<const u32*>(Hst + o);
    s0[n] = b2f_lo(hw); s1[n] = b2f_hi(hw);
  }
  const float Dh0 = Dp[h0], Dh1 = Dp[h0 + 1];
  __syncthreads();
  const u32* up = reinterpret_cast<const u32*>(uc + (size_t)t0 * NB_H + h0);
  const u32* dp = reinterpret_cast<const u32*>(dt + (size_t)t0 * NB_H + h0);
  const u32* zp = reinterpret_cast<const u32*>(xz + (size_t)t0 * 4096 + NB_H + h0);
  u16* yp = ybf + (size_t)t0 * NB_H + h0;
  const int STR = NB_H / 2;
  const int ZSTR = 4096 / 2;
  u32 uA = up[0],   dA = dp[0],   zA = zp[0];
  u32 uB = up[STR], dB = dp[STR], zB = zp[ZSTR];
  for (int tt = 0; tt < CLEN; ++tt) {
    u32 uC = 0, dC = 0, zC = 0;
    if (tt + 2 < CLEN) { uC = up[2 * STR]; dC = dp[2 * STR]; zC = zp[2 * ZSTR]; }
    up += STR; dp += STR; zp += ZSTR;
    float u0 = b2f_lo(uA), u1 = b2f_hi(uA);
    float d0 = b2f_lo(dA), d1 = b2f_hi(dA);
    float z0 = b2f_lo(zA), z1 = b2f_hi(zA);
    float4 B0 = *reinterpret_cast<const float4*>(&bc[tt][0]);
    float4 B1 = *reinterpret_cast<const float4*>(&bc[tt][4]);
    float4 B2 = *reinterpret_cast<const float4*>(&bc[tt][8]);
    float4 B3 = *reinterpret_cast<const float4*>(&bc[tt][12]);
    float4 C0 = *reinterpret_cast<const float4*>(&bc[tt][16]);
    float4 C1 = *reinterpret_cast<const float4*>(&bc[tt][20]);
    float4 C2 = *reinterpret_cast<const float4*>(&bc[tt][24]);
    float4 C3 = *reinterpret_cast<const float4*>(&bc[tt][28]);
    const float Bf[NB_NS] = {B0.x, B0.y, B0.z, B0.w, B1.x, B1.y, B1.z, B1.w,
                             B2.x, B2.y, B2.z, B2.w, B3.x, B3.y, B3.z, B3.w};
    const float Cf[NB_NS] = {C0.x, C0.y, C0.z, C0.w, C1.x, C1.y, C1.z, C1.w,
                             C2.x, C2.y, C2.z, C2.w, C3.x, C3.y, C3.z, C3.w};
    float y0 = 0.f, y1 = 0.f;
#pragma unroll
    for (int n = 0; n < NB_NS; ++n) {
      float e0 = exp_small(d0 * An[n]);
      float e1 = exp_small(d1 * An[n]);
      s0[n] = __builtin_fmaf(e0, s0[n], Bf[n] * u0);
      s1[n] = __builtin_fmaf(e1, s1[n], Bf[n] * u1);
      y0 = __builtin_fmaf(Cf[n], s0[n], y0);
      y1 = __builtin_fmaf(Cf[n], s1[n], y1);
    }
    float v0 = __builtin_fmaf(Dh0, u0, y0);
    float v1 = __builtin_fmaf(Dh1, u1, y1);
    float g0 = z0 / (1.f + __expf(-z0));
    float g1 = z1 / (1.f + __expf(-z1));
    *reinterpret_cast<u32*>(yp) = (u32)f2b(v0 * g0) | ((u32)f2b(v1 * g1) << 16);
    yp += NB_H;
    uA = uB; dA = dB; zA = zB; uB = uC; dB = dC; zB = zC;
  }
}

// ---------------- launcher ----------------
extern "C" void kernel_launch(void* const* d_in, const int* in_sizes, int n_in,
                              void* d_out, int out_size, void* d_ws, size_t ws_size,
                              hipStream_t stream) {
  const float* x      = (const float*)d_in[0];
  const float* W_in   = (const float*)d_in[1];
  const float* conv_w = (const float*)d_in[2];
  const float* conv_b = (const float*)d_in[3];
  const float* W_xprj = (const float*)d_in[4];
  const float* W_dt   = (const float*)d_in[5];
  const float* b_dt   = (const float*)d_in[6];
  const float* A_log  = (const float*)d_in[7];
  const float* Dp     = (const float*)d_in[8];
  const float* W_out  = (const float*)d_in[9];
  float* out = (float*)d_out;

  char* ws = (char*)d_ws;
  size_t off = 0;
  auto alloc = [&](size_t bytes) {
    void* p = ws + off;
    off += (bytes + 255) & ~(size_t)255;
    return p;
  };
  u16*   xz_b   = (u16*)alloc((size_t)NB_TOK * 4096 * 2);     // 64MB
  u16*   x_b    = (u16*)alloc((size_t)NB_TOK * NB_DIM * 2);   // 16MB
  u16*   win_b  = (u16*)alloc((size_t)4096 * NB_DIM * 2);     // 8MB
  u16*   wxp_b  = (u16*)alloc((size_t)128 * NB_H * 2);        // 512KB
  u16*   wdt_b  = (u16*)alloc((size_t)NB_H * NB_DTR * 2);     // 256KB
  u16*   wout_b = (u16*)alloc((size_t)NB_DIM * NB_H * 2);     // 4MB
  u16*   uc_b   = (u16*)alloc((size_t)NB_TOK * NB_H * 2);     // 32MB
  float* xdbl   = (float*)alloc((size_t)NB_TOK * 128 * 4);    // 4MB
  u16*   dtp_b  = (u16*)alloc((size_t)NB_TOK * NB_DTR * 2);   // 1MB
  u16*   dt_b   = (u16*)alloc((size_t)NB_TOK * NB_H * 2);     // 32MB
  u16*   scdP   = (u16*)alloc((size_t)NB_B * NCHUNK * NB_NS * NB_H * 2); // 16MB (dP -> Hst)
  u16*   scS    = (u16*)alloc((size_t)NB_B * NCHUNK * NB_NS * NB_H * 2); // 16MB
  u16*   y_b    = (u16*)alloc((size_t)NB_TOK * NB_H * 2);     // 32MB
  float* g2part = (float*)scdP;   // split-K partials alias (stream-ordered)
  (void)ws_size; (void)in_sizes; (void)n_in; (void)out_size;

  cvt_all_k<<<(CVT_N5 + 255) / 256, 256, 0, stream>>>(
      x, W_in, W_dt, W_out, W_xprj, x_b, win_b, wdt_b, wout_b, wxp_b);

  // GEMM1: xz = x @ W_in^T  (tiles 32x16): XCD chunks 8x8, chunk grid 4x2
  gemm8p_k<EPI_BF16, 256><<<512, 512, 0, stream>>>(
      x_b, win_b, NB_DIM, 4096, xz_b, nullptr, nullptr, nullptr, 8, 8, 2);

  dwconv_silu_k<<<(NB_TOK * NB_H / 8) / 256, 256, 0, stream>>>(xz_b, conv_w, conv_b, uc_b);

  // GEMM2 split-K=8 -> partials; reduce -> xdbl f32 + dtp bf16
  gemm2sk_k<<<dim3(128, 1, 8), 256, 0, stream>>>(uc_b, wxp_b, g2part);
  reduce_xdbl_k<<<(NB_TOK * 128) / 256, 256, 0, stream>>>(g2part, xdbl, dtp_b);

  // GEMM3: dt = softplus(dtp @ W_dt^T + b_dt)  (BM=128: tiles 64x8, chunks 8x8)
  gemm8p_k<EPI_SP_BF16, 128><<<512, 512, 0, stream>>>(
      dtp_b, wdt_b, NB_DTR, NB_H, dt_b, nullptr, b_dt, nullptr, 8, 8, 1);

  scan_passA_k<<<(NB_B * NCHUNK * NB_H / 2) / 256, 256, 0, stream>>>(dt_b, uc_b, xdbl, A_log, scdP, scS);
  scan_passB_k<<<(NB_B * NB_NS * NB_H / 2) / 256, 256, 0, stream>>>(scdP, scS);
  scan_passC_k<<<(NB_B * NCHUNK * NB_H / 2) / 256, 256, 0, stream>>>(dt_b, uc_b, xdbl, xz_b, A_log, Dp, scdP, y_b);

  // GEMM4: out = y @ W_out^T + x  (tiles 64x4, BM=128): chunks 8x4
  gemm8p_k<EPI_RES_F32, 128><<<256, 512, 0, stream>>>(
      y_b, wout_b, NB_H, NB_DIM, nullptr, out, nullptr, x, 8, 4, 1);
}

// Round 14
// 288.674 us; speedup vs baseline: 1.4414x; 1.0342x over previous
//
#include <hip/hip_runtime.h>
#include <cmath>

typedef unsigned short u16;
typedef unsigned int u32;
typedef __bf16 bf16x8 __attribute__((ext_vector_type(8)));
typedef float f32x4 __attribute__((ext_vector_type(4)));
typedef unsigned short u16x8 __attribute__((ext_vector_type(8)));

#define NB_B   4
#define NB_L   2048
#define NB_DIM 1024
#define NB_H   2048
#define NB_NS  16
#define NB_DTR 64
#define NB_TOK (NB_B * NB_L)   // 8192
#define NCHUNK 64
#define CLEN   32              // NB_L / NCHUNK

__device__ __forceinline__ u16 f2b(float f) {
  union { float f; unsigned u; } v; v.f = f;
  unsigned r = v.u + 0x7fffu + ((v.u >> 16) & 1u);
  return (u16)(r >> 16);
}
__device__ __forceinline__ float b2f(u16 h) {
  union { unsigned u; float f; } v; v.u = ((unsigned)h) << 16;
  return v.f;
}
__device__ __forceinline__ float b2f_lo(u32 w) {
  union { unsigned u; float f; } v; v.u = w << 16;
  return v.f;
}
__device__ __forceinline__ float b2f_hi(u32 w) {
  union { unsigned u; float f; } v; v.u = w & 0xffff0000u;
  return v.f;
}
// exp(w) for |w| <= ~2e-4 here: 1 + w + w^2/2, err ~ |w|^3/6
__device__ __forceinline__ float exp_small(float w) {
  return __builtin_fmaf(w, __builtin_fmaf(w, 0.5f, 1.0f), 1.0f);
}

// ---------------- fused converts (x, W_in, W_dt, W_out, W_xproj+pad) --------
#define CVT_N0 2097152                      // x          f4
#define CVT_N1 (CVT_N0 + 1048576)           // W_in       f4
#define CVT_N2 (CVT_N1 + 32768)             // W_dt       f4
#define CVT_N3 (CVT_N2 + 524288)            // W_out      f4
#define CVT_N4 (CVT_N3 + 49152)             // W_xproj    f4 (96*2048/4)
#define CVT_N5 (CVT_N4 + 8192)              // xproj pad  u16x8 (32*2048/8)
__global__ void cvt_all_k(const float* __restrict__ x, const float* __restrict__ W_in,
                          const float* __restrict__ W_dt, const float* __restrict__ W_out,
                          const float* __restrict__ W_xp,
                          u16* __restrict__ xb, u16* __restrict__ winb,
                          u16* __restrict__ wdtb, u16* __restrict__ woutb,
                          u16* __restrict__ wxpb) {
  int i = blockIdx.x * 256 + threadIdx.x;
  if (i >= CVT_N5) return;
  if (i >= CVT_N4) {   // zero pad rows 96..127 of wxp
    int q = i - CVT_N4;
    u16x8 z = {};
    *reinterpret_cast<u16x8*>(wxpb + 96 * 2048 + q * 8) = z;
    return;
  }
  const float* src; u16* dst; int off;
  if (i < CVT_N0)      { src = x;     dst = xb;    off = i; }
  else if (i < CVT_N1) { src = W_in;  dst = winb;  off = i - CVT_N0; }
  else if (i < CVT_N2) { src = W_dt;  dst = wdtb;  off = i - CVT_N1; }
  else if (i < CVT_N3) { src = W_out; dst = woutb; off = i - CVT_N2; }
  else                 { src = W_xp;  dst = wxpb;  off = i - CVT_N3; }
  float4 v = reinterpret_cast<const float4*>(src)[off];
  ushort4 o;
  o.x = f2b(v.x); o.y = f2b(v.y); o.z = f2b(v.z); o.w = f2b(v.w);
  reinterpret_cast<ushort4*>(dst)[off] = o;
}

#define EPI_BF16    0
#define EPI_F32     1
#define EPI_SP_BF16 2
#define EPI_RES_F32 3

__device__ __forceinline__ void stage16(const u16* g, u16* l) {
  __builtin_amdgcn_global_load_lds(
      (const __attribute__((address_space(1))) unsigned int*)g,
      (__attribute__((address_space(3))) unsigned int*)l, 16, 0, 0);
}

// ============ 1-barrier/K-tile pipelined GEMM (BK=64, BN=256) ==============
// (round-12 structure; round-14 change: STAGE_A(kt+1) issued at loop top
// right after STAGE_B(kt+1) -- invariant: passing tile kt's gate implies all
// waves' last lgkm(0) of tile kt-1 retired, so ALL of buf[bi^1] is free.)
template <int EPI, int BM>
__global__ __launch_bounds__(512, 1)
void gemm8p_k(const u16* __restrict__ A, const u16* __restrict__ Bm,
              int K, int ldc,
              u16* __restrict__ outB, float* __restrict__ outF,
              const float* __restrict__ bias, const float* __restrict__ resid,
              int cr, int cc, int ncx) {
  constexpr int MR = BM / 32;          // m-frags per wave
  constexpr int MH = MR / 2;
  constexpr int HA = BM / 2;           // A staging-half rows
  constexpr int LA = BM / 128;         // gloads per thread per A-half
  constexpr int BUFE = (BM + 256) * 64; // u16 per buffer
  __shared__ u16 smem[2 * BUFE];

  const int tid  = threadIdx.x;
  const int lane = tid & 63;
  const int wave = tid >> 6;
  const int wr = wave >> 2, wc = wave & 3;
  const int fr = lane & 15, fq = lane >> 4;

  const int bid = blockIdx.x;
  const int e = bid & 7, w = bid >> 3;
  const int row0 = ((e / ncx) * cr + (w % cr)) * BM;
  const int col0 = ((e % ncx) * cc + (w / cr)) * 256;

  f32x4 acc[MR][4] = {};
  bf16x8 bB[4][2], bA0[MH][2], bA1[MH][2];

  auto STAGE_B = [&](int kt) {
    const int k0 = kt * 64;
    u16* base = smem + (kt & 1) * BUFE + BM * 64;
#pragma unroll
    for (int h = 0; h < 2; ++h)
#pragma unroll
      for (int l = 0; l < 2; ++l) {
        int c = l * 512 + tid;
        int rih = c >> 3, p = c & 7;
        stage16(Bm + (size_t)(col0 + h * 128 + rih) * K + k0 + ((p ^ (rih & 7)) * 8),
                base + (h * 128 + rih) * 64 + p * 8);
      }
  };
  auto STAGE_A = [&](int kt) {
    const int k0 = kt * 64;
    u16* base = smem + (kt & 1) * BUFE;
#pragma unroll
    for (int h = 0; h < 2; ++h)
#pragma unroll
      for (int l = 0; l < LA; ++l) {
        int c = l * 512 + tid;
        int rih = c >> 3, p = c & 7;
        stage16(A + (size_t)(row0 + h * HA + rih) * K + k0 + ((p ^ (rih & 7)) * 8),
                base + (h * HA + rih) * 64 + p * 8);
      }
  };
  auto LD_A = [&](int m, int kk, int bi) {
    int rt = wr * HA + m * 16 + fr;
    int p = (kk * 4 + fq) ^ (rt & 7);
    return *reinterpret_cast<const bf16x8*>(smem + bi * BUFE + rt * 64 + p * 8);
  };
  auto LD_B = [&](int n, int kk, int bi) {
    int rt = wc * 64 + n * 16 + fr;
    int p = (kk * 4 + fq) ^ (rt & 7);
    return *reinterpret_cast<const bf16x8*>(smem + bi * BUFE + BM * 64 + rt * 64 + p * 8);
  };

  const int nk = K >> 6;
  STAGE_B(0); STAGE_A(0);

  for (int kt = 0; kt < nk; ++kt) {
    const int bi = kt & 1;
    asm volatile("s_waitcnt vmcnt(0)" ::: "memory");
    __builtin_amdgcn_s_barrier();
    __builtin_amdgcn_sched_barrier(0);
    if (kt + 1 < nk) { STAGE_B(kt + 1); STAGE_A(kt + 1); }
#pragma unroll
    for (int n = 0; n < 4; ++n) { bB[n][0] = LD_B(n, 0, bi); bB[n][1] = LD_B(n, 1, bi); }
#pragma unroll
    for (int m = 0; m < MH; ++m) { bA0[m][0] = LD_A(m, 0, bi); bA0[m][1] = LD_A(m, 1, bi); }
    asm volatile("s_waitcnt lgkmcnt(0)" ::: "memory");
    __builtin_amdgcn_sched_barrier(0);
    __builtin_amdgcn_s_setprio(1);
#pragma unroll
    for (int m = 0; m < MH; ++m)
#pragma unroll
      for (int n = 0; n < 2; ++n)
#pragma unroll
        for (int kk = 0; kk < 2; ++kk)
          acc[m][n] = __builtin_amdgcn_mfma_f32_16x16x32_bf16(bA0[m][kk], bB[n][kk], acc[m][n], 0, 0, 0);
    __builtin_amdgcn_s_setprio(0);
#pragma unroll
    for (int m = 0; m < MH; ++m) { bA1[m][0] = LD_A(MH + m, 0, bi); bA1[m][1] = LD_A(MH + m, 1, bi); }
    __builtin_amdgcn_s_setprio(1);
#pragma unroll
    for (int m = 0; m < MH; ++m)
#pragma unroll
      for (int n = 2; n < 4; ++n)
#pragma unroll
        for (int kk = 0; kk < 2; ++kk)
          acc[m][n] = __builtin_amdgcn_mfma_f32_16x16x32_bf16(bA0[m][kk], bB[n][kk], acc[m][n], 0, 0, 0);
    __builtin_amdgcn_s_setprio(0);
    asm volatile("s_waitcnt lgkmcnt(0)" ::: "memory");
    __builtin_amdgcn_sched_barrier(0);
    __builtin_amdgcn_s_setprio(1);
#pragma unroll
    for (int m = 0; m < MH; ++m)
#pragma unroll
      for (int n = 0; n < 2; ++n)
#pragma unroll
        for (int kk = 0; kk < 2; ++kk)
          acc[MH + m][n] = __builtin_amdgcn_mfma_f32_16x16x32_bf16(bA1[m][kk], bB[n][kk], acc[MH + m][n], 0, 0, 0);
#pragma unroll
    for (int m = 0; m < MH; ++m)
#pragma unroll
      for (int n = 2; n < 4; ++n)
#pragma unroll
        for (int kk = 0; kk < 2; ++kk)
          acc[MH + m][n] = __builtin_amdgcn_mfma_f32_16x16x32_bf16(bA1[m][kk], bB[n][kk], acc[MH + m][n], 0, 0, 0);
    __builtin_amdgcn_s_setprio(0);
  }

  __syncthreads();

  if constexpr (EPI == EPI_BF16 || EPI == EPI_SP_BF16) {
    u16* wv = smem + wave * 1152;   // 16 rows x 72 u16 per wave
#pragma unroll
    for (int m = 0; m < MR; ++m) {
#pragma unroll
      for (int n = 0; n < 4; ++n) {
        const int c = col0 + wc * 64 + n * 16 + fr;
        float bv = (EPI == EPI_SP_BF16) ? bias[c] : 0.f;
#pragma unroll
        for (int j = 0; j < 4; ++j) {
          float v = acc[m][n][j];
          if (EPI == EPI_SP_BF16) {
            float xx = v + bv;
            float t = __expf(xx);
            float sp = (xx > -5.f) ? log1pf(t) : t;
            v = (xx > 20.f) ? xx : sp;
          }
          wv[(fq * 4 + j) * 72 + n * 16 + fr] = f2b(v);
        }
      }
#pragma unroll
      for (int p = 0; p < 2; ++p) {
        const int rf = p * 8 + (lane >> 3);
        const int c0 = (lane & 7) * 8;
        u16x8 ov = *reinterpret_cast<const u16x8*>(wv + rf * 72 + c0);
        const int grow = row0 + wr * HA + m * 16 + rf;
        const int gcol = col0 + wc * 64 + c0;
        *reinterpret_cast<u16x8*>(&outB[(size_t)grow * ldc + gcol]) = ov;
      }
    }
  } else {
#pragma unroll
    for (int m = 0; m < MR; ++m) {
      const int r = row0 + wr * HA + m * 16 + fq * 4;
#pragma unroll
      for (int n = 0; n < 4; ++n) {
        const int c = col0 + wc * 64 + n * 16 + fr;
#pragma unroll
        for (int j = 0; j < 4; ++j) {
          size_t o = (size_t)(r + j) * ldc + c;
          if (EPI == EPI_F32) outF[o] = acc[m][n][j];
          else                outF[o] = acc[m][n][j] + resid[o];
        }
      }
    }
  }
}

// ---------------- GEMM2 split-K=4: partial[z] = uc[:,z*512:(z+1)*512] @ Wxp^T
// 512 blocks (2/CU), 16 BK=32 tiles per block; f32 partials 16MB (was 32MB).
__global__ __launch_bounds__(256)
void gemm2sk_k(const u16* __restrict__ A, const u16* __restrict__ Bm,
               float* __restrict__ partial) {
  constexpr int K = NB_H;
  __shared__ u16 smem[(64 + 128) * 32];
  u16* As = smem;
  u16* Bs = smem + 64 * 32;
  const int tid  = threadIdx.x;
  const int lane = tid & 63;
  const int wave = tid >> 6;
  const int wr = wave >> 1, wc = wave & 1;
  const int row0 = blockIdx.x * 64;
  const int z = blockIdx.z;
  f32x4 acc[2][4] = {};

  const int r_ld = tid >> 2;            // 0..63
  const int kb   = (((tid & 3) ^ ((tid >> 3) & 3)) * 8);
  const size_t a_base = (size_t)(row0 + r_ld) * K + kb;
  const size_t b_base = (size_t)r_ld * K + kb;
  u16* lA = As + tid * 8;
  u16* lB = Bs + tid * 8;

  const int fr = lane & 15;
  const int fq = lane >> 4;
  const int fkx = ((fq ^ ((fr >> 1) & 3)) * 8);

  for (int kt = 0; kt < 16; ++kt) {
    const int k0 = z * 512 + kt * 32;
    __syncthreads();
    stage16(A + a_base + k0, lA);
#pragma unroll
    for (int hh = 0; hh < 2; ++hh)
      stage16(Bm + b_base + (size_t)(hh * 64) * K + k0, lB + hh * 64 * 32);
    __syncthreads();
    bf16x8 af[2], bfr[4];
#pragma unroll
    for (int m = 0; m < 2; ++m)
      af[m] = *reinterpret_cast<const bf16x8*>(&As[(wr * 32 + m * 16 + fr) * 32 + fkx]);
#pragma unroll
    for (int n = 0; n < 4; ++n)
      bfr[n] = *reinterpret_cast<const bf16x8*>(&Bs[(wc * 64 + n * 16 + fr) * 32 + fkx]);
#pragma unroll
    for (int m = 0; m < 2; ++m)
#pragma unroll
      for (int n = 0; n < 4; ++n)
        acc[m][n] = __builtin_amdgcn_mfma_f32_16x16x32_bf16(af[m], bfr[n], acc[m][n], 0, 0, 0);
  }

  float* outp = partial + (size_t)z * (NB_TOK * 128);
#pragma unroll
  for (int m = 0; m < 2; ++m) {
    const int r = row0 + wr * 32 + m * 16 + fq * 4;
#pragma unroll
    for (int n = 0; n < 4; ++n) {
      const int c = wc * 64 + n * 16 + fr;
#pragma unroll
      for (int j = 0; j < 4; ++j)
        outp[(size_t)(r + j) * 128 + c] = acc[m][n][j];
    }
  }
}

// reduce 4 partials -> xdbl f32 + dtp bf16 (cols<64)
__global__ void reduce_xdbl_k(const float* __restrict__ partial,
                              float* __restrict__ xdbl, u16* __restrict__ dtp) {
  int i = blockIdx.x * 256 + threadIdx.x;   // 8192*128
  float s = 0.f;
#pragma unroll
  for (int zz = 0; zz < 4; ++zz) s += partial[(size_t)zz * (NB_TOK * 128) + i];
  xdbl[i] = s;
  int col = i & 127;
  if (col < NB_DTR) dtp[(size_t)(i >> 7) * NB_DTR + col] = f2b(s);
}

// ---------------- depthwise conv (k=3, pad 1) + silu ----------------
__global__ void dwconv_silu_k(const u16* __restrict__ xz, const float* __restrict__ cw,
                              const float* __restrict__ cb, u16* __restrict__ uc) {
  int i = blockIdx.x * 256 + threadIdx.x;     // over 8192*2048/8
  int hb = i & (NB_H / 8 - 1);
  int t = i >> 8;
  int l = t & (NB_L - 1);
  int h0 = hb * 8;
  const u16* base = xz + (size_t)t * 4096 + h0;
  u16x8 vm = *reinterpret_cast<const u16x8*>(base);
  u16x8 vq = {}, vp = {};
  if (l > 0)          vq = *reinterpret_cast<const u16x8*>(base - 4096);
  if (l < NB_L - 1)   vp = *reinterpret_cast<const u16x8*>(base + 4096);
  u16x8 o;
#pragma unroll
  for (int j = 0; j < 8; ++j) {
    int h = h0 + j;
    float acc = cb[h];
    acc = __builtin_fmaf(b2f(vq[j]), cw[h * 3 + 0], acc);
    acc = __builtin_fmaf(b2f(vm[j]), cw[h * 3 + 1], acc);
    acc = __builtin_fmaf(b2f(vp[j]), cw[h * 3 + 2], acc);
    float s = acc / (1.f + __expf(-acc));
    o[j] = f2b(s);
  }
  *reinterpret_cast<u16x8*>(uc + (size_t)t * NB_H + h0) = o;
}

// ---------------- chunked selective scan, h-pair + depth-3 prefetch --------
__global__ __launch_bounds__(256)
void scan_passA_k(const u16* __restrict__ dt, const u16* __restrict__ uc,
                  const float* __restrict__ xdbl, const float* __restrict__ A_log,
                  u16* __restrict__ dPout, u16* __restrict__ Sout) {
  __shared__ float bc[CLEN][32];
  const int tid = threadIdx.x;
  int idx = blockIdx.x * 256 + tid;   // 4*64*1024
  int hp = idx & 1023;
  int ck = (idx >> 10) & (NCHUNK - 1);
  int b = idx >> 16;
  int h0 = hp * 2;
  const int t0 = b * NB_L + ck * CLEN;
  {
    int r = tid >> 3, q = tid & 7;
    *reinterpret_cast<float4*>(&bc[r][q * 4]) =
        *reinterpret_cast<const float4*>(xdbl + (size_t)(t0 + r) * 128 + 64 + q * 4);
  }
  float An[NB_NS];
#pragma unroll
  for (int n = 0; n < NB_NS; ++n) An[n] = -__expf(A_log[n]);
  float P0[NB_NS], S0[NB_NS], P1[NB_NS], S1[NB_NS];
#pragma unroll
  for (int n = 0; n < NB_NS; ++n) { P0[n] = 1.f; S0[n] = 0.f; P1[n] = 1.f; S1[n] = 0.f; }
  __syncthreads();
  const u32* up = reinterpret_cast<const u32*>(uc + (size_t)t0 * NB_H + h0);
  const u32* dp = reinterpret_cast<const u32*>(dt + (size_t)t0 * NB_H + h0);
  const int STR = NB_H / 2;   // u32 stride per step
  u32 uA = up[0],       dA = dp[0];
  u32 uB = up[STR],     dB = dp[STR];
  u32 uC2 = up[2 * STR], dC2 = dp[2 * STR];
  for (int tt = 0; tt < CLEN; ++tt) {
    u32 uD = 0, dD = 0;
    if (tt + 3 < CLEN) { uD = up[3 * STR]; dD = dp[3 * STR]; }
    up += STR; dp += STR;
    float u0 = b2f_lo(uA), u1 = b2f_hi(uA);
    float d0 = b2f_lo(dA), d1 = b2f_hi(dA);
    float4 B0 = *reinterpret_cast<const float4*>(&bc[tt][0]);
    float4 B1 = *reinterpret_cast<const float4*>(&bc[tt][4]);
    float4 B2 = *reinterpret_cast<const float4*>(&bc[tt][8]);
    float4 B3 = *reinterpret_cast<const float4*>(&bc[tt][12]);
    const float Bf[NB_NS] = {B0.x, B0.y, B0.z, B0.w, B1.x, B1.y, B1.z, B1.w,
                             B2.x, B2.y, B2.z, B2.w, B3.x, B3.y, B3.z, B3.w};
#pragma unroll
    for (int n = 0; n < NB_NS; ++n) {
      float e0 = exp_small(d0 * An[n]);
      float e1 = exp_small(d1 * An[n]);
      P0[n] *= e0;
      P1[n] *= e1;
      S0[n] = __builtin_fmaf(e0, S0[n], Bf[n] * u0);
      S1[n] = __builtin_fmaf(e1, S1[n], Bf[n] * u1);
    }
    uA = uB; dA = dB; uB = uC2; dB = dC2; uC2 = uD; dC2 = dD;
  }
#pragma unroll
  for (int n = 0; n < NB_NS; ++n) {
    size_t o = ((((size_t)b * NCHUNK + ck) * NB_NS + n) * NB_H + h0);
    *reinterpret_cast<u32*>(dPout + o) =
        (u32)f2b(1.0f - P0[n]) | ((u32)f2b(1.0f - P1[n]) << 16);
    *reinterpret_cast<u32*>(Sout + o) =
        (u32)f2b(S0[n]) | ((u32)f2b(S1[n]) << 16);
  }
}

// pass B: sequential combine over chunks; Hst (bf16) in-place over dP. h-pair.
__global__ void scan_passB_k(u16* __restrict__ dP, const u16* __restrict__ S) {
  int idx = blockIdx.x * 256 + threadIdx.x;   // 4*16*1024 = 65536
  int hp = idx & 1023;
  int n = (idx >> 10) & (NB_NS - 1);
  int b = idx >> 14;
  int h0 = hp * 2;
  const size_t stride = (size_t)NB_NS * NB_H;   // u16 units
  size_t o = ((size_t)b * NCHUNK * NB_NS + n) * NB_H + h0;
  float hs0 = 0.f, hs1 = 0.f;
  u32 pw = *reinterpret_cast<const u32*>(dP + o);
  u32 sw = *reinterpret_cast<const u32*>(S + o);
  for (int ck = 0; ck < NCHUNK; ++ck) {
    u32 pn = 0, sn = 0;
    if (ck + 1 < NCHUNK) {
      pn = *reinterpret_cast<const u32*>(dP + o + stride);
      sn = *reinterpret_cast<const u32*>(S + o + stride);
    }
    float p0 = 1.f - b2f_lo(pw), p1 = 1.f - b2f_hi(pw);
    float s0 = b2f_lo(sw),       s1 = b2f_hi(sw);
    *reinterpret_cast<u32*>(dP + o) = (u32)f2b(hs0) | ((u32)f2b(hs1) << 16);
    hs0 = __builtin_fmaf(p0, hs0, s0);
    hs1 = __builtin_fmaf(p1, hs1, s1);
    o += stride; pw = pn; sw = sn;
  }
}

// pass C: replay + gate, h-pair + depth-3 prefetch.
__global__ __launch_bounds__(256)
void scan_passC_k(const u16* __restrict__ dt, const u16* __restrict__ uc,
                  const float* __restrict__ xdbl, const u16* __restrict__ xz,
                  const float* __restrict__ A_log, const float* __restrict__ Dp,
                  const u16* __restrict__ Hst, u16* __restrict__ ybf) {
  __shared__ float bc[CLEN][32];
  const int tid = threadIdx.x;
  int idx = blockIdx.x * 256 + tid;   // 4*64*1024
  int hp = idx & 1023;
  int ck = (idx >> 10) & (NCHUNK - 1);
  int b = idx >> 16;
  int h0 = hp * 2;
  const int t0 = b * NB_L + ck * CLEN;
  {
    int r = tid >> 3, q = tid & 7;
    *reinterpret_cast<float4*>(&bc[r][q * 4]) =
        *reinterpret_cast<const float4*>(xdbl + (size_t)(t0 + r) * 128 + 64 + q * 4);
  }
  float An[NB_NS];
#pragma unroll
  for (int n = 0; n < NB_NS; ++n) An[n] = -__expf(A_log[n]);
  float s0[NB_NS], s1[NB_NS];
#pragma unroll
  for (int n = 0; n < NB_NS; ++n) {
    size_t o = ((((size_t)b * NCHUNK + ck) * NB_NS + n) * NB_H + h0);
    u32 hw = *reinterpret_cast<const u32*>(Hst + o);
    s0[n] = b2f_lo(hw); s1[n] = b2f_hi(hw);
  }
  const float Dh0 = Dp[h0], Dh1 = Dp[h0 + 1];
  __syncthreads();
  const u32* up = reinterpret_cast<const u32*>(uc + (size_t)t0 * NB_H + h0);
  const u32* dp = reinterpret_cast<const u32*>(dt + (size_t)t0 * NB_H + h0);
  const u32* zp = reinterpret_cast<const u32*>(xz + (size_t)t0 * 4096 + NB_H + h0);
  u16* yp = ybf + (size_t)t0 * NB_H + h0;
  const int STR = NB_H / 2;
  const int ZSTR = 4096 / 2;
  u32 uA = up[0],        dA = dp[0],        zA = zp[0];
  u32 uB = up[STR],      dB = dp[STR],      zB = zp[ZSTR];
  u32 uC2 = up[2 * STR], dC2 = dp[2 * STR], zC2 = zp[2 * ZSTR];
  for (int tt = 0; tt < CLEN; ++tt) {
    u32 uD = 0, dD = 0, zD = 0;
    if (tt + 3 < CLEN) { uD = up[3 * STR]; dD = dp[3 * STR]; zD = zp[3 * ZSTR]; }
    up += STR; dp += STR; zp += ZSTR;
    float u0 = b2f_lo(uA), u1 = b2f_hi(uA);
    float d0 = b2f_lo(dA), d1 = b2f_hi(dA);
    float z0 = b2f_lo(zA), z1 = b2f_hi(zA);
    float4 B0 = *reinterpret_cast<const float4*>(&bc[tt][0]);
    float4 B1 = *reinterpret_cast<const float4*>(&bc[tt][4]);
    float4 B2 = *reinterpret_cast<const float4*>(&bc[tt][8]);
    float4 B3 = *reinterpret_cast<const float4*>(&bc[tt][12]);
    float4 C0 = *reinterpret_cast<const float4*>(&bc[tt][16]);
    float4 C1 = *reinterpret_cast<const float4*>(&bc[tt][20]);
    float4 C2 = *reinterpret_cast<const float4*>(&bc[tt][24]);
    float4 C3 = *reinterpret_cast<const float4*>(&bc[tt][28]);
    const float Bf[NB_NS] = {B0.x, B0.y, B0.z, B0.w, B1.x, B1.y, B1.z, B1.w,
                             B2.x, B2.y, B2.z, B2.w, B3.x, B3.y, B3.z, B3.w};
    const float Cf[NB_NS] = {C0.x, C0.y, C0.z, C0.w, C1.x, C1.y, C1.z, C1.w,
                             C2.x, C2.y, C2.z, C2.w, C3.x, C3.y, C3.z, C3.w};
    float y0 = 0.f, y1 = 0.f;
#pragma unroll
    for (int n = 0; n < NB_NS; ++n) {
      float e0 = exp_small(d0 * An[n]);
      float e1 = exp_small(d1 * An[n]);
      s0[n] = __builtin_fmaf(e0, s0[n], Bf[n] * u0);
      s1[n] = __builtin_fmaf(e1, s1[n], Bf[n] * u1);
      y0 = __builtin_fmaf(Cf[n], s0[n], y0);
      y1 = __builtin_fmaf(Cf[n], s1[n], y1);
    }
    float v0 = __builtin_fmaf(Dh0, u0, y0);
    float v1 = __builtin_fmaf(Dh1, u1, y1);
    float g0 = z0 / (1.f + __expf(-z0));
    float g1 = z1 / (1.f + __expf(-z1));
    *reinterpret_cast<u32*>(yp) = (u32)f2b(v0 * g0) | ((u32)f2b(v1 * g1) << 16);
    yp += NB_H;
    uA = uB; dA = dB; zA = zB; uB = uC2; dB = dC2; zB = zC2;
    uC2 = uD; dC2 = dD; zC2 = zD;
  }
}

// ---------------- launcher ----------------
extern "C" void kernel_launch(void* const* d_in, const int* in_sizes, int n_in,
                              void* d_out, int out_size, void* d_ws, size_t ws_size,
                              hipStream_t stream) {
  const float* x      = (const float*)d_in[0];
  const float* W_in   = (const float*)d_in[1];
  const float* conv_w = (const float*)d_in[2];
  const float* conv_b = (const float*)d_in[3];
  const float* W_xprj = (const float*)d_in[4];
  const float* W_dt   = (const float*)d_in[5];
  const float* b_dt   = (const float*)d_in[6];
  const float* A_log  = (const float*)d_in[7];
  const float* Dp     = (const float*)d_in[8];
  const float* W_out  = (const float*)d_in[9];
  float* out = (float*)d_out;

  char* ws = (char*)d_ws;
  size_t off = 0;
  auto alloc = [&](size_t bytes) {
    void* p = ws + off;
    off += (bytes + 255) & ~(size_t)255;
    return p;
  };
  u16*   xz_b   = (u16*)alloc((size_t)NB_TOK * 4096 * 2);     // 64MB
  u16*   x_b    = (u16*)alloc((size_t)NB_TOK * NB_DIM * 2);   // 16MB
  u16*   win_b  = (u16*)alloc((size_t)4096 * NB_DIM * 2);     // 8MB
  u16*   wxp_b  = (u16*)alloc((size_t)128 * NB_H * 2);        // 512KB
  u16*   wdt_b  = (u16*)alloc((size_t)NB_H * NB_DTR * 2);     // 256KB
  u16*   wout_b = (u16*)alloc((size_t)NB_DIM * NB_H * 2);     // 4MB
  u16*   uc_b   = (u16*)alloc((size_t)NB_TOK * NB_H * 2);     // 32MB
  float* xdbl   = (float*)alloc((size_t)NB_TOK * 128 * 4);    // 4MB
  u16*   dtp_b  = (u16*)alloc((size_t)NB_TOK * NB_DTR * 2);   // 1MB
  u16*   dt_b   = (u16*)alloc((size_t)NB_TOK * NB_H * 2);     // 32MB
  u16*   scdP   = (u16*)alloc((size_t)NB_B * NCHUNK * NB_NS * NB_H * 2); // 16MB (dP -> Hst)
  u16*   scS    = (u16*)alloc((size_t)NB_B * NCHUNK * NB_NS * NB_H * 2); // 16MB
  u16*   y_b    = (u16*)alloc((size_t)NB_TOK * NB_H * 2);     // 32MB
  float* g2part = (float*)scdP;   // split-K partials (16MB) alias scdP+scS
  (void)ws_size; (void)in_sizes; (void)n_in; (void)out_size;

  cvt_all_k<<<(CVT_N5 + 255) / 256, 256, 0, stream>>>(
      x, W_in, W_dt, W_out, W_xprj, x_b, win_b, wdt_b, wout_b, wxp_b);

  // GEMM1: xz = x @ W_in^T  (tiles 32x16): XCD chunks 8x8, chunk grid 4x2
  gemm8p_k<EPI_BF16, 256><<<512, 512, 0, stream>>>(
      x_b, win_b, NB_DIM, 4096, xz_b, nullptr, nullptr, nullptr, 8, 8, 2);

  dwconv_silu_k<<<(NB_TOK * NB_H / 8) / 256, 256, 0, stream>>>(xz_b, conv_w, conv_b, uc_b);

  // GEMM2 split-K=4 -> partials; reduce -> xdbl f32 + dtp bf16
  gemm2sk_k<<<dim3(128, 1, 4), 256, 0, stream>>>(uc_b, wxp_b, g2part);
  reduce_xdbl_k<<<(NB_TOK * 128) / 256, 256, 0, stream>>>(g2part, xdbl, dtp_b);

  // GEMM3: dt = softplus(dtp @ W_dt^T + b_dt)  (BM=128: tiles 64x8, chunks 8x8)
  gemm8p_k<EPI_SP_BF16, 128><<<512, 512, 0, stream>>>(
      dtp_b, wdt_b, NB_DTR, NB_H, dt_b, nullptr, b_dt, nullptr, 8, 8, 1);

  scan_passA_k<<<(NB_B * NCHUNK * NB_H / 2) / 256, 256, 0, stream>>>(dt_b, uc_b, xdbl, A_log, scdP, scS);
  scan_passB_k<<<(NB_B * NB_NS * NB_H / 2) / 256, 256, 0, stream>>>(scdP, scS);
  scan_passC_k<<<(NB_B * NCHUNK * NB_H / 2) / 256, 256, 0, stream>>>(dt_b, uc_b, xdbl, xz_b, A_log, Dp, scdP, y_b);

  // GEMM4: out = y @ W_out^T + x  (tiles 64x4, BM=128): chunks 8x4
  gemm8p_k<EPI_RES_F32, 128><<<256, 512, 0, stream>>>(
      y_b, wout_b, NB_H, NB_DIM, nullptr, out, nullptr, x, 8, 4, 1);
}